// Round 1
// baseline (3845.496 us; speedup 1.0000x reference)
//
#include <hip/hip_runtime.h>
#include <hip/hip_bf16.h>
#include <math.h>

#define DIM 1024
#define D_STATE 16
#define D_CONV 4
#define D_INNER 2048
#define DT_RANK 64
#define N_EXP 8
#define TOP_K 2
#define HID 2048
#define BB 2
#define TT 2048
#define NTOK (BB*TT)          // 4096
#define NSLOT (NTOK*TOP_K)    // 8192
#define EPS 1e-5f

// ---------------- workspace layout (floats) ----------------
#define OFF_XN   ((size_t)0)                       // 4096*1024        (later xn2)
#define OFF_XZ   ((size_t)4194304)                 // 4096*4096        (later MoE H: 8192*2048)
#define OFF_XCS  ((size_t)20971520)                // 4096*2048        (later down_out: 8192*1024)
#define OFF_DTP  ((size_t)29360128)                // 4096*2048
#define OFF_YM   ((size_t)37748736)                // 4096*2048
#define OFF_X1   ((size_t)46137344)                // 4096*1024
#define OFF_PROJ ((size_t)50331648)                // 4096*96
#define OFF_TW   ((size_t)50724864)                // 4096*2
#define OFF_INT  ((size_t)50733056)                // int area
// int area offsets (in ints, relative to OFF_INT)
#define IO_TI    0        // 8192
#define IO_CNT   8192     // 8
#define IO_CUR   8200     // 8
#define IO_OFS   8208     // 8
#define IO_TOK   8216     // 8192
#define IO_SLOT  16408    // 8192

__device__ __forceinline__ float siluf(float v){ return v / (1.f + expf(-v)); }

// ---------------- LayerNorm: one block per token ----------------
__global__ __launch_bounds__(256) void ln_kernel(const float* __restrict__ x,
    const float* __restrict__ s, const float* __restrict__ b, float* __restrict__ o)
{
    int t = blockIdx.x;
    const float* xp = x + (size_t)t * DIM;
    float v[4]; float sum = 0.f, sq = 0.f;
    #pragma unroll
    for (int j = 0; j < 4; ++j){
        v[j] = xp[threadIdx.x + 256*j];
        sum += v[j]; sq += v[j]*v[j];
    }
    #pragma unroll
    for (int off = 32; off; off >>= 1){
        sum += __shfl_xor(sum, off, 64);
        sq  += __shfl_xor(sq , off, 64);
    }
    __shared__ float red[4][2];
    int w = threadIdx.x >> 6, lane = threadIdx.x & 63;
    if (lane == 0){ red[w][0] = sum; red[w][1] = sq; }
    __syncthreads();
    sum = red[0][0]+red[1][0]+red[2][0]+red[3][0];
    sq  = red[0][1]+red[1][1]+red[2][1]+red[3][1];
    float mu = sum * (1.f/DIM);
    float var = sq * (1.f/DIM) - mu*mu;
    float r = rsqrtf(var + EPS);
    float* op = o + (size_t)t * DIM;
    #pragma unroll
    for (int j = 0; j < 4; ++j){
        int d = threadIdx.x + 256*j;
        op[d] = (v[j]-mu)*r*s[d] + b[d];
    }
}

// ---------------- generic fp32 GEMM: C[m,n] = act(sum_k A[m,k]W[n,k] + bias) (+resid) ----------
// ACT: 0 none, 1 softplus
template<int ACT>
__global__ __launch_bounds__(256) void gemm_nt(
    const float* __restrict__ A, const float* __restrict__ W,
    const float* __restrict__ bias, const float* __restrict__ resid,
    float* __restrict__ C, int M, int N, int K, int lda, int ldw, int ldc)
{
    __shared__ float As[16][68];
    __shared__ float Ws[16][68];
    int tid = threadIdx.x;
    int m0 = blockIdx.y * 64, n0 = blockIdx.x * 64;
    int ty = tid >> 4, tx = tid & 15;
    int lr = tid >> 2, lc = (tid & 3) * 4;
    float acc[4][4] = {};
    for (int k0 = 0; k0 < K; k0 += 16){
        int m = m0 + lr;
        float4 v = make_float4(0,0,0,0);
        if (m < M) v = *(const float4*)(A + (size_t)m*lda + k0 + lc);
        As[lc+0][lr]=v.x; As[lc+1][lr]=v.y; As[lc+2][lr]=v.z; As[lc+3][lr]=v.w;
        int n = n0 + lr;
        float4 u = make_float4(0,0,0,0);
        if (n < N) u = *(const float4*)(W + (size_t)n*ldw + k0 + lc);
        Ws[lc+0][lr]=u.x; Ws[lc+1][lr]=u.y; Ws[lc+2][lr]=u.z; Ws[lc+3][lr]=u.w;
        __syncthreads();
        #pragma unroll
        for (int kk = 0; kk < 16; ++kk){
            float4 a = *(const float4*)&As[kk][ty*4];
            float4 b = *(const float4*)&Ws[kk][tx*4];
            float av[4] = {a.x,a.y,a.z,a.w};
            float bv[4] = {b.x,b.y,b.z,b.w};
            #pragma unroll
            for (int i = 0; i < 4; ++i)
                #pragma unroll
                for (int j = 0; j < 4; ++j)
                    acc[i][j] += av[i]*bv[j];
        }
        __syncthreads();
    }
    #pragma unroll
    for (int i = 0; i < 4; ++i){
        int m = m0 + ty*4 + i;
        if (m >= M) break;
        #pragma unroll
        for (int j = 0; j < 4; ++j){
            int n = n0 + tx*4 + j;
            if (n >= N) continue;
            float v = acc[i][j];
            if (bias) v += bias[n];
            if (ACT == 1) v = (v > 20.f) ? v : log1pf(expf(v));
            if (resid) v += resid[(size_t)m*ldc + n];
            C[(size_t)m*ldc + n] = v;
        }
    }
}

// ---------------- causal depthwise conv(4) + bias + silu ----------------
__global__ __launch_bounds__(256) void conv_kernel(const float* __restrict__ xz,
    const float* __restrict__ cs, const float* __restrict__ cw,
    const float* __restrict__ cb, float* __restrict__ xcs)
{
    int idx = blockIdx.x*256 + threadIdx.x;      // over B*T*D_INNER = 8,388,608
    int d = idx & (D_INNER-1);
    int bt = idx >> 11;
    int b = bt >> 11;                            // T = 2048
    int t = bt & (TT-1);
    float acc = cb[d];
    #pragma unroll
    for (int k = 0; k < 4; ++k){
        int tau = t + k - 3;
        float xv;
        if (tau >= 0) xv = xz[(size_t)(b*TT + tau)*(2*D_INNER) + d];
        else          xv = cs[((size_t)b*D_INNER + d)*3 + (tau + 3)];
        acc += cw[d*4 + k] * xv;
    }
    xcs[idx] = siluf(acc);
}

// ---------------- SSM scan: 16 lanes per (b,d) channel ----------------
__global__ __launch_bounds__(256) void ssm_scan(const float* __restrict__ dtp,
    const float* __restrict__ proj, const float* __restrict__ xcs,
    const float* __restrict__ xz, const float* __restrict__ A_log,
    const float* __restrict__ Dp, const float* __restrict__ ssm0,
    float* __restrict__ ym)
{
    int gid = blockIdx.x*256 + threadIdx.x;      // 65536
    int lane = gid & 15;
    int ch = gid >> 4;                           // 0..4095
    int b = ch >> 11;
    int d = ch & (D_INNER-1);
    float As = -expf(A_log[d*D_STATE + lane]);
    float h = ssm0[((size_t)b*D_INNER + d)*D_STATE + lane];
    float Dd = Dp[d];
    int base = b*TT;
    // pipelined loads
    size_t bt0 = (size_t)base;
    float dt = dtp[bt0*D_INNER + d];
    float x  = xcs[bt0*D_INNER + d];
    float Bv = proj[bt0*96 + DT_RANK + lane];
    float Cv = proj[bt0*96 + DT_RANK + D_STATE + lane];
    for (int t = 0; t < TT; ++t){
        float dt_n=0.f, x_n=0.f, B_n=0.f, C_n=0.f;
        if (t + 1 < TT){
            size_t btn = (size_t)(base + t + 1);
            dt_n = dtp[btn*D_INNER + d];
            x_n  = xcs[btn*D_INNER + d];
            B_n  = proj[btn*96 + DT_RANK + lane];
            C_n  = proj[btn*96 + DT_RANK + D_STATE + lane];
        }
        float dA = __expf(dt*As);
        h = dA*h + dt*Bv*x;
        float p = h*Cv;
        p += __shfl_xor(p, 1, 16);
        p += __shfl_xor(p, 2, 16);
        p += __shfl_xor(p, 4, 16);
        p += __shfl_xor(p, 8, 16);
        if (lane == 0){
            size_t bt = (size_t)(base + t);
            float y = p + Dd*x;
            float z = xz[bt*(2*D_INNER) + D_INNER + d];
            ym[bt*D_INNER + d] = y * siluf(z);
        }
        dt = dt_n; x = x_n; Bv = B_n; Cv = C_n;
    }
}

// ---------------- router: one wave per token ----------------
__global__ __launch_bounds__(256) void router_kernel(const float* __restrict__ xn2,
    const float* __restrict__ rw, float* __restrict__ tw, int* __restrict__ ti,
    int* __restrict__ counts)
{
    int tok = blockIdx.x*4 + (threadIdx.x >> 6);
    int lane = threadIdx.x & 63;
    float p[N_EXP] = {};
    const float* xp = xn2 + (size_t)tok * DIM;
    for (int dd = lane; dd < DIM; dd += 64){
        float xv = xp[dd];
        #pragma unroll
        for (int e = 0; e < N_EXP; ++e) p[e] += xv * rw[e*DIM + dd];
    }
    #pragma unroll
    for (int e = 0; e < N_EXP; ++e){
        #pragma unroll
        for (int off = 32; off; off >>= 1) p[e] += __shfl_xor(p[e], off, 64);
    }
    if (lane == 0){
        float mx = p[0];
        #pragma unroll
        for (int e = 1; e < N_EXP; ++e) mx = fmaxf(mx, p[e]);
        float q[N_EXP]; float ssum = 0.f;
        #pragma unroll
        for (int e = 0; e < N_EXP; ++e){ q[e] = expf(p[e]-mx); ssum += q[e]; }
        int i0 = 0;
        #pragma unroll
        for (int e = 1; e < N_EXP; ++e) if (q[e] > q[i0]) i0 = e;
        int i1 = (i0 == 0) ? 1 : 0;
        #pragma unroll
        for (int e = 0; e < N_EXP; ++e) if (e != i0 && q[e] > q[i1]) i1 = e;
        float w0 = q[i0]/ssum, w1 = q[i1]/ssum;
        float sw = w0 + w1; w0 /= sw; w1 /= sw;
        tw[tok*2] = w0; tw[tok*2+1] = w1;
        ti[tok*2] = i0; ti[tok*2+1] = i1;
        atomicAdd(&counts[i0], 1);
        atomicAdd(&counts[i1], 1);
    }
}

__global__ void offs_kernel(const int* __restrict__ counts, int* __restrict__ offs)
{
    if (threadIdx.x == 0 && blockIdx.x == 0){
        int s = 0;
        for (int e = 0; e < N_EXP; ++e){ offs[e] = s; s += counts[e]; }
    }
}

__global__ __launch_bounds__(256) void assign_kernel(const int* __restrict__ ti,
    const int* __restrict__ offs, int* __restrict__ cursors,
    int* __restrict__ tok_of_slot, int* __restrict__ slot_of)
{
    int t = blockIdx.x*256 + threadIdx.x;
    if (t >= NTOK) return;
    #pragma unroll
    for (int k = 0; k < TOP_K; ++k){
        int e = ti[t*2 + k];
        int pos = atomicAdd(&cursors[e], 1);
        int slot = offs[e] + pos;
        tok_of_slot[slot] = t;
        slot_of[t*2 + k] = slot;
    }
}

// ---------------- MoE fused gate/up GEMM: H[slot,n] = silu(X W_g^T) * (X W_u^T) ----------
__global__ __launch_bounds__(256) void moe_gateup(const float* __restrict__ X,
    const float* __restrict__ Wg, const float* __restrict__ Wu,
    const int* __restrict__ tok_of_slot, const int* __restrict__ counts,
    const int* __restrict__ offs, float* __restrict__ H)
{
    int e = blockIdx.z;
    int cnt = counts[e];
    int m0 = blockIdx.y * 64;
    if (m0 >= cnt) return;
    int n0 = blockIdx.x * 64;
    int base = offs[e];
    const float* wg = Wg + (size_t)e * HID * DIM;
    const float* wu = Wu + (size_t)e * HID * DIM;
    __shared__ float As[16][68], Gs[16][68], Us[16][68];
    __shared__ int toks[64];
    int tid = threadIdx.x;
    if (tid < 64){
        int m = m0 + tid;
        toks[tid] = (m < cnt) ? tok_of_slot[base + m] : -1;
    }
    __syncthreads();
    int ty = tid >> 4, tx = tid & 15;
    int lr = tid >> 2, lc = (tid & 3) * 4;
    float accg[4][4] = {}, accu[4][4] = {};
    for (int k0 = 0; k0 < DIM; k0 += 16){
        int tk = toks[lr];
        float4 v = make_float4(0,0,0,0);
        if (tk >= 0) v = *(const float4*)(X + (size_t)tk*DIM + k0 + lc);
        As[lc+0][lr]=v.x; As[lc+1][lr]=v.y; As[lc+2][lr]=v.z; As[lc+3][lr]=v.w;
        float4 g = *(const float4*)(wg + (size_t)(n0+lr)*DIM + k0 + lc);
        Gs[lc+0][lr]=g.x; Gs[lc+1][lr]=g.y; Gs[lc+2][lr]=g.z; Gs[lc+3][lr]=g.w;
        float4 u = *(const float4*)(wu + (size_t)(n0+lr)*DIM + k0 + lc);
        Us[lc+0][lr]=u.x; Us[lc+1][lr]=u.y; Us[lc+2][lr]=u.z; Us[lc+3][lr]=u.w;
        __syncthreads();
        #pragma unroll
        for (int kk = 0; kk < 16; ++kk){
            float4 a  = *(const float4*)&As[kk][ty*4];
            float4 bg = *(const float4*)&Gs[kk][tx*4];
            float4 bu = *(const float4*)&Us[kk][tx*4];
            float av[4]={a.x,a.y,a.z,a.w}, gv[4]={bg.x,bg.y,bg.z,bg.w}, uv[4]={bu.x,bu.y,bu.z,bu.w};
            #pragma unroll
            for (int i = 0; i < 4; ++i)
                #pragma unroll
                for (int j = 0; j < 4; ++j){
                    accg[i][j] += av[i]*gv[j];
                    accu[i][j] += av[i]*uv[j];
                }
        }
        __syncthreads();
    }
    #pragma unroll
    for (int i = 0; i < 4; ++i){
        int m = m0 + ty*4 + i;
        if (m >= cnt) break;
        size_t slot = base + m;
        #pragma unroll
        for (int j = 0; j < 4; ++j){
            int n = n0 + tx*4 + j;
            float g = accg[i][j], u = accu[i][j];
            H[slot*HID + n] = siluf(g) * u;
        }
    }
}

// ---------------- MoE down GEMM: down_out[slot,n] = H[slot,:] @ w_down[e][n,:] ----------
__global__ __launch_bounds__(256) void moe_down(const float* __restrict__ H,
    const float* __restrict__ Wd, const int* __restrict__ counts,
    const int* __restrict__ offs, float* __restrict__ down_out)
{
    int e = blockIdx.z;
    int cnt = counts[e];
    int m0 = blockIdx.y * 64;
    if (m0 >= cnt) return;
    int n0 = blockIdx.x * 64;
    int base = offs[e];
    const float* wd = Wd + (size_t)e * DIM * HID;
    __shared__ float As[16][68], Ws[16][68];
    int tid = threadIdx.x;
    int ty = tid >> 4, tx = tid & 15;
    int lr = tid >> 2, lc = (tid & 3) * 4;
    float acc[4][4] = {};
    for (int k0 = 0; k0 < HID; k0 += 16){
        int m = m0 + lr;
        float4 v = make_float4(0,0,0,0);
        if (m < cnt) v = *(const float4*)(H + (size_t)(base+m)*HID + k0 + lc);
        As[lc+0][lr]=v.x; As[lc+1][lr]=v.y; As[lc+2][lr]=v.z; As[lc+3][lr]=v.w;
        float4 u = *(const float4*)(wd + (size_t)(n0+lr)*HID + k0 + lc);
        Ws[lc+0][lr]=u.x; Ws[lc+1][lr]=u.y; Ws[lc+2][lr]=u.z; Ws[lc+3][lr]=u.w;
        __syncthreads();
        #pragma unroll
        for (int kk = 0; kk < 16; ++kk){
            float4 a = *(const float4*)&As[kk][ty*4];
            float4 b = *(const float4*)&Ws[kk][tx*4];
            float av[4]={a.x,a.y,a.z,a.w}, bv[4]={b.x,b.y,b.z,b.w};
            #pragma unroll
            for (int i = 0; i < 4; ++i)
                #pragma unroll
                for (int j = 0; j < 4; ++j)
                    acc[i][j] += av[i]*bv[j];
        }
        __syncthreads();
    }
    #pragma unroll
    for (int i = 0; i < 4; ++i){
        int m = m0 + ty*4 + i;
        if (m >= cnt) break;
        size_t slot = base + m;
        #pragma unroll
        for (int j = 0; j < 4; ++j){
            int n = n0 + tx*4 + j;
            down_out[slot*DIM + n] = acc[i][j];
        }
    }
}

// ---------------- final: out = x1 + tw0*down[slot0] + tw1*down[slot1] ----------------
__global__ __launch_bounds__(256) void final_kernel(const float* __restrict__ x1,
    const float* __restrict__ down_out, const float* __restrict__ tw,
    const int* __restrict__ slot_of, float* __restrict__ out)
{
    int idx4 = blockIdx.x*256 + threadIdx.x;     // over NTOK*DIM/4
    int t = idx4 >> 8;                           // DIM/4 = 256
    int c = idx4 & 255;
    float w0 = tw[t*2], w1 = tw[t*2+1];
    size_t s0 = (size_t)slot_of[t*2] * DIM;
    size_t s1 = (size_t)slot_of[t*2+1] * DIM;
    float4 a = *(const float4*)(x1 + (size_t)t*DIM + c*4);
    float4 d0 = *(const float4*)(down_out + s0 + c*4);
    float4 d1 = *(const float4*)(down_out + s1 + c*4);
    float4 r;
    r.x = a.x + w0*d0.x + w1*d1.x;
    r.y = a.y + w0*d0.y + w1*d1.y;
    r.z = a.z + w0*d0.z + w1*d1.z;
    r.w = a.w + w0*d0.w + w1*d1.w;
    *(float4*)(out + (size_t)t*DIM + c*4) = r;
}

extern "C" void kernel_launch(void* const* d_in, const int* in_sizes, int n_in,
                              void* d_out, int out_size, void* d_ws, size_t ws_size,
                              hipStream_t stream)
{
    const float* x        = (const float*)d_in[0];
    const float* ssm0     = (const float*)d_in[1];
    const float* conv0    = (const float*)d_in[2];
    const float* ln1_s    = (const float*)d_in[3];
    const float* ln1_b    = (const float*)d_in[4];
    const float* ln2_s    = (const float*)d_in[5];
    const float* ln2_b    = (const float*)d_in[6];
    const float* in_proj  = (const float*)d_in[7];
    const float* conv_w   = (const float*)d_in[8];
    const float* conv_b   = (const float*)d_in[9];
    const float* x_proj   = (const float*)d_in[10];
    const float* dt_proj  = (const float*)d_in[11];
    const float* dt_b     = (const float*)d_in[12];
    const float* A_log    = (const float*)d_in[13];
    const float* Dp       = (const float*)d_in[14];
    const float* out_proj = (const float*)d_in[15];
    const float* router_w = (const float*)d_in[16];
    const float* w_gate   = (const float*)d_in[17];
    const float* w_up     = (const float*)d_in[18];
    const float* w_down   = (const float*)d_in[19];
    float* out = (float*)d_out;

    float* ws = (float*)d_ws;
    float* xn   = ws + OFF_XN;
    float* xz   = ws + OFF_XZ;
    float* xcs  = ws + OFF_XCS;
    float* dtp  = ws + OFF_DTP;
    float* ym   = ws + OFF_YM;
    float* x1   = ws + OFF_X1;
    float* proj = ws + OFF_PROJ;
    float* tw   = ws + OFF_TW;
    int*   ip   = (int*)(ws + OFF_INT);
    int* ti          = ip + IO_TI;
    int* counts      = ip + IO_CNT;
    int* cursors     = ip + IO_CUR;
    int* offs        = ip + IO_OFS;
    int* tok_of_slot = ip + IO_TOK;
    int* slot_of     = ip + IO_SLOT;
    // reused regions
    float* xn2      = xn;    // xn dead after in_proj
    float* Hbuf     = xz;    // 8192*2048 fits in xz region exactly
    float* down_out = xcs;   // 8192*1024 fits in xcs region exactly

    // zero counts + cursors (16 ints)
    hipMemsetAsync(counts, 0, 16*sizeof(int), stream);

    // 1. xn = LN1(x)
    ln_kernel<<<NTOK, 256, 0, stream>>>(x, ln1_s, ln1_b, xn);
    // 2. xz = xn @ in_proj^T   (M=4096,N=4096,K=1024)
    gemm_nt<0><<<dim3(64,64), 256, 0, stream>>>(xn, in_proj, nullptr, nullptr, xz,
        NTOK, 2*D_INNER, DIM, DIM, DIM, 2*D_INNER);
    // 3. conv + silu -> xcs
    conv_kernel<<<(NTOK*D_INNER)/256, 256, 0, stream>>>(xz, conv0, conv_w, conv_b, xcs);
    // 4. proj = xcs @ x_proj^T  (N=96, K=2048)
    gemm_nt<0><<<dim3(2,64), 256, 0, stream>>>(xcs, x_proj, nullptr, nullptr, proj,
        NTOK, 96, D_INNER, D_INNER, D_INNER, 96);
    // 5. dtp = softplus(proj[:, :64] @ dt_proj^T + dt_b)  (N=2048, K=64)
    gemm_nt<1><<<dim3(32,64), 256, 0, stream>>>(proj, dt_proj, dt_b, nullptr, dtp,
        NTOK, D_INNER, DT_RANK, 96, DT_RANK, D_INNER);
    // 6. scan -> ym = y * silu(z)
    ssm_scan<<<256, 256, 0, stream>>>(dtp, proj, xcs, xz, A_log, Dp, ssm0, ym);
    // 7. x1 = x + ym @ out_proj^T  (N=1024, K=2048)
    gemm_nt<0><<<dim3(16,64), 256, 0, stream>>>(ym, out_proj, nullptr, x, x1,
        NTOK, DIM, D_INNER, D_INNER, D_INNER, DIM);
    // 8. xn2 = LN2(x1)
    ln_kernel<<<NTOK, 256, 0, stream>>>(x1, ln2_s, ln2_b, xn2);
    // 9. router
    router_kernel<<<NTOK/4, 256, 0, stream>>>(xn2, router_w, tw, ti, counts);
    offs_kernel<<<1, 64, 0, stream>>>(counts, offs);
    assign_kernel<<<NTOK/256, 256, 0, stream>>>(ti, offs, cursors, tok_of_slot, slot_of);
    // 10. MoE
    moe_gateup<<<dim3(HID/64, 64, N_EXP), 256, 0, stream>>>(xn2, w_gate, w_up,
        tok_of_slot, counts, offs, Hbuf);
    moe_down<<<dim3(DIM/64, 64, N_EXP), 256, 0, stream>>>(Hbuf, w_down, counts, offs, down_out);
    // 11. out = x1 + weighted experts
    final_kernel<<<(NTOK*DIM/4)/256, 256, 0, stream>>>(x1, down_out, tw, slot_of, out);
}

// Round 2
// 1241.226 us; speedup vs baseline: 3.0981x; 3.0981x over previous
//
#include <hip/hip_runtime.h>
#include <hip/hip_bf16.h>
#include <math.h>

#define DIM 1024
#define D_STATE 16
#define D_CONV 4
#define D_INNER 2048
#define DT_RANK 64
#define N_EXP 8
#define TOP_K 2
#define HID 2048
#define BB 2
#define TT 2048
#define NTOK (BB*TT)          // 4096
#define NSLOT (NTOK*TOP_K)    // 8192
#define EPS 1e-5f
#define NCHUNK 16
#define CLEN (TT/NCHUNK)      // 128

// ---------------- workspace layout (float offsets) ----------------
#define OFF_XN   ((size_t)0)                       // 4096*1024  (xn, later scan scratch, later xn2)
#define OFF_XZ   ((size_t)4194304)                 // 4096*4096  (xz, later G fp32 8192*2048)
#define OFF_XCS  ((size_t)20971520)                // 4096*2048  (xcs; +dtp region = H fp32 8192*2048)
#define OFF_DTP  ((size_t)29360128)                // 4096*2048
#define OFF_YM   ((size_t)37748736)                // 4096*2048  (ym, later down_out 8192*1024)
#define OFF_X1   ((size_t)46137344)                // 4096*1024
#define OFF_PROJ ((size_t)50331648)                // 4096*96
#define OFF_TW   ((size_t)50724864)                // 4096*2
#define OFF_INT  ((size_t)50733056)                // int area
// scan scratch inside xn region (xn dead after in_proj; region rewritten by LN2 later)
#define OFF_HEND (OFF_XN)                          // 4096*16*16 = 1,048,576 floats
#define OFF_HST  (OFF_XN + 1048576)                // 1,048,576 floats
#define OFF_SDT  (OFF_XN + 2097152)                // 65,536 floats
// int area offsets (ints)
#define IO_TI    0
#define IO_CNT   8192
#define IO_CUR   8200
#define IO_OFS   8208
#define IO_TOK   8216
#define IO_SLOT  16408

typedef __attribute__((ext_vector_type(4))) float f32x4;
typedef __attribute__((ext_vector_type(8))) __bf16 bf16x8;

__device__ __forceinline__ float siluf(float v){ return v / (1.f + expf(-v)); }

__device__ __forceinline__ f32x4 mfma16(bf16x8 a, bf16x8 b, f32x4 c){
    return __builtin_amdgcn_mfma_f32_16x16x32_bf16(a, b, c, 0, 0, 0);
}

__device__ __forceinline__ void cvt_store16(__bf16* dst, f32x4 a0, f32x4 a1, f32x4 a2, f32x4 a3){
    bf16x8 p0, p1;
    #pragma unroll
    for (int j = 0; j < 4; ++j){
        p0[j]   = (__bf16)a0[j];
        p0[j+4] = (__bf16)a1[j];
        p1[j]   = (__bf16)a2[j];
        p1[j+4] = (__bf16)a3[j];
    }
    *(bf16x8*)dst = p0;
    *(bf16x8*)(dst+8) = p1;
}

// ---------------- LayerNorm ----------------
__global__ __launch_bounds__(256) void ln_kernel(const float* __restrict__ x,
    const float* __restrict__ s, const float* __restrict__ b, float* __restrict__ o)
{
    int t = blockIdx.x;
    const float* xp = x + (size_t)t * DIM;
    float v[4]; float sum = 0.f, sq = 0.f;
    #pragma unroll
    for (int j = 0; j < 4; ++j){
        v[j] = xp[threadIdx.x + 256*j];
        sum += v[j]; sq += v[j]*v[j];
    }
    #pragma unroll
    for (int off = 32; off; off >>= 1){
        sum += __shfl_xor(sum, off, 64);
        sq  += __shfl_xor(sq , off, 64);
    }
    __shared__ float red[4][2];
    int w = threadIdx.x >> 6, lane = threadIdx.x & 63;
    if (lane == 0){ red[w][0] = sum; red[w][1] = sq; }
    __syncthreads();
    sum = red[0][0]+red[1][0]+red[2][0]+red[3][0];
    sq  = red[0][1]+red[1][1]+red[2][1]+red[3][1];
    float mu = sum * (1.f/DIM);
    float var = sq * (1.f/DIM) - mu*mu;
    float r = rsqrtf(var + EPS);
    float* op = o + (size_t)t * DIM;
    #pragma unroll
    for (int j = 0; j < 4; ++j){
        int d = threadIdx.x + 256*j;
        op[d] = (v[j]-mu)*r*s[d] + b[d];
    }
}

// ---------------- small fp32 GEMM (x_proj, dt) ----------------
template<int ACT>
__global__ __launch_bounds__(256) void gemm_nt(
    const float* __restrict__ A, const float* __restrict__ W,
    const float* __restrict__ bias, const float* __restrict__ resid,
    float* __restrict__ C, int M, int N, int K, int lda, int ldw, int ldc)
{
    __shared__ float As[16][68];
    __shared__ float Ws[16][68];
    int tid = threadIdx.x;
    int m0 = blockIdx.y * 64, n0 = blockIdx.x * 64;
    int ty = tid >> 4, tx = tid & 15;
    int lr = tid >> 2, lc = (tid & 3) * 4;
    float acc[4][4] = {};
    for (int k0 = 0; k0 < K; k0 += 16){
        int m = m0 + lr;
        float4 v = make_float4(0,0,0,0);
        if (m < M) v = *(const float4*)(A + (size_t)m*lda + k0 + lc);
        As[lc+0][lr]=v.x; As[lc+1][lr]=v.y; As[lc+2][lr]=v.z; As[lc+3][lr]=v.w;
        int n = n0 + lr;
        float4 u = make_float4(0,0,0,0);
        if (n < N) u = *(const float4*)(W + (size_t)n*ldw + k0 + lc);
        Ws[lc+0][lr]=u.x; Ws[lc+1][lr]=u.y; Ws[lc+2][lr]=u.z; Ws[lc+3][lr]=u.w;
        __syncthreads();
        #pragma unroll
        for (int kk = 0; kk < 16; ++kk){
            float4 a = *(const float4*)&As[kk][ty*4];
            float4 b = *(const float4*)&Ws[kk][tx*4];
            float av[4] = {a.x,a.y,a.z,a.w};
            float bv[4] = {b.x,b.y,b.z,b.w};
            #pragma unroll
            for (int i = 0; i < 4; ++i)
                #pragma unroll
                for (int j = 0; j < 4; ++j)
                    acc[i][j] += av[i]*bv[j];
        }
        __syncthreads();
    }
    #pragma unroll
    for (int i = 0; i < 4; ++i){
        int m = m0 + ty*4 + i;
        if (m >= M) break;
        #pragma unroll
        for (int j = 0; j < 4; ++j){
            int n = n0 + tx*4 + j;
            if (n >= N) continue;
            float v = acc[i][j];
            if (bias) v += bias[n];
            if (ACT == 1) v = (v > 20.f) ? v : log1pf(expf(v));
            if (resid) v += resid[(size_t)m*ldc + n];
            C[(size_t)m*ldc + n] = v;
        }
    }
}

// ---------------- bf16 MFMA GEMM: C[m,n] = sum_k A[m,k] W[n,k] ----------------
// MODE: 0 dense A-rows, 1 gather A-rows via tok_of_slot (grouped), 2 grouped contiguous A-rows
// EPI : 0 plain, 1 +resid[m*N+n] (dense), 2 silu(G[row*N+n]) * acc
template<int MODE, int EPI>
__global__ __launch_bounds__(256,2) void mfma_gemm(
    const float* __restrict__ A, const float* __restrict__ W,
    const float* __restrict__ RG, float* __restrict__ C,
    const int* __restrict__ tok_of_slot, const int* __restrict__ counts,
    const int* __restrict__ offs, int M, int N, int K, int lda)
{
    int e    = (MODE == 0) ? 0 : blockIdx.z;
    int cnt  = (MODE == 0) ? M : counts[e];
    int base = (MODE == 0) ? 0 : offs[e];
    int m0 = blockIdx.y * 128;
    if (m0 >= cnt) return;
    int n0 = blockIdx.x * 128;
    const float* We = W + (size_t)e * N * K;

    __shared__ __bf16 As[128*32];
    __shared__ __bf16 Ws[128*32];

    int tid = threadIdx.x;
    int srow = tid >> 1;            // 0..127
    int scol = (tid & 1) * 16;      // 0 / 16

    int am = m0 + srow;
    int amc = (am < cnt) ? am : (cnt - 1);
    const float* aptr;
    if (MODE == 1){
        int tok = tok_of_slot[base + amc];
        aptr = A + (size_t)tok * lda + scol;
    } else if (MODE == 2){
        aptr = A + (size_t)(base + amc) * lda + scol;
    } else {
        aptr = A + (size_t)am * lda + scol;
    }
    const float* wptr = We + (size_t)(n0 + srow) * K + scol;

    f32x4 ra[4], rw[4];
    #pragma unroll
    for (int j = 0; j < 4; ++j){
        ra[j] = *(const f32x4*)(aptr + j*4);
        rw[j] = *(const f32x4*)(wptr + j*4);
    }

    int wave = tid >> 6, lane = tid & 63;
    int wm = (wave >> 1) * 64, wn = (wave & 1) * 64;
    int fr = lane & 15, fk = (lane >> 4) * 8;

    f32x4 acc[4][4];
    #pragma unroll
    for (int i = 0; i < 4; ++i)
        #pragma unroll
        for (int j = 0; j < 4; ++j)
            acc[i][j] = (f32x4){0.f, 0.f, 0.f, 0.f};

    for (int k0 = 0; k0 < K; k0 += 32){
        cvt_store16(&As[srow*32 + scol], ra[0], ra[1], ra[2], ra[3]);
        cvt_store16(&Ws[srow*32 + scol], rw[0], rw[1], rw[2], rw[3]);
        __syncthreads();
        if (k0 + 32 < K){
            #pragma unroll
            for (int j = 0; j < 4; ++j){
                ra[j] = *(const f32x4*)(aptr + k0 + 32 + j*4);
                rw[j] = *(const f32x4*)(wptr + k0 + 32 + j*4);
            }
        }
        bf16x8 af[4], bfr[4];
        #pragma unroll
        for (int i = 0; i < 4; ++i)
            af[i] = *(const bf16x8*)&As[(wm + i*16 + fr)*32 + fk];
        #pragma unroll
        for (int i = 0; i < 4; ++i)
            bfr[i] = *(const bf16x8*)&Ws[(wn + i*16 + fr)*32 + fk];
        #pragma unroll
        for (int i = 0; i < 4; ++i)
            #pragma unroll
            for (int j = 0; j < 4; ++j)
                acc[i][j] = mfma16(af[i], bfr[j], acc[i][j]);
        __syncthreads();
    }

    int orow = (lane >> 4) * 4;
    int ocol = lane & 15;
    #pragma unroll
    for (int i = 0; i < 4; ++i){
        #pragma unroll
        for (int jj = 0; jj < 4; ++jj){
            #pragma unroll
            for (int j = 0; j < 4; ++j){
                int m = m0 + wm + i*16 + orow + j;
                if (m < cnt){
                    int n = n0 + wn + jj*16 + ocol;
                    size_t row = (size_t)(base + m);
                    float v = acc[i][jj][j];
                    if (EPI == 1) v += RG[row * (size_t)N + n];
                    if (EPI == 2) v = siluf(RG[row * (size_t)N + n]) * v;
                    C[row * (size_t)N + n] = v;
                }
            }
        }
    }
}

// ---------------- conv ----------------
__global__ __launch_bounds__(256) void conv_kernel(const float* __restrict__ xz,
    const float* __restrict__ cs, const float* __restrict__ cw,
    const float* __restrict__ cb, float* __restrict__ xcs)
{
    int idx = blockIdx.x*256 + threadIdx.x;
    int d = idx & (D_INNER-1);
    int bt = idx >> 11;
    int b = bt >> 11;
    int t = bt & (TT-1);
    float acc = cb[d];
    #pragma unroll
    for (int k = 0; k < 4; ++k){
        int tau = t + k - 3;
        float xv;
        if (tau >= 0) xv = xz[(size_t)(b*TT + tau)*(2*D_INNER) + d];
        else          xv = cs[((size_t)b*D_INNER + d)*3 + (tau + 3)];
        acc += cw[d*4 + k] * xv;
    }
    xcs[idx] = siluf(acc);
}

// ---------------- chunked SSM scan ----------------
__global__ __launch_bounds__(256) void scan_pass1(const float* __restrict__ dtp,
    const float* __restrict__ proj, const float* __restrict__ xcs,
    const float* __restrict__ A_log, float* __restrict__ hend,
    float* __restrict__ sumdt)
{
    int c = blockIdx.x >> 8;                     // chunk
    int ch = ((blockIdx.x & 255) << 4) + (threadIdx.x >> 4);
    int s = threadIdx.x & 15;
    int b = ch >> 11, d = ch & (D_INNER-1);
    float As = -__expf(A_log[d*D_STATE + s]);
    float h = 0.f, sdt = 0.f;
    int t0 = c * CLEN, base = b * TT;
    for (int t = t0; t < t0 + CLEN; ++t){
        size_t bt = (size_t)(base + t);
        float dt = dtp[bt*D_INNER + d];
        float x  = xcs[bt*D_INNER + d];
        float Bv = proj[bt*96 + DT_RANK + s];
        h = __expf(dt*As)*h + dt*Bv*x;
        sdt += dt;
    }
    hend[((size_t)ch*NCHUNK + c)*D_STATE + s] = h;
    if (s == 0) sumdt[ch*NCHUNK + c] = sdt;
}

__global__ __launch_bounds__(256) void scan_combine(const float* __restrict__ hend,
    const float* __restrict__ sumdt, const float* __restrict__ A_log,
    const float* __restrict__ ssm0, float* __restrict__ hstart)
{
    int gid = blockIdx.x*256 + threadIdx.x;      // 65536
    int s = gid & 15;
    int ch = gid >> 4;
    int b = ch >> 11, d = ch & (D_INNER-1);
    float As = -__expf(A_log[d*D_STATE + s]);
    float h = ssm0[((size_t)b*D_INNER + d)*D_STATE + s];
    #pragma unroll
    for (int c = 0; c < NCHUNK; ++c){
        size_t idx = ((size_t)ch*NCHUNK + c)*D_STATE + s;
        hstart[idx] = h;
        h = hend[idx] + __expf(As * sumdt[ch*NCHUNK + c]) * h;
    }
}

__global__ __launch_bounds__(256) void scan_pass3(const float* __restrict__ dtp,
    const float* __restrict__ proj, const float* __restrict__ xcs,
    const float* __restrict__ xz, const float* __restrict__ A_log,
    const float* __restrict__ Dp, const float* __restrict__ hstart,
    float* __restrict__ ym)
{
    int c = blockIdx.x >> 8;
    int ch = ((blockIdx.x & 255) << 4) + (threadIdx.x >> 4);
    int s = threadIdx.x & 15;
    int b = ch >> 11, d = ch & (D_INNER-1);
    float As = -__expf(A_log[d*D_STATE + s]);
    float h = hstart[((size_t)ch*NCHUNK + c)*D_STATE + s];
    float Dd = Dp[d];
    int t0 = c*CLEN, base = b*TT;
    for (int t = t0; t < t0 + CLEN; ++t){
        size_t bt = (size_t)(base + t);
        float dt = dtp[bt*D_INNER + d];
        float x  = xcs[bt*D_INNER + d];
        float Bv = proj[bt*96 + DT_RANK + s];
        float Cv = proj[bt*96 + DT_RANK + D_STATE + s];
        h = __expf(dt*As)*h + dt*Bv*x;
        float p = h*Cv;
        p += __shfl_xor(p, 1, 16);
        p += __shfl_xor(p, 2, 16);
        p += __shfl_xor(p, 4, 16);
        p += __shfl_xor(p, 8, 16);
        if (s == 0){
            float z = xz[bt*(2*D_INNER) + D_INNER + d];
            ym[bt*D_INNER + d] = (p + Dd*x) * siluf(z);
        }
    }
}

// ---------------- router ----------------
__global__ __launch_bounds__(256) void router_kernel(const float* __restrict__ xn2,
    const float* __restrict__ rw, float* __restrict__ tw, int* __restrict__ ti,
    int* __restrict__ counts)
{
    int tok = blockIdx.x*4 + (threadIdx.x >> 6);
    int lane = threadIdx.x & 63;
    float p[N_EXP] = {};
    const float* xp = xn2 + (size_t)tok * DIM;
    for (int dd = lane; dd < DIM; dd += 64){
        float xv = xp[dd];
        #pragma unroll
        for (int e = 0; e < N_EXP; ++e) p[e] += xv * rw[e*DIM + dd];
    }
    #pragma unroll
    for (int e = 0; e < N_EXP; ++e){
        #pragma unroll
        for (int off = 32; off; off >>= 1) p[e] += __shfl_xor(p[e], off, 64);
    }
    if (lane == 0){
        float mx = p[0];
        #pragma unroll
        for (int e = 1; e < N_EXP; ++e) mx = fmaxf(mx, p[e]);
        float q[N_EXP]; float ssum = 0.f;
        #pragma unroll
        for (int e = 0; e < N_EXP; ++e){ q[e] = expf(p[e]-mx); ssum += q[e]; }
        int i0 = 0;
        #pragma unroll
        for (int e = 1; e < N_EXP; ++e) if (q[e] > q[i0]) i0 = e;
        int i1 = (i0 == 0) ? 1 : 0;
        #pragma unroll
        for (int e = 0; e < N_EXP; ++e) if (e != i0 && q[e] > q[i1]) i1 = e;
        float w0 = q[i0]/ssum, w1 = q[i1]/ssum;
        float sw = w0 + w1; w0 /= sw; w1 /= sw;
        tw[tok*2] = w0; tw[tok*2+1] = w1;
        ti[tok*2] = i0; ti[tok*2+1] = i1;
        atomicAdd(&counts[i0], 1);
        atomicAdd(&counts[i1], 1);
    }
}

__global__ void offs_kernel(const int* __restrict__ counts, int* __restrict__ offs)
{
    if (threadIdx.x == 0 && blockIdx.x == 0){
        int s = 0;
        for (int e = 0; e < N_EXP; ++e){ offs[e] = s; s += counts[e]; }
    }
}

__global__ __launch_bounds__(256) void assign_kernel(const int* __restrict__ ti,
    const int* __restrict__ offs, int* __restrict__ cursors,
    int* __restrict__ tok_of_slot, int* __restrict__ slot_of)
{
    int t = blockIdx.x*256 + threadIdx.x;
    if (t >= NTOK) return;
    #pragma unroll
    for (int k = 0; k < TOP_K; ++k){
        int e = ti[t*2 + k];
        int pos = atomicAdd(&cursors[e], 1);
        int slot = offs[e] + pos;
        tok_of_slot[slot] = t;
        slot_of[t*2 + k] = slot;
    }
}

// ---------------- final combine ----------------
__global__ __launch_bounds__(256) void final_kernel(const float* __restrict__ x1,
    const float* __restrict__ down_out, const float* __restrict__ tw,
    const int* __restrict__ slot_of, float* __restrict__ out)
{
    int idx4 = blockIdx.x*256 + threadIdx.x;
    int t = idx4 >> 8;
    int c = idx4 & 255;
    float w0 = tw[t*2], w1 = tw[t*2+1];
    size_t s0 = (size_t)slot_of[t*2] * DIM;
    size_t s1 = (size_t)slot_of[t*2+1] * DIM;
    float4 a = *(const float4*)(x1 + (size_t)t*DIM + c*4);
    float4 d0 = *(const float4*)(down_out + s0 + c*4);
    float4 d1 = *(const float4*)(down_out + s1 + c*4);
    float4 r;
    r.x = a.x + w0*d0.x + w1*d1.x;
    r.y = a.y + w0*d0.y + w1*d1.y;
    r.z = a.z + w0*d0.z + w1*d1.z;
    r.w = a.w + w0*d0.w + w1*d1.w;
    *(float4*)(out + (size_t)t*DIM + c*4) = r;
}

extern "C" void kernel_launch(void* const* d_in, const int* in_sizes, int n_in,
                              void* d_out, int out_size, void* d_ws, size_t ws_size,
                              hipStream_t stream)
{
    const float* x        = (const float*)d_in[0];
    const float* ssm0     = (const float*)d_in[1];
    const float* conv0    = (const float*)d_in[2];
    const float* ln1_s    = (const float*)d_in[3];
    const float* ln1_b    = (const float*)d_in[4];
    const float* ln2_s    = (const float*)d_in[5];
    const float* ln2_b    = (const float*)d_in[6];
    const float* in_proj  = (const float*)d_in[7];
    const float* conv_w   = (const float*)d_in[8];
    const float* conv_b   = (const float*)d_in[9];
    const float* x_proj   = (const float*)d_in[10];
    const float* dt_proj  = (const float*)d_in[11];
    const float* dt_b     = (const float*)d_in[12];
    const float* A_log    = (const float*)d_in[13];
    const float* Dp       = (const float*)d_in[14];
    const float* out_proj = (const float*)d_in[15];
    const float* router_w = (const float*)d_in[16];
    const float* w_gate   = (const float*)d_in[17];
    const float* w_up     = (const float*)d_in[18];
    const float* w_down   = (const float*)d_in[19];
    float* out = (float*)d_out;

    float* ws = (float*)d_ws;
    float* xn    = ws + OFF_XN;
    float* xz    = ws + OFF_XZ;
    float* xcs   = ws + OFF_XCS;
    float* dtp   = ws + OFF_DTP;
    float* ym    = ws + OFF_YM;
    float* x1    = ws + OFF_X1;
    float* proj  = ws + OFF_PROJ;
    float* tw    = ws + OFF_TW;
    float* hend  = ws + OFF_HEND;
    float* hst   = ws + OFF_HST;
    float* sdt   = ws + OFF_SDT;
    int*   ip    = (int*)(ws + OFF_INT);
    int* ti          = ip + IO_TI;
    int* counts      = ip + IO_CNT;
    int* cursors     = ip + IO_CUR;
    int* offs        = ip + IO_OFS;
    int* tok_of_slot = ip + IO_TOK;
    int* slot_of     = ip + IO_SLOT;
    // region reuse
    float* xn2      = xn;     // after scan scratch is dead
    float* G        = xz;     // 8192*2048 fp32 = 64MB (xz dead after scan)
    float* H        = xcs;    // spans xcs+dtp = 64MB (both dead after scan)
    float* down_out = ym;     // 8192*1024 fp32 = 32MB (ym dead after out_proj)

    hipMemsetAsync(counts, 0, 16*sizeof(int), stream);

    // 1. xn = LN1(x)
    ln_kernel<<<NTOK, 256, 0, stream>>>(x, ln1_s, ln1_b, xn);
    // 2. xz = xn @ in_proj^T  (bf16 MFMA)  M=4096 N=4096 K=1024
    mfma_gemm<0,0><<<dim3(32,32), 256, 0, stream>>>(xn, in_proj, nullptr, xz,
        nullptr, nullptr, nullptr, NTOK, 2*D_INNER, DIM, DIM);
    // 3. conv + silu
    conv_kernel<<<(NTOK*D_INNER)/256, 256, 0, stream>>>(xz, conv0, conv_w, conv_b, xcs);
    // 4. proj = xcs @ x_proj^T  (fp32, N=96)
    gemm_nt<0><<<dim3(2,64), 256, 0, stream>>>(xcs, x_proj, nullptr, nullptr, proj,
        NTOK, 96, D_INNER, D_INNER, D_INNER, 96);
    // 5. dtp = softplus(proj[:,:64] @ dt_proj^T + dt_b)  (fp32, K=64)
    gemm_nt<1><<<dim3(32,64), 256, 0, stream>>>(proj, dt_proj, dt_b, nullptr, dtp,
        NTOK, D_INNER, DT_RANK, 96, DT_RANK, D_INNER);
    // 6. chunked scan
    scan_pass1<<<256*NCHUNK, 256, 0, stream>>>(dtp, proj, xcs, A_log, hend, sdt);
    scan_combine<<<256, 256, 0, stream>>>(hend, sdt, A_log, ssm0, hst);
    scan_pass3<<<256*NCHUNK, 256, 0, stream>>>(dtp, proj, xcs, xz, A_log, Dp, hst, ym);
    // 7. x1 = x + ym @ out_proj^T  (bf16 MFMA, resid)  M=4096 N=1024 K=2048
    mfma_gemm<0,1><<<dim3(8,32), 256, 0, stream>>>(ym, out_proj, x, x1,
        nullptr, nullptr, nullptr, NTOK, DIM, D_INNER, D_INNER);
    // 8. xn2 = LN2(x1)
    ln_kernel<<<NTOK, 256, 0, stream>>>(x1, ln2_s, ln2_b, xn2);
    // 9. router + slot assignment
    router_kernel<<<NTOK/4, 256, 0, stream>>>(xn2, router_w, tw, ti, counts);
    offs_kernel<<<1, 64, 0, stream>>>(counts, offs);
    assign_kernel<<<NTOK/256, 256, 0, stream>>>(ti, offs, cursors, tok_of_slot, slot_of);
    // 10. MoE: G = gather(xn2) @ Wg^T ; H = silu(G) * (gather(xn2) @ Wu^T) ; down
    mfma_gemm<1,0><<<dim3(HID/128, 64, N_EXP), 256, 0, stream>>>(xn2, w_gate, nullptr, G,
        tok_of_slot, counts, offs, NSLOT, HID, DIM, DIM);
    mfma_gemm<1,2><<<dim3(HID/128, 64, N_EXP), 256, 0, stream>>>(xn2, w_up, G, H,
        tok_of_slot, counts, offs, NSLOT, HID, DIM, DIM);
    mfma_gemm<2,0><<<dim3(DIM/128, 64, N_EXP), 256, 0, stream>>>(H, w_down, nullptr, down_out,
        tok_of_slot, counts, offs, NSLOT, DIM, HID, HID);
    // 11. out = x1 + weighted experts
    final_kernel<<<(NTOK*DIM/4)/256, 256, 0, stream>>>(x1, down_out, tw, slot_of, out);
}

// Round 3
// 924.149 us; speedup vs baseline: 4.1611x; 1.3431x over previous
//
#include <hip/hip_runtime.h>
#include <hip/hip_bf16.h>
#include <math.h>

#define DIM 1024
#define D_STATE 16
#define D_CONV 4
#define D_INNER 2048
#define DT_RANK 64
#define N_EXP 8
#define TOP_K 2
#define HID 2048
#define BB 2
#define TT 2048
#define NTOK (BB*TT)          // 4096
#define NSLOT (NTOK*TOP_K)    // 8192
#define EPS 1e-5f
#define NCHUNK 64
#define CLEN (TT/NCHUNK)      // 32

// ---------------- workspace layout (float units) ----------------
// R0: xn_bf16 (s1-2) -> hend (s6a-6b) -> ym_bf16 (s6c-7)
#define OFF_R0   ((size_t)0)          // 4.19M floats
// R1: hst (s6b-6c) -> xn2_f32 (s8-10)
#define OFF_R1   ((size_t)4194304)
// R2: sdt (s6a-6b) -> xn2_bf16 (s8-10)
#define OFF_R2   ((size_t)8388608)
// xz f32 (s2-6c) -> G bf16 @+0 (10a-10b), H bf16 @+8.39M (10b-10c)
#define OFF_XZ   ((size_t)10485760)   // 16.78M floats
#define OFF_G    ((size_t)10485760)
#define OFF_H    ((size_t)18874368)
// xcs f32 (3-6c) -> down_out f32 (10c-11)
#define OFF_XCS  ((size_t)27262976)   // 8.39M
#define OFF_DTP  ((size_t)35651584)   // 8.39M
#define OFF_X1   ((size_t)44040192)   // 4.19M
#define OFF_PROJ ((size_t)48234496)   // 393216
#define OFF_TW   ((size_t)48627712)   // 8192
#define OFF_INT  ((size_t)48635904)   // ints
// int offsets (ints)
#define IO_TI    0
#define IO_CNT   8192
#define IO_CUR   8200
#define IO_OFS   8208
#define IO_TOK   8216
#define IO_SLOT  16408

typedef __attribute__((ext_vector_type(4))) float f32x4;
typedef __attribute__((ext_vector_type(8))) __bf16 bf16x8;

__device__ __forceinline__ float siluf(float v){ return v / (1.f + expf(-v)); }

__device__ __forceinline__ f32x4 mfma16(bf16x8 a, bf16x8 b, f32x4 c){
    return __builtin_amdgcn_mfma_f32_16x16x32_bf16(a, b, c, 0, 0, 0);
}

__device__ __forceinline__ void cvt_store16(__bf16* dst, f32x4 a0, f32x4 a1, f32x4 a2, f32x4 a3){
    bf16x8 p0, p1;
    #pragma unroll
    for (int j = 0; j < 4; ++j){
        p0[j]   = (__bf16)a0[j];
        p0[j+4] = (__bf16)a1[j];
        p1[j]   = (__bf16)a2[j];
        p1[j+4] = (__bf16)a3[j];
    }
    *(bf16x8*)dst = p0;
    *(bf16x8*)(dst+8) = p1;
}

// ---------------- LayerNorm: bf16 out (+optional f32 out) ----------------
template<int BOTH>
__global__ __launch_bounds__(256) void ln_kernel(const float* __restrict__ x,
    const float* __restrict__ s, const float* __restrict__ b,
    __bf16* __restrict__ obf, float* __restrict__ of32)
{
    int t = blockIdx.x;
    const float* xp = x + (size_t)t * DIM;
    float v[4]; float sum = 0.f, sq = 0.f;
    #pragma unroll
    for (int j = 0; j < 4; ++j){
        v[j] = xp[threadIdx.x + 256*j];
        sum += v[j]; sq += v[j]*v[j];
    }
    #pragma unroll
    for (int off = 32; off; off >>= 1){
        sum += __shfl_xor(sum, off, 64);
        sq  += __shfl_xor(sq , off, 64);
    }
    __shared__ float red[4][2];
    int w = threadIdx.x >> 6, lane = threadIdx.x & 63;
    if (lane == 0){ red[w][0] = sum; red[w][1] = sq; }
    __syncthreads();
    sum = red[0][0]+red[1][0]+red[2][0]+red[3][0];
    sq  = red[0][1]+red[1][1]+red[2][1]+red[3][1];
    float mu = sum * (1.f/DIM);
    float var = sq * (1.f/DIM) - mu*mu;
    float r = rsqrtf(var + EPS);
    #pragma unroll
    for (int j = 0; j < 4; ++j){
        int d = threadIdx.x + 256*j;
        float o = (v[j]-mu)*r*s[d] + b[d];
        obf[(size_t)t*DIM + d] = (__bf16)o;
        if (BOTH) of32[(size_t)t*DIM + d] = o;
    }
}

// ---------------- bf16 MFMA GEMM: C[m,n] = epi(sum_k A[m,k] W[n,k]) ----------------
// MODE: 0 dense, 1 gather A via tok_of_slot, 2 contiguous slot rows
// EPI : 0 none, 1 +resid f32[row*N+n], 2 silu(Gbf[row*N+n])*acc, 3 softplus(acc + bias[n])
// ADT : 0 A fp32 (cvt-stage), 1 A bf16
// CBF : 0 C fp32, 1 C bf16
// SWZ : XCD-aware block swizzle (dense only)
template<int MODE, int EPI, int ADT, int CBF, int SWZ>
__global__ __launch_bounds__(256,2) void mfma_gemm(
    const void* __restrict__ Av, const float* __restrict__ W,
    const void* __restrict__ RG, void* __restrict__ Cv,
    const int* __restrict__ tok_of_slot, const int* __restrict__ counts,
    const int* __restrict__ offs, int M, int N, int K, int lda)
{
    int bx = blockIdx.x, by = blockIdx.y;
    if (SWZ){
        int nwg = gridDim.x*gridDim.y;
        int id = by*gridDim.x + bx;
        int swz = (id & 7)*(nwg >> 3) + (id >> 3);
        bx = swz % gridDim.x; by = swz / gridDim.x;
    }
    int e    = (MODE == 0) ? 0 : blockIdx.z;
    int cnt  = (MODE == 0) ? M : counts[e];
    int base = (MODE == 0) ? 0 : offs[e];
    int m0 = by * 128;
    if (m0 >= cnt) return;
    int n0 = bx * 128;
    const float* We = W + (size_t)e * N * K;

    __shared__ __bf16 As[128*32];
    __shared__ __bf16 Ws[128*32];

    int tid = threadIdx.x;
    int srow = tid >> 1;
    int scol = (tid & 1) * 16;

    int am = m0 + srow;
    int amc = (am < cnt) ? am : (cnt - 1);
    int arow;
    if (MODE == 1)      arow = tok_of_slot[base + amc];
    else if (MODE == 2) arow = base + amc;
    else                arow = amc;
    const __bf16* abf = (const __bf16*)Av + (size_t)arow * lda + scol;
    const float*  af  = (const float* )Av + (size_t)arow * lda + scol;
    int wrow = n0 + srow; if (wrow >= N) wrow = N - 1;
    const float* wptr = We + (size_t)wrow * K + scol;

    bf16x8 ra0, ra1;
    f32x4 raf[4], rw[4];
    if (ADT){
        ra0 = *(const bf16x8*)abf;
        ra1 = *(const bf16x8*)(abf + 8);
    } else {
        #pragma unroll
        for (int q = 0; q < 4; ++q) raf[q] = *(const f32x4*)(af + q*4);
    }
    #pragma unroll
    for (int q = 0; q < 4; ++q) rw[q] = *(const f32x4*)(wptr + q*4);

    int wave = tid >> 6, lane = tid & 63;
    int wm = (wave >> 1) * 64, wn = (wave & 1) * 64;
    int fr = lane & 15, fk = (lane >> 4) * 8;

    f32x4 acc[4][4];
    #pragma unroll
    for (int i = 0; i < 4; ++i)
        #pragma unroll
        for (int j = 0; j < 4; ++j)
            acc[i][j] = (f32x4){0.f, 0.f, 0.f, 0.f};

    for (int k0 = 0; k0 < K; k0 += 32){
        if (ADT){
            *(bf16x8*)&As[srow*32 + scol]     = ra0;
            *(bf16x8*)&As[srow*32 + scol + 8] = ra1;
        } else {
            cvt_store16(&As[srow*32 + scol], raf[0], raf[1], raf[2], raf[3]);
        }
        cvt_store16(&Ws[srow*32 + scol], rw[0], rw[1], rw[2], rw[3]);
        __syncthreads();
        if (k0 + 32 < K){
            if (ADT){
                ra0 = *(const bf16x8*)(abf + k0 + 32);
                ra1 = *(const bf16x8*)(abf + k0 + 40);
            } else {
                #pragma unroll
                for (int q = 0; q < 4; ++q) raf[q] = *(const f32x4*)(af + k0 + 32 + q*4);
            }
            #pragma unroll
            for (int q = 0; q < 4; ++q) rw[q] = *(const f32x4*)(wptr + k0 + 32 + q*4);
        }
        bf16x8 afr[4], bfr[4];
        #pragma unroll
        for (int i = 0; i < 4; ++i)
            afr[i] = *(const bf16x8*)&As[(wm + i*16 + fr)*32 + fk];
        #pragma unroll
        for (int i = 0; i < 4; ++i)
            bfr[i] = *(const bf16x8*)&Ws[(wn + i*16 + fr)*32 + fk];
        #pragma unroll
        for (int i = 0; i < 4; ++i)
            #pragma unroll
            for (int j = 0; j < 4; ++j)
                acc[i][j] = mfma16(afr[i], bfr[j], acc[i][j]);
        __syncthreads();
    }

    int orow = (lane >> 4) * 4;
    int ocol = lane & 15;
    #pragma unroll
    for (int i = 0; i < 4; ++i){
        #pragma unroll
        for (int jj = 0; jj < 4; ++jj){
            #pragma unroll
            for (int j = 0; j < 4; ++j){
                int m = m0 + wm + i*16 + orow + j;
                int n = n0 + wn + jj*16 + ocol;
                if (m < cnt && n < N){
                    size_t row = (size_t)(base + m);
                    float v = acc[i][jj][j];
                    if (EPI == 1) v += ((const float*)RG)[row * (size_t)N + n];
                    if (EPI == 2){
                        float g = (float)((const __bf16*)RG)[row * (size_t)N + n];
                        v = siluf(g) * v;
                    }
                    if (EPI == 3){
                        v += ((const float*)RG)[n];
                        v = (v > 20.f) ? v : log1pf(expf(v));
                    }
                    if (CBF) ((__bf16*)Cv)[row * (size_t)N + n] = (__bf16)v;
                    else     ((float* )Cv)[row * (size_t)N + n] = v;
                }
            }
        }
    }
}

// ---------------- conv ----------------
__global__ __launch_bounds__(256) void conv_kernel(const float* __restrict__ xz,
    const float* __restrict__ cs, const float* __restrict__ cw,
    const float* __restrict__ cb, float* __restrict__ xcs)
{
    int idx = blockIdx.x*256 + threadIdx.x;
    int d = idx & (D_INNER-1);
    int bt = idx >> 11;
    int b = bt >> 11;
    int t = bt & (TT-1);
    float acc = cb[d];
    #pragma unroll
    for (int k = 0; k < 4; ++k){
        int tau = t + k - 3;
        float xv;
        if (tau >= 0) xv = xz[(size_t)(b*TT + tau)*(2*D_INNER) + d];
        else          xv = cs[((size_t)b*D_INNER + d)*3 + (tau + 3)];
        acc += cw[d*4 + k] * xv;
    }
    xcs[idx] = siluf(acc);
}

// ---------------- chunked SSM scan: one lane per (b,d,chunk) ----------------
__global__ __launch_bounds__(256) void scan_pass1(const float* __restrict__ dtp,
    const float* __restrict__ proj, const float* __restrict__ xcs,
    const float* __restrict__ A_log, float* __restrict__ hend,
    float* __restrict__ sumdt)
{
    int gid = blockIdx.x*256 + threadIdx.x;          // 262144
    int bd = gid & (BB*D_INNER-1);
    int chunk = gid >> 12;
    int b = bd >> 11, d = bd & (D_INNER-1);
    float As[D_STATE], h[D_STATE];
    #pragma unroll
    for (int s = 0; s < D_STATE; ++s){
        As[s] = -__expf(A_log[d*D_STATE + s]);
        h[s] = 0.f;
    }
    float sdt = 0.f;
    int base = b*TT + chunk*CLEN;
    for (int t = 0; t < CLEN; ++t){
        size_t bt = (size_t)(base + t);
        float dt = dtp[bt*D_INNER + d];
        float x  = xcs[bt*D_INNER + d];
        f32x4 Bv[4];
        #pragma unroll
        for (int q = 0; q < 4; ++q) Bv[q] = *(const f32x4*)(proj + bt*96 + DT_RANK + q*4);
        float dtx = dt * x;
        sdt += dt;
        #pragma unroll
        for (int s = 0; s < D_STATE; ++s)
            h[s] = __expf(dt*As[s])*h[s] + Bv[s>>2][s&3]*dtx;
    }
    size_t hb = ((size_t)bd*NCHUNK + chunk)*D_STATE;
    #pragma unroll
    for (int q = 0; q < 4; ++q)
        *(f32x4*)(hend + hb + q*4) = (f32x4){h[q*4], h[q*4+1], h[q*4+2], h[q*4+3]};
    sumdt[bd*NCHUNK + chunk] = sdt;
}

__global__ __launch_bounds__(256) void scan_combine(const float* __restrict__ hend,
    const float* __restrict__ sumdt, const float* __restrict__ A_log,
    const float* __restrict__ ssm0, float* __restrict__ hstart)
{
    int gid = blockIdx.x*256 + threadIdx.x;          // 65536
    int s = gid & 15;
    int bd = gid >> 4;
    int b = bd >> 11, d = bd & (D_INNER-1);
    float As = -__expf(A_log[d*D_STATE + s]);
    float h = ssm0[((size_t)b*D_INNER + d)*D_STATE + s];
    for (int c = 0; c < NCHUNK; ++c){
        size_t idx = ((size_t)bd*NCHUNK + c)*D_STATE + s;
        hstart[idx] = h;
        h = hend[idx] + __expf(As * sumdt[bd*NCHUNK + c]) * h;
    }
}

__global__ __launch_bounds__(256) void scan_pass3(const float* __restrict__ dtp,
    const float* __restrict__ proj, const float* __restrict__ xcs,
    const float* __restrict__ xz, const float* __restrict__ A_log,
    const float* __restrict__ Dp, const float* __restrict__ hstart,
    __bf16* __restrict__ ym)
{
    int gid = blockIdx.x*256 + threadIdx.x;          // 262144
    int bd = gid & (BB*D_INNER-1);
    int chunk = gid >> 12;
    int b = bd >> 11, d = bd & (D_INNER-1);
    float As[D_STATE], h[D_STATE];
    #pragma unroll
    for (int s = 0; s < D_STATE; ++s)
        As[s] = -__expf(A_log[d*D_STATE + s]);
    size_t hb = ((size_t)bd*NCHUNK + chunk)*D_STATE;
    #pragma unroll
    for (int q = 0; q < 4; ++q){
        f32x4 hv = *(const f32x4*)(hstart + hb + q*4);
        h[q*4] = hv[0]; h[q*4+1] = hv[1]; h[q*4+2] = hv[2]; h[q*4+3] = hv[3];
    }
    float Dd = Dp[d];
    int base = b*TT + chunk*CLEN;
    for (int t = 0; t < CLEN; ++t){
        size_t bt = (size_t)(base + t);
        float dt = dtp[bt*D_INNER + d];
        float x  = xcs[bt*D_INNER + d];
        f32x4 Bv[4], Cv[4];
        #pragma unroll
        for (int q = 0; q < 4; ++q){
            Bv[q] = *(const f32x4*)(proj + bt*96 + DT_RANK + q*4);
            Cv[q] = *(const f32x4*)(proj + bt*96 + DT_RANK + D_STATE + q*4);
        }
        float dtx = dt * x;
        float p = 0.f;
        #pragma unroll
        for (int s = 0; s < D_STATE; ++s){
            h[s] = __expf(dt*As[s])*h[s] + Bv[s>>2][s&3]*dtx;
            p += h[s] * Cv[s>>2][s&3];
        }
        float y = p + Dd*x;
        float z = xz[bt*(2*D_INNER) + D_INNER + d];
        float sz = z / (1.f + __expf(-z));
        ym[bt*D_INNER + d] = (__bf16)(y * sz);
    }
}

// ---------------- router ----------------
__global__ __launch_bounds__(256) void router_kernel(const float* __restrict__ xn2,
    const float* __restrict__ rw, float* __restrict__ tw, int* __restrict__ ti,
    int* __restrict__ counts)
{
    int tok = blockIdx.x*4 + (threadIdx.x >> 6);
    int lane = threadIdx.x & 63;
    float p[N_EXP] = {};
    const float* xp = xn2 + (size_t)tok * DIM;
    for (int dd = lane; dd < DIM; dd += 64){
        float xv = xp[dd];
        #pragma unroll
        for (int e = 0; e < N_EXP; ++e) p[e] += xv * rw[e*DIM + dd];
    }
    #pragma unroll
    for (int e = 0; e < N_EXP; ++e){
        #pragma unroll
        for (int off = 32; off; off >>= 1) p[e] += __shfl_xor(p[e], off, 64);
    }
    if (lane == 0){
        float mx = p[0];
        #pragma unroll
        for (int e = 1; e < N_EXP; ++e) mx = fmaxf(mx, p[e]);
        float q[N_EXP]; float ssum = 0.f;
        #pragma unroll
        for (int e = 0; e < N_EXP; ++e){ q[e] = expf(p[e]-mx); ssum += q[e]; }
        int i0 = 0;
        #pragma unroll
        for (int e = 1; e < N_EXP; ++e) if (q[e] > q[i0]) i0 = e;
        int i1 = (i0 == 0) ? 1 : 0;
        #pragma unroll
        for (int e = 0; e < N_EXP; ++e) if (e != i0 && q[e] > q[i1]) i1 = e;
        float w0 = q[i0]/ssum, w1 = q[i1]/ssum;
        float sw = w0 + w1; w0 /= sw; w1 /= sw;
        tw[tok*2] = w0; tw[tok*2+1] = w1;
        ti[tok*2] = i0; ti[tok*2+1] = i1;
        atomicAdd(&counts[i0], 1);
        atomicAdd(&counts[i1], 1);
    }
}

__global__ void offs_kernel(const int* __restrict__ counts, int* __restrict__ offs)
{
    if (threadIdx.x == 0 && blockIdx.x == 0){
        int s = 0;
        for (int e = 0; e < N_EXP; ++e){ offs[e] = s; s += counts[e]; }
    }
}

__global__ __launch_bounds__(256) void assign_kernel(const int* __restrict__ ti,
    const int* __restrict__ offs, int* __restrict__ cursors,
    int* __restrict__ tok_of_slot, int* __restrict__ slot_of)
{
    int t = blockIdx.x*256 + threadIdx.x;
    if (t >= NTOK) return;
    #pragma unroll
    for (int k = 0; k < TOP_K; ++k){
        int e = ti[t*2 + k];
        int pos = atomicAdd(&cursors[e], 1);
        int slot = offs[e] + pos;
        tok_of_slot[slot] = t;
        slot_of[t*2 + k] = slot;
    }
}

// ---------------- final combine ----------------
__global__ __launch_bounds__(256) void final_kernel(const float* __restrict__ x1,
    const float* __restrict__ down_out, const float* __restrict__ tw,
    const int* __restrict__ slot_of, float* __restrict__ out)
{
    int idx4 = blockIdx.x*256 + threadIdx.x;
    int t = idx4 >> 8;
    int c = idx4 & 255;
    float w0 = tw[t*2], w1 = tw[t*2+1];
    size_t s0 = (size_t)slot_of[t*2] * DIM;
    size_t s1 = (size_t)slot_of[t*2+1] * DIM;
    float4 a = *(const float4*)(x1 + (size_t)t*DIM + c*4);
    float4 d0 = *(const float4*)(down_out + s0 + c*4);
    float4 d1 = *(const float4*)(down_out + s1 + c*4);
    float4 r;
    r.x = a.x + w0*d0.x + w1*d1.x;
    r.y = a.y + w0*d0.y + w1*d1.y;
    r.z = a.z + w0*d0.z + w1*d1.z;
    r.w = a.w + w0*d0.w + w1*d1.w;
    *(float4*)(out + (size_t)t*DIM + c*4) = r;
}

extern "C" void kernel_launch(void* const* d_in, const int* in_sizes, int n_in,
                              void* d_out, int out_size, void* d_ws, size_t ws_size,
                              hipStream_t stream)
{
    const float* x        = (const float*)d_in[0];
    const float* ssm0     = (const float*)d_in[1];
    const float* conv0    = (const float*)d_in[2];
    const float* ln1_s    = (const float*)d_in[3];
    const float* ln1_b    = (const float*)d_in[4];
    const float* ln2_s    = (const float*)d_in[5];
    const float* ln2_b    = (const float*)d_in[6];
    const float* in_proj  = (const float*)d_in[7];
    const float* conv_w   = (const float*)d_in[8];
    const float* conv_b   = (const float*)d_in[9];
    const float* x_proj   = (const float*)d_in[10];
    const float* dt_proj  = (const float*)d_in[11];
    const float* dt_b     = (const float*)d_in[12];
    const float* A_log    = (const float*)d_in[13];
    const float* Dp       = (const float*)d_in[14];
    const float* out_proj = (const float*)d_in[15];
    const float* router_w = (const float*)d_in[16];
    const float* w_gate   = (const float*)d_in[17];
    const float* w_up     = (const float*)d_in[18];
    const float* w_down   = (const float*)d_in[19];
    float* out = (float*)d_out;

    float* ws = (float*)d_ws;
    __bf16* xn_bf  = (__bf16*)(ws + OFF_R0);
    float*  hend   = ws + OFF_R0;
    __bf16* ym_bf  = (__bf16*)(ws + OFF_R0);
    float*  hst    = ws + OFF_R1;
    float*  xn2f   = ws + OFF_R1;
    float*  sdt    = ws + OFF_R2;
    __bf16* xn2bf  = (__bf16*)(ws + OFF_R2);
    float*  xz     = ws + OFF_XZ;
    __bf16* G      = (__bf16*)(ws + OFF_G);
    __bf16* H      = (__bf16*)(ws + OFF_H);
    float*  xcs    = ws + OFF_XCS;
    float*  dnout  = ws + OFF_XCS;
    float*  dtp    = ws + OFF_DTP;
    float*  x1     = ws + OFF_X1;
    float*  proj   = ws + OFF_PROJ;
    float*  tw     = ws + OFF_TW;
    int*    ip     = (int*)(ws + OFF_INT);
    int* ti          = ip + IO_TI;
    int* counts      = ip + IO_CNT;
    int* cursors     = ip + IO_CUR;
    int* offs        = ip + IO_OFS;
    int* tok_of_slot = ip + IO_TOK;
    int* slot_of     = ip + IO_SLOT;

    hipMemsetAsync(counts, 0, 16*sizeof(int), stream);

    // 1. xn_bf = LN1(x)
    ln_kernel<0><<<NTOK, 256, 0, stream>>>(x, ln1_s, ln1_b, xn_bf, nullptr);
    // 2. xz = xn @ in_proj^T  (bf16 A)
    mfma_gemm<0,0,1,0,1><<<dim3(32,32), 256, 0, stream>>>(xn_bf, in_proj, nullptr, xz,
        nullptr, nullptr, nullptr, NTOK, 2*D_INNER, DIM, DIM);
    // 3. conv + silu -> xcs (f32)
    conv_kernel<<<(NTOK*D_INNER)/256, 256, 0, stream>>>(xz, conv0, conv_w, conv_b, xcs);
    // 4. proj = xcs @ x_proj^T  (fp32 A cvt, N=96)
    mfma_gemm<0,0,0,0,0><<<dim3(1,32), 256, 0, stream>>>(xcs, x_proj, nullptr, proj,
        nullptr, nullptr, nullptr, NTOK, 96, D_INNER, D_INNER);
    // 5. dtp = softplus(proj[:,:64] @ dt_proj^T + dt_b)  (fp32 A, lda=96, K=64)
    mfma_gemm<0,3,0,0,0><<<dim3(16,32), 256, 0, stream>>>(proj, dt_proj, dt_b, dtp,
        nullptr, nullptr, nullptr, NTOK, D_INNER, DT_RANK, 96);
    // 6. chunked scan (lane-per-channel)
    scan_pass1<<<1024, 256, 0, stream>>>(dtp, proj, xcs, A_log, hend, sdt);
    scan_combine<<<256, 256, 0, stream>>>(hend, sdt, A_log, ssm0, hst);
    scan_pass3<<<1024, 256, 0, stream>>>(dtp, proj, xcs, xz, A_log, Dp, hst, ym_bf);
    // 7. x1 = x + ym @ out_proj^T
    mfma_gemm<0,1,1,0,1><<<dim3(8,32), 256, 0, stream>>>(ym_bf, out_proj, x, x1,
        nullptr, nullptr, nullptr, NTOK, DIM, D_INNER, D_INNER);
    // 8. xn2 = LN2(x1): f32 for router + bf16 for MoE
    ln_kernel<1><<<NTOK, 256, 0, stream>>>(x1, ln2_s, ln2_b, xn2bf, xn2f);
    // 9. router + slot assignment
    router_kernel<<<NTOK/4, 256, 0, stream>>>(xn2f, router_w, tw, ti, counts);
    offs_kernel<<<1, 64, 0, stream>>>(counts, offs);
    assign_kernel<<<NTOK/256, 256, 0, stream>>>(ti, offs, cursors, tok_of_slot, slot_of);
    // 10. MoE
    mfma_gemm<1,0,1,1,0><<<dim3(HID/128, 64, N_EXP), 256, 0, stream>>>(xn2bf, w_gate, nullptr, G,
        tok_of_slot, counts, offs, NSLOT, HID, DIM, DIM);
    mfma_gemm<1,2,1,1,0><<<dim3(HID/128, 64, N_EXP), 256, 0, stream>>>(xn2bf, w_up, G, H,
        tok_of_slot, counts, offs, NSLOT, HID, DIM, DIM);
    mfma_gemm<2,0,1,0,0><<<dim3(DIM/128, 64, N_EXP), 256, 0, stream>>>(H, w_down, nullptr, dnout,
        tok_of_slot, counts, offs, NSLOT, DIM, HID, HID);
    // 11. out = x1 + weighted experts
    final_kernel<<<(NTOK*DIM/4)/256, 256, 0, stream>>>(x1, dnout, tw, slot_of, out);
}

// Round 4
// 841.292 us; speedup vs baseline: 4.5709x; 1.0985x over previous
//
#include <hip/hip_runtime.h>
#include <hip/hip_bf16.h>
#include <math.h>

#define DIM 1024
#define D_STATE 16
#define D_CONV 4
#define D_INNER 2048
#define DT_RANK 64
#define N_EXP 8
#define TOP_K 2
#define HID 2048
#define BB 2
#define TT 2048
#define NTOK (BB*TT)          // 4096
#define NSLOT (NTOK*TOP_K)    // 8192
#define EPS 1e-5f
#define NCHUNK 64
#define CLEN (TT/NCHUNK)      // 32

// ---------------- workspace layout (float units) ----------------
// R0: xn_bf16 (s1-2) -> hend (s6a-6b) -> ym_bf16 (s6c-7)
#define OFF_R0   ((size_t)0)          // 4.19M floats
// R1: hst (s6b-6c) -> xn2_f32 (s8-10)
#define OFF_R1   ((size_t)4194304)
// R2: sdt (s6a-6b) -> out_proj_bf16 (s7) -> xn2_bf16 (s8-10)
#define OFF_R2   ((size_t)8388608)
// xz f32 (s2-6c) -> G bf16 @+0 (10a-10b), H bf16 @+8.39M (10b-10c)
#define OFF_XZ   ((size_t)10485760)   // 16.78M floats
#define OFF_G    ((size_t)10485760)
#define OFF_H    ((size_t)18874368)
// xcs f32 (3-6c) -> down_out f32 (10c-11)
#define OFF_XCS  ((size_t)27262976)   // 8.39M
// DTP: in_proj_bf16 (s2) -> dtp f32 (s5-6c) -> MoE weight bf16 staging (s10)
#define OFF_DTP  ((size_t)35651584)   // 8.39M
#define OFF_X1   ((size_t)44040192)   // 4.19M
#define OFF_PROJ ((size_t)48234496)   // 393216
#define OFF_TW   ((size_t)48627712)   // 8192
#define OFF_INT  ((size_t)48635904)   // ints
// int offsets (ints)
#define IO_TI    0
#define IO_CNT   8192
#define IO_CUR   8200
#define IO_OFS   8208
#define IO_TOK   8216
#define IO_SLOT  16408

typedef __attribute__((ext_vector_type(4))) float f32x4;
typedef __attribute__((ext_vector_type(8))) __bf16 bf16x8;
typedef __attribute__((ext_vector_type(4))) __bf16 bf16x4;

__device__ __forceinline__ float siluf(float v){ return v / (1.f + expf(-v)); }

__device__ __forceinline__ f32x4 mfma16(bf16x8 a, bf16x8 b, f32x4 c){
    return __builtin_amdgcn_mfma_f32_16x16x32_bf16(a, b, c, 0, 0, 0);
}

__device__ __forceinline__ void gload16(const void* g, void* l){
    __builtin_amdgcn_global_load_lds(
        (const __attribute__((address_space(1))) unsigned int*)g,
        (__attribute__((address_space(3))) unsigned int*)l, 16, 0, 0);
}

__device__ __forceinline__ void cvt_store16(__bf16* dst, f32x4 a0, f32x4 a1, f32x4 a2, f32x4 a3){
    bf16x8 p0, p1;
    #pragma unroll
    for (int j = 0; j < 4; ++j){
        p0[j]   = (__bf16)a0[j];
        p0[j+4] = (__bf16)a1[j];
        p1[j]   = (__bf16)a2[j];
        p1[j+4] = (__bf16)a3[j];
    }
    *(bf16x8*)dst = p0;
    *(bf16x8*)(dst+8) = p1;
}

// ---------------- weight f32 -> bf16 convert ----------------
__global__ __launch_bounds__(256) void cvt_w_kernel(const float* __restrict__ src,
    __bf16* __restrict__ dst, int n4)
{
    int i = blockIdx.x*256 + threadIdx.x;
    int stride = gridDim.x*256;
    for (; i < n4; i += stride){
        f32x4 v = *(const f32x4*)(src + (size_t)i*4);
        bf16x4 o;
        o[0] = (__bf16)v[0]; o[1] = (__bf16)v[1];
        o[2] = (__bf16)v[2]; o[3] = (__bf16)v[3];
        *(bf16x4*)(dst + (size_t)i*4) = o;
    }
}

// ---------------- LayerNorm: bf16 out (+optional f32 out) ----------------
template<int BOTH>
__global__ __launch_bounds__(256) void ln_kernel(const float* __restrict__ x,
    const float* __restrict__ s, const float* __restrict__ b,
    __bf16* __restrict__ obf, float* __restrict__ of32)
{
    int t = blockIdx.x;
    const float* xp = x + (size_t)t * DIM;
    float v[4]; float sum = 0.f, sq = 0.f;
    #pragma unroll
    for (int j = 0; j < 4; ++j){
        v[j] = xp[threadIdx.x + 256*j];
        sum += v[j]; sq += v[j]*v[j];
    }
    #pragma unroll
    for (int off = 32; off; off >>= 1){
        sum += __shfl_xor(sum, off, 64);
        sq  += __shfl_xor(sq , off, 64);
    }
    __shared__ float red[4][2];
    int w = threadIdx.x >> 6, lane = threadIdx.x & 63;
    if (lane == 0){ red[w][0] = sum; red[w][1] = sq; }
    __syncthreads();
    sum = red[0][0]+red[1][0]+red[2][0]+red[3][0];
    sq  = red[0][1]+red[1][1]+red[2][1]+red[3][1];
    float mu = sum * (1.f/DIM);
    float var = sq * (1.f/DIM) - mu*mu;
    float r = rsqrtf(var + EPS);
    #pragma unroll
    for (int j = 0; j < 4; ++j){
        int d = threadIdx.x + 256*j;
        float o = (v[j]-mu)*r*s[d] + b[d];
        obf[(size_t)t*DIM + d] = (__bf16)o;
        if (BOTH) of32[(size_t)t*DIM + d] = o;
    }
}

// ---------------- fast bf16 MFMA GEMM with global_load_lds ----------------
// C[m,n] = epi(sum_k A[m,k] W[n,k]); A,W bf16; N multiple of 128
// MODE: 0 dense, 1 gather A via tok_of_slot, 2 contiguous slot rows
// EPI : 0 none, 1 +resid f32[row*N+n], 2 silu(Gbf[row*N+n])*acc
// CBF : 0 C fp32, 1 C bf16
// SWZ : XCD swizzle (dense; nwg%8==0)
template<int MODE, int EPI, int CBF, int SWZ>
__global__ __launch_bounds__(256,3) void mfma_gemm_fast(
    const __bf16* __restrict__ A, const __bf16* __restrict__ W,
    const void* __restrict__ RG, void* __restrict__ Cv,
    const int* __restrict__ tok_of_slot, const int* __restrict__ counts,
    const int* __restrict__ offs, int M, int N, int K, int lda)
{
    int bx = blockIdx.x, by = blockIdx.y;
    if (SWZ){
        int nwg = gridDim.x*gridDim.y;
        int id = by*gridDim.x + bx;
        int swz = (id & 7)*(nwg >> 3) + (id >> 3);
        bx = swz % gridDim.x; by = swz / gridDim.x;
    }
    int e    = (MODE == 0) ? 0 : blockIdx.z;
    int cnt  = (MODE == 0) ? M : counts[e];
    int base = (MODE == 0) ? 0 : offs[e];
    int m0 = by * 128;
    if (m0 >= cnt) return;
    int n0 = bx * 128;
    const __bf16* We = W + (size_t)e * N * K;

    __shared__ __bf16 As[128*32];
    __shared__ __bf16 Ws[128*32];

    int tid = threadIdx.x;
    int wave = tid >> 6, lane = tid & 63;
    // load slots: wave w stages 16-row chunks {2w, 2w+1} of A and W
    int c0 = wave*2, c1 = wave*2 + 1;
    int lr0 = c0*16 + (lane >> 2);
    int lr1 = c1*16 + (lane >> 2);
    int koff = (lane & 3) * 8;

    int ar0, ar1;
    {
        int m0c = m0 + lr0, m1c = m0 + lr1;
        if (MODE != 0){
            if (m0c >= cnt) m0c = cnt - 1;
            if (m1c >= cnt) m1c = cnt - 1;
        }
        if (MODE == 1){ ar0 = tok_of_slot[base + m0c]; ar1 = tok_of_slot[base + m1c]; }
        else if (MODE == 2){ ar0 = base + m0c; ar1 = base + m1c; }
        else { ar0 = m0c; ar1 = m1c; }
    }
    const __bf16* aS0 = A + (size_t)ar0 * lda + koff;
    const __bf16* aS1 = A + (size_t)ar1 * lda + koff;
    const __bf16* wS0 = We + (size_t)(n0 + lr0) * K + koff;
    const __bf16* wS1 = We + (size_t)(n0 + lr1) * K + koff;
    __bf16* ldsA0 = As + c0*512;
    __bf16* ldsA1 = As + c1*512;
    __bf16* ldsW0 = Ws + c0*512;
    __bf16* ldsW1 = Ws + c1*512;

    int wm = (wave >> 1) * 64, wn = (wave & 1) * 64;
    int fr = lane & 15, fk = (lane >> 4) * 8;

    f32x4 acc[4][4];
    #pragma unroll
    for (int i = 0; i < 4; ++i)
        #pragma unroll
        for (int j = 0; j < 4; ++j)
            acc[i][j] = (f32x4){0.f, 0.f, 0.f, 0.f};

    for (int k0 = 0; k0 < K; k0 += 32){
        gload16(aS0 + k0, ldsA0);
        gload16(aS1 + k0, ldsA1);
        gload16(wS0 + k0, ldsW0);
        gload16(wS1 + k0, ldsW1);
        __syncthreads();
        bf16x8 af[4], bf[4];
        #pragma unroll
        for (int i = 0; i < 4; ++i)
            af[i] = *(const bf16x8*)&As[(wm + i*16 + fr)*32 + fk];
        #pragma unroll
        for (int j = 0; j < 4; ++j)
            bf[j] = *(const bf16x8*)&Ws[(wn + j*16 + fr)*32 + fk];
        #pragma unroll
        for (int i = 0; i < 4; ++i)
            #pragma unroll
            for (int j = 0; j < 4; ++j)
                acc[i][j] = mfma16(af[i], bf[j], acc[i][j]);
        __syncthreads();
    }

    int orow = (lane >> 4) * 4;
    int ocol = lane & 15;
    #pragma unroll
    for (int i = 0; i < 4; ++i){
        #pragma unroll
        for (int jj = 0; jj < 4; ++jj){
            #pragma unroll
            for (int j = 0; j < 4; ++j){
                int m = m0 + wm + i*16 + orow + j;
                int n = n0 + wn + jj*16 + ocol;
                if (m < cnt){
                    size_t row = (size_t)(base + m);
                    float v = acc[i][jj][j];
                    if (EPI == 1) v += ((const float*)RG)[row * (size_t)N + n];
                    if (EPI == 2){
                        float g = (float)((const __bf16*)RG)[row * (size_t)N + n];
                        v = siluf(g) * v;
                    }
                    if (CBF) ((__bf16*)Cv)[row * (size_t)N + n] = (__bf16)v;
                    else     ((float* )Cv)[row * (size_t)N + n] = v;
                }
            }
        }
    }
}

// ---------------- reg-staging MFMA GEMM (small/odd shapes) ----------------
// EPI: 0 none, 3 softplus(acc + bias[n])
template<int EPI>
__global__ __launch_bounds__(256,2) void mfma_gemm(
    const float* __restrict__ A, const float* __restrict__ W,
    const float* __restrict__ bias, float* __restrict__ C,
    int M, int N, int K, int lda)
{
    int m0 = blockIdx.y * 128;
    int n0 = blockIdx.x * 128;

    __shared__ __bf16 As[128*32];
    __shared__ __bf16 Ws[128*32];

    int tid = threadIdx.x;
    int srow = tid >> 1;
    int scol = (tid & 1) * 16;

    const float* af = A + (size_t)(m0 + srow) * lda + scol;
    int wrow = n0 + srow; if (wrow >= N) wrow = N - 1;
    const float* wptr = W + (size_t)wrow * K + scol;

    f32x4 raf[4], rw[4];
    #pragma unroll
    for (int q = 0; q < 4; ++q){
        raf[q] = *(const f32x4*)(af + q*4);
        rw[q]  = *(const f32x4*)(wptr + q*4);
    }

    int wave = tid >> 6, lane = tid & 63;
    int wm = (wave >> 1) * 64, wn = (wave & 1) * 64;
    int fr = lane & 15, fk = (lane >> 4) * 8;

    f32x4 acc[4][4];
    #pragma unroll
    for (int i = 0; i < 4; ++i)
        #pragma unroll
        for (int j = 0; j < 4; ++j)
            acc[i][j] = (f32x4){0.f, 0.f, 0.f, 0.f};

    for (int k0 = 0; k0 < K; k0 += 32){
        cvt_store16(&As[srow*32 + scol], raf[0], raf[1], raf[2], raf[3]);
        cvt_store16(&Ws[srow*32 + scol], rw[0], rw[1], rw[2], rw[3]);
        __syncthreads();
        if (k0 + 32 < K){
            #pragma unroll
            for (int q = 0; q < 4; ++q){
                raf[q] = *(const f32x4*)(af + k0 + 32 + q*4);
                rw[q]  = *(const f32x4*)(wptr + k0 + 32 + q*4);
            }
        }
        bf16x8 afr[4], bfr[4];
        #pragma unroll
        for (int i = 0; i < 4; ++i)
            afr[i] = *(const bf16x8*)&As[(wm + i*16 + fr)*32 + fk];
        #pragma unroll
        for (int i = 0; i < 4; ++i)
            bfr[i] = *(const bf16x8*)&Ws[(wn + i*16 + fr)*32 + fk];
        #pragma unroll
        for (int i = 0; i < 4; ++i)
            #pragma unroll
            for (int j = 0; j < 4; ++j)
                acc[i][j] = mfma16(afr[i], bfr[j], acc[i][j]);
        __syncthreads();
    }

    int orow = (lane >> 4) * 4;
    int ocol = lane & 15;
    #pragma unroll
    for (int i = 0; i < 4; ++i){
        #pragma unroll
        for (int jj = 0; jj < 4; ++jj){
            #pragma unroll
            for (int j = 0; j < 4; ++j){
                int m = m0 + wm + i*16 + orow + j;
                int n = n0 + wn + jj*16 + ocol;
                if (m < M && n < N){
                    float v = acc[i][jj][j];
                    if (EPI == 3){
                        v += bias[n];
                        v = (v > 20.f) ? v : log1pf(expf(v));
                    }
                    C[(size_t)m * N + n] = v;
                }
            }
        }
    }
}

// ---------------- conv ----------------
__global__ __launch_bounds__(256) void conv_kernel(const float* __restrict__ xz,
    const float* __restrict__ cs, const float* __restrict__ cw,
    const float* __restrict__ cb, float* __restrict__ xcs)
{
    int idx = blockIdx.x*256 + threadIdx.x;
    int d = idx & (D_INNER-1);
    int bt = idx >> 11;
    int b = bt >> 11;
    int t = bt & (TT-1);
    float acc = cb[d];
    #pragma unroll
    for (int k = 0; k < 4; ++k){
        int tau = t + k - 3;
        float xv;
        if (tau >= 0) xv = xz[(size_t)(b*TT + tau)*(2*D_INNER) + d];
        else          xv = cs[((size_t)b*D_INNER + d)*3 + (tau + 3)];
        acc += cw[d*4 + k] * xv;
    }
    xcs[idx] = siluf(acc);
}

// ---------------- chunked SSM scan: one lane per (b,d,chunk) ----------------
__global__ __launch_bounds__(256) void scan_pass1(const float* __restrict__ dtp,
    const float* __restrict__ proj, const float* __restrict__ xcs,
    const float* __restrict__ A_log, float* __restrict__ hend,
    float* __restrict__ sumdt)
{
    int gid = blockIdx.x*256 + threadIdx.x;          // 262144
    int bd = gid & (BB*D_INNER-1);
    int chunk = gid >> 12;
    int b = bd >> 11, d = bd & (D_INNER-1);
    float As[D_STATE], h[D_STATE];
    #pragma unroll
    for (int s = 0; s < D_STATE; ++s){
        As[s] = -__expf(A_log[d*D_STATE + s]);
        h[s] = 0.f;
    }
    float sdt = 0.f;
    int base = b*TT + chunk*CLEN;
    for (int t = 0; t < CLEN; ++t){
        size_t bt = (size_t)(base + t);
        float dt = dtp[bt*D_INNER + d];
        float x  = xcs[bt*D_INNER + d];
        f32x4 Bv[4];
        #pragma unroll
        for (int q = 0; q < 4; ++q) Bv[q] = *(const f32x4*)(proj + bt*96 + DT_RANK + q*4);
        float dtx = dt * x;
        sdt += dt;
        #pragma unroll
        for (int s = 0; s < D_STATE; ++s)
            h[s] = __expf(dt*As[s])*h[s] + Bv[s>>2][s&3]*dtx;
    }
    size_t hb = ((size_t)bd*NCHUNK + chunk)*D_STATE;
    #pragma unroll
    for (int q = 0; q < 4; ++q)
        *(f32x4*)(hend + hb + q*4) = (f32x4){h[q*4], h[q*4+1], h[q*4+2], h[q*4+3]};
    sumdt[bd*NCHUNK + chunk] = sdt;
}

__global__ __launch_bounds__(256) void scan_combine(const float* __restrict__ hend,
    const float* __restrict__ sumdt, const float* __restrict__ A_log,
    const float* __restrict__ ssm0, float* __restrict__ hstart)
{
    int gid = blockIdx.x*256 + threadIdx.x;          // 65536
    int s = gid & 15;
    int bd = gid >> 4;
    int b = bd >> 11, d = bd & (D_INNER-1);
    float As = -__expf(A_log[d*D_STATE + s]);
    float h = ssm0[((size_t)b*D_INNER + d)*D_STATE + s];
    for (int c = 0; c < NCHUNK; ++c){
        size_t idx = ((size_t)bd*NCHUNK + c)*D_STATE + s;
        hstart[idx] = h;
        h = hend[idx] + __expf(As * sumdt[bd*NCHUNK + c]) * h;
    }
}

__global__ __launch_bounds__(256) void scan_pass3(const float* __restrict__ dtp,
    const float* __restrict__ proj, const float* __restrict__ xcs,
    const float* __restrict__ xz, const float* __restrict__ A_log,
    const float* __restrict__ Dp, const float* __restrict__ hstart,
    __bf16* __restrict__ ym)
{
    int gid = blockIdx.x*256 + threadIdx.x;          // 262144
    int bd = gid & (BB*D_INNER-1);
    int chunk = gid >> 12;
    int b = bd >> 11, d = bd & (D_INNER-1);
    float As[D_STATE], h[D_STATE];
    #pragma unroll
    for (int s = 0; s < D_STATE; ++s)
        As[s] = -__expf(A_log[d*D_STATE + s]);
    size_t hb = ((size_t)bd*NCHUNK + chunk)*D_STATE;
    #pragma unroll
    for (int q = 0; q < 4; ++q){
        f32x4 hv = *(const f32x4*)(hstart + hb + q*4);
        h[q*4] = hv[0]; h[q*4+1] = hv[1]; h[q*4+2] = hv[2]; h[q*4+3] = hv[3];
    }
    float Dd = Dp[d];
    int base = b*TT + chunk*CLEN;
    for (int t = 0; t < CLEN; ++t){
        size_t bt = (size_t)(base + t);
        float dt = dtp[bt*D_INNER + d];
        float x  = xcs[bt*D_INNER + d];
        f32x4 Bv[4], Cv[4];
        #pragma unroll
        for (int q = 0; q < 4; ++q){
            Bv[q] = *(const f32x4*)(proj + bt*96 + DT_RANK + q*4);
            Cv[q] = *(const f32x4*)(proj + bt*96 + DT_RANK + D_STATE + q*4);
        }
        float dtx = dt * x;
        float p = 0.f;
        #pragma unroll
        for (int s = 0; s < D_STATE; ++s){
            h[s] = __expf(dt*As[s])*h[s] + Bv[s>>2][s&3]*dtx;
            p += h[s] * Cv[s>>2][s&3];
        }
        float y = p + Dd*x;
        float z = xz[bt*(2*D_INNER) + D_INNER + d];
        float sz = z / (1.f + __expf(-z));
        ym[bt*D_INNER + d] = (__bf16)(y * sz);
    }
}

// ---------------- router ----------------
__global__ __launch_bounds__(256) void router_kernel(const float* __restrict__ xn2,
    const float* __restrict__ rw, float* __restrict__ tw, int* __restrict__ ti,
    int* __restrict__ counts)
{
    int tok = blockIdx.x*4 + (threadIdx.x >> 6);
    int lane = threadIdx.x & 63;
    float p[N_EXP] = {};
    const float* xp = xn2 + (size_t)tok * DIM;
    for (int dd = lane; dd < DIM; dd += 64){
        float xv = xp[dd];
        #pragma unroll
        for (int e = 0; e < N_EXP; ++e) p[e] += xv * rw[e*DIM + dd];
    }
    #pragma unroll
    for (int e = 0; e < N_EXP; ++e){
        #pragma unroll
        for (int off = 32; off; off >>= 1) p[e] += __shfl_xor(p[e], off, 64);
    }
    if (lane == 0){
        float mx = p[0];
        #pragma unroll
        for (int e = 1; e < N_EXP; ++e) mx = fmaxf(mx, p[e]);
        float q[N_EXP]; float ssum = 0.f;
        #pragma unroll
        for (int e = 0; e < N_EXP; ++e){ q[e] = expf(p[e]-mx); ssum += q[e]; }
        int i0 = 0;
        #pragma unroll
        for (int e = 1; e < N_EXP; ++e) if (q[e] > q[i0]) i0 = e;
        int i1 = (i0 == 0) ? 1 : 0;
        #pragma unroll
        for (int e = 0; e < N_EXP; ++e) if (e != i0 && q[e] > q[i1]) i1 = e;
        float w0 = q[i0]/ssum, w1 = q[i1]/ssum;
        float sw = w0 + w1; w0 /= sw; w1 /= sw;
        tw[tok*2] = w0; tw[tok*2+1] = w1;
        ti[tok*2] = i0; ti[tok*2+1] = i1;
        atomicAdd(&counts[i0], 1);
        atomicAdd(&counts[i1], 1);
    }
}

__global__ void offs_kernel(const int* __restrict__ counts, int* __restrict__ offs)
{
    if (threadIdx.x == 0 && blockIdx.x == 0){
        int s = 0;
        for (int e = 0; e < N_EXP; ++e){ offs[e] = s; s += counts[e]; }
    }
}

__global__ __launch_bounds__(256) void assign_kernel(const int* __restrict__ ti,
    const int* __restrict__ offs, int* __restrict__ cursors,
    int* __restrict__ tok_of_slot, int* __restrict__ slot_of)
{
    int t = blockIdx.x*256 + threadIdx.x;
    if (t >= NTOK) return;
    #pragma unroll
    for (int k = 0; k < TOP_K; ++k){
        int e = ti[t*2 + k];
        int pos = atomicAdd(&cursors[e], 1);
        int slot = offs[e] + pos;
        tok_of_slot[slot] = t;
        slot_of[t*2 + k] = slot;
    }
}

// ---------------- final combine ----------------
__global__ __launch_bounds__(256) void final_kernel(const float* __restrict__ x1,
    const float* __restrict__ down_out, const float* __restrict__ tw,
    const int* __restrict__ slot_of, float* __restrict__ out)
{
    int idx4 = blockIdx.x*256 + threadIdx.x;
    int t = idx4 >> 8;
    int c = idx4 & 255;
    float w0 = tw[t*2], w1 = tw[t*2+1];
    size_t s0 = (size_t)slot_of[t*2] * DIM;
    size_t s1 = (size_t)slot_of[t*2+1] * DIM;
    float4 a = *(const float4*)(x1 + (size_t)t*DIM + c*4);
    float4 d0 = *(const float4*)(down_out + s0 + c*4);
    float4 d1 = *(const float4*)(down_out + s1 + c*4);
    float4 r;
    r.x = a.x + w0*d0.x + w1*d1.x;
    r.y = a.y + w0*d0.y + w1*d1.y;
    r.z = a.z + w0*d0.z + w1*d1.z;
    r.w = a.w + w0*d0.w + w1*d1.w;
    *(float4*)(out + (size_t)t*DIM + c*4) = r;
}

extern "C" void kernel_launch(void* const* d_in, const int* in_sizes, int n_in,
                              void* d_out, int out_size, void* d_ws, size_t ws_size,
                              hipStream_t stream)
{
    const float* x        = (const float*)d_in[0];
    const float* ssm0     = (const float*)d_in[1];
    const float* conv0    = (const float*)d_in[2];
    const float* ln1_s    = (const float*)d_in[3];
    const float* ln1_b    = (const float*)d_in[4];
    const float* ln2_s    = (const float*)d_in[5];
    const float* ln2_b    = (const float*)d_in[6];
    const float* in_proj  = (const float*)d_in[7];
    const float* conv_w   = (const float*)d_in[8];
    const float* conv_b   = (const float*)d_in[9];
    const float* x_proj   = (const float*)d_in[10];
    const float* dt_proj  = (const float*)d_in[11];
    const float* dt_b     = (const float*)d_in[12];
    const float* A_log    = (const float*)d_in[13];
    const float* Dp       = (const float*)d_in[14];
    const float* out_proj = (const float*)d_in[15];
    const float* router_w = (const float*)d_in[16];
    const float* w_gate   = (const float*)d_in[17];
    const float* w_up     = (const float*)d_in[18];
    const float* w_down   = (const float*)d_in[19];
    float* out = (float*)d_out;

    float* ws = (float*)d_ws;
    __bf16* xn_bf  = (__bf16*)(ws + OFF_R0);
    float*  hend   = ws + OFF_R0;
    __bf16* ym_bf  = (__bf16*)(ws + OFF_R0);
    float*  hst    = ws + OFF_R1;
    float*  xn2f   = ws + OFF_R1;
    float*  sdt    = ws + OFF_R2;
    __bf16* opbf   = (__bf16*)(ws + OFF_R2);
    __bf16* xn2bf  = (__bf16*)(ws + OFF_R2);
    float*  xz     = ws + OFF_XZ;
    __bf16* G      = (__bf16*)(ws + OFF_G);
    __bf16* H      = (__bf16*)(ws + OFF_H);
    float*  xcs    = ws + OFF_XCS;
    float*  dnout  = ws + OFF_XCS;
    float*  dtp    = ws + OFF_DTP;
    __bf16* ipbf   = (__bf16*)(ws + OFF_DTP);
    __bf16* wbf    = (__bf16*)(ws + OFF_DTP);
    float*  x1     = ws + OFF_X1;
    float*  proj   = ws + OFF_PROJ;
    float*  tw     = ws + OFF_TW;
    int*    ip     = (int*)(ws + OFF_INT);
    int* ti          = ip + IO_TI;
    int* counts      = ip + IO_CNT;
    int* cursors     = ip + IO_CUR;
    int* offs        = ip + IO_OFS;
    int* tok_of_slot = ip + IO_TOK;
    int* slot_of     = ip + IO_SLOT;

    hipMemsetAsync(counts, 0, 16*sizeof(int), stream);

    // 0a. in_proj -> bf16 (into dtp region, dead until step 5)
    cvt_w_kernel<<<1024, 256, 0, stream>>>(in_proj, ipbf, (2*D_INNER*DIM)/4);
    // 1. xn_bf = LN1(x)
    ln_kernel<0><<<NTOK, 256, 0, stream>>>(x, ln1_s, ln1_b, xn_bf, nullptr);
    // 2. xz = xn @ in_proj^T  (fast, dense, swz)
    mfma_gemm_fast<0,0,0,1><<<dim3(32,32), 256, 0, stream>>>(xn_bf, ipbf, nullptr, xz,
        nullptr, nullptr, nullptr, NTOK, 2*D_INNER, DIM, DIM);
    // 3. conv + silu -> xcs (f32)
    conv_kernel<<<(NTOK*D_INNER)/256, 256, 0, stream>>>(xz, conv0, conv_w, conv_b, xcs);
    // 4. proj = xcs @ x_proj^T  (reg-staging, N=96)
    mfma_gemm<0><<<dim3(1,32), 256, 0, stream>>>(xcs, x_proj, nullptr, proj,
        NTOK, 96, D_INNER, D_INNER);
    // 5. dtp = softplus(proj[:,:64] @ dt_proj^T + dt_b)  (reg-staging, K=64, lda=96)
    mfma_gemm<3><<<dim3(16,32), 256, 0, stream>>>(proj, dt_proj, dt_b, dtp,
        NTOK, D_INNER, DT_RANK, 96);
    // 6. chunked scan
    scan_pass1<<<1024, 256, 0, stream>>>(dtp, proj, xcs, A_log, hend, sdt);
    scan_combine<<<256, 256, 0, stream>>>(hend, sdt, A_log, ssm0, hst);
    scan_pass3<<<1024, 256, 0, stream>>>(dtp, proj, xcs, xz, A_log, Dp, hst, ym_bf);
    // 6b. out_proj -> bf16 (into R2; sdt dead after combine)
    cvt_w_kernel<<<512, 256, 0, stream>>>(out_proj, opbf, (DIM*D_INNER)/4);
    // 7. x1 = x + ym @ out_proj^T  (fast, dense, swz)
    mfma_gemm_fast<0,1,0,1><<<dim3(8,32), 256, 0, stream>>>(ym_bf, opbf, x, x1,
        nullptr, nullptr, nullptr, NTOK, DIM, D_INNER, D_INNER);
    // 8. xn2 = LN2(x1): bf16 (overwrites opbf, now dead) + f32 for router
    ln_kernel<1><<<NTOK, 256, 0, stream>>>(x1, ln2_s, ln2_b, xn2bf, xn2f);
    // 9. router + slot assignment
    router_kernel<<<NTOK/4, 256, 0, stream>>>(xn2f, router_w, tw, ti, counts);
    offs_kernel<<<1, 64, 0, stream>>>(counts, offs);
    assign_kernel<<<NTOK/256, 256, 0, stream>>>(ti, offs, cursors, tok_of_slot, slot_of);
    // 10. MoE (weights converted one-at-a-time into dtp region, dead after scan)
    cvt_w_kernel<<<2048, 256, 0, stream>>>(w_gate, wbf, (N_EXP*HID*DIM)/4);
    mfma_gemm_fast<1,0,1,0><<<dim3(HID/128, 64, N_EXP), 256, 0, stream>>>(xn2bf, wbf, nullptr, G,
        tok_of_slot, counts, offs, NSLOT, HID, DIM, DIM);
    cvt_w_kernel<<<2048, 256, 0, stream>>>(w_up, wbf, (N_EXP*HID*DIM)/4);
    mfma_gemm_fast<1,2,1,0><<<dim3(HID/128, 64, N_EXP), 256, 0, stream>>>(xn2bf, wbf, G, H,
        tok_of_slot, counts, offs, NSLOT, HID, DIM, DIM);
    cvt_w_kernel<<<2048, 256, 0, stream>>>(w_down, wbf, (N_EXP*DIM*HID)/4);
    mfma_gemm_fast<2,0,0,0><<<dim3(DIM/128, 64, N_EXP), 256, 0, stream>>>(H, wbf, nullptr, dnout,
        tok_of_slot, counts, offs, NSLOT, DIM, HID, HID);
    // 11. out = x1 + weighted experts
    final_kernel<<<(NTOK*DIM/4)/256, 256, 0, stream>>>(x1, dnout, tw, slot_of, out);
}

// Round 6
// 744.268 us; speedup vs baseline: 5.1668x; 1.1304x over previous
//
#include <hip/hip_runtime.h>
#include <hip/hip_bf16.h>
#include <math.h>

#define DIM 1024
#define D_STATE 16
#define D_CONV 4
#define D_INNER 2048
#define DT_RANK 64
#define N_EXP 8
#define TOP_K 2
#define HID 2048
#define BB 2
#define TT 2048
#define NTOK (BB*TT)          // 4096
#define NSLOT (NTOK*TOP_K)    // 8192
#define EPS 1e-5f
#define NCHUNK 64
#define CLEN (TT/NCHUNK)      // 32
#define XPJ_KS 8
#define XPJ_KLEN (D_INNER/XPJ_KS)   // 256

// ---------------- workspace layout (float units) ----------------
// R0 (4.19M): xn_bf16 (s1-2) -> hend (s6) -> ym_bf16 (s6c-7)
#define OFF_R0   ((size_t)0)
// R1 (4.19M): xproj partials [8][4096][128] (s4) -> hst (s6)
#define OFF_R1   ((size_t)4194304)
// R2 (2.10M): sdt (s6) -> out_proj_bf16 (s6b-7) -> xn2_bf16 (s8-10)
#define OFF_R2   ((size_t)8388608)
// XZ (16.78M): xz f32 (s2-6c) -> H bf16 (first half, s10) + wu_bf16 (second half, s10)
#define OFF_XZ   ((size_t)10485760)
#define OFF_H    OFF_XZ                       // H bf16: 8192*2048 = 8.39M float-units
#define OFF_WU   ((size_t)18874368)           // wu bf16: 8*2048*1024 = 8.39M float-units
// XCS (8.39M): xcs f32 (s3-6c) -> down_out f32 (s10c-11)
#define OFF_XCS  ((size_t)27262976)
// DTP (8.39M): in_proj_bf16 (s2) -> dtp f32 (s5-6c) -> wg_bf16 (s10) -> wd_bf16 (s10c)
#define OFF_DTP  ((size_t)35651584)
// X1 (4.19M): xcs_bf16 (s3-4) -> x1 f32 (s7-11)
#define OFF_X1   ((size_t)44040192)
#define OFF_PROJ ((size_t)48234496)   // 393216
#define OFF_TW   ((size_t)48627712)   // 8192
#define OFF_INT  ((size_t)48635904)   // int area
#define OFF_XPW  ((size_t)48668672)   // 131072 float-units (x_proj padded bf16)
// int offsets (ints)
#define IO_TI    0
#define IO_CNT   8192
#define IO_CUR   8200
#define IO_OFS   8208
#define IO_TOK   8216
#define IO_SLOT  16408

typedef __attribute__((ext_vector_type(4))) float f32x4;
typedef __attribute__((ext_vector_type(8))) __bf16 bf16x8;
typedef __attribute__((ext_vector_type(4))) __bf16 bf16x4;

__device__ __forceinline__ float siluf(float v){ return v / (1.f + expf(-v)); }

__device__ __forceinline__ f32x4 mfma16(bf16x8 a, bf16x8 b, f32x4 c){
    return __builtin_amdgcn_mfma_f32_16x16x32_bf16(a, b, c, 0, 0, 0);
}

__device__ __forceinline__ void gload16(const void* g, void* l){
    __builtin_amdgcn_global_load_lds(
        (const __attribute__((address_space(1))) unsigned int*)g,
        (__attribute__((address_space(3))) unsigned int*)l, 16, 0, 0);
}

__device__ __forceinline__ void cvt_store16(__bf16* dst, f32x4 a0, f32x4 a1, f32x4 a2, f32x4 a3){
    bf16x8 p0, p1;
    #pragma unroll
    for (int j = 0; j < 4; ++j){
        p0[j]   = (__bf16)a0[j];
        p0[j+4] = (__bf16)a1[j];
        p1[j]   = (__bf16)a2[j];
        p1[j+4] = (__bf16)a3[j];
    }
    *(bf16x8*)dst = p0;
    *(bf16x8*)(dst+8) = p1;
}

// ---------------- weight f32 -> bf16 convert ----------------
__global__ __launch_bounds__(256) void cvt_w_kernel(const float* __restrict__ src,
    __bf16* __restrict__ dst, int n4)
{
    int i = blockIdx.x*256 + threadIdx.x;
    int stride = gridDim.x*256;
    for (; i < n4; i += stride){
        f32x4 v = *(const f32x4*)(src + (size_t)i*4);
        bf16x4 o;
        o[0] = (__bf16)v[0]; o[1] = (__bf16)v[1];
        o[2] = (__bf16)v[2]; o[3] = (__bf16)v[3];
        *(bf16x4*)(dst + (size_t)i*4) = o;
    }
}

// x_proj (96x2048) -> padded bf16 (128x2048), rows 96..127 = 0
__global__ __launch_bounds__(256) void cvt_pad_xproj(const float* __restrict__ src,
    __bf16* __restrict__ dst)
{
    int i = blockIdx.x*256 + threadIdx.x;       // over 128*2048/4 = 65536
    int base = i*4;
    int row = base >> 11;
    bf16x4 o;
    if (row < 96){
        f32x4 v = *(const f32x4*)(src + base);
        o[0] = (__bf16)v[0]; o[1] = (__bf16)v[1];
        o[2] = (__bf16)v[2]; o[3] = (__bf16)v[3];
    } else {
        o[0] = (__bf16)0.f; o[1] = (__bf16)0.f;
        o[2] = (__bf16)0.f; o[3] = (__bf16)0.f;
    }
    *(bf16x4*)(dst + base) = o;
}

// ---------------- LayerNorm (LN1): bf16 out ----------------
__global__ __launch_bounds__(256) void ln_kernel(const float* __restrict__ x,
    const float* __restrict__ s, const float* __restrict__ b,
    __bf16* __restrict__ obf)
{
    int t = blockIdx.x;
    const float* xp = x + (size_t)t * DIM;
    float v[4]; float sum = 0.f, sq = 0.f;
    #pragma unroll
    for (int j = 0; j < 4; ++j){
        v[j] = xp[threadIdx.x + 256*j];
        sum += v[j]; sq += v[j]*v[j];
    }
    #pragma unroll
    for (int off = 32; off; off >>= 1){
        sum += __shfl_xor(sum, off, 64);
        sq  += __shfl_xor(sq , off, 64);
    }
    __shared__ float red[4][2];
    int w = threadIdx.x >> 6, lane = threadIdx.x & 63;
    if (lane == 0){ red[w][0] = sum; red[w][1] = sq; }
    __syncthreads();
    sum = red[0][0]+red[1][0]+red[2][0]+red[3][0];
    sq  = red[0][1]+red[1][1]+red[2][1]+red[3][1];
    float mu = sum * (1.f/DIM);
    float var = sq * (1.f/DIM) - mu*mu;
    float r = rsqrtf(var + EPS);
    #pragma unroll
    for (int j = 0; j < 4; ++j){
        int d = threadIdx.x + 256*j;
        obf[(size_t)t*DIM + d] = (__bf16)((v[j]-mu)*r*s[d] + b[d]);
    }
}

// ---------------- LN2 fused with router ----------------
__global__ __launch_bounds__(256) void ln2_router_kernel(const float* __restrict__ x,
    const float* __restrict__ s, const float* __restrict__ b,
    const float* __restrict__ rw, __bf16* __restrict__ obf,
    float* __restrict__ tw, int* __restrict__ ti, int* __restrict__ counts)
{
    int t = blockIdx.x;
    const float* xp = x + (size_t)t * DIM;
    float v[4]; float sum = 0.f, sq = 0.f;
    #pragma unroll
    for (int j = 0; j < 4; ++j){
        v[j] = xp[threadIdx.x + 256*j];
        sum += v[j]; sq += v[j]*v[j];
    }
    #pragma unroll
    for (int off = 32; off; off >>= 1){
        sum += __shfl_xor(sum, off, 64);
        sq  += __shfl_xor(sq , off, 64);
    }
    __shared__ float red[4][2];
    __shared__ float red2[4][N_EXP];
    int w = threadIdx.x >> 6, lane = threadIdx.x & 63;
    if (lane == 0){ red[w][0] = sum; red[w][1] = sq; }
    __syncthreads();
    sum = red[0][0]+red[1][0]+red[2][0]+red[3][0];
    sq  = red[0][1]+red[1][1]+red[2][1]+red[3][1];
    float mu = sum * (1.f/DIM);
    float var = sq * (1.f/DIM) - mu*mu;
    float r = rsqrtf(var + EPS);
    float p[N_EXP] = {};
    #pragma unroll
    for (int j = 0; j < 4; ++j){
        int d = threadIdx.x + 256*j;
        float o = (v[j]-mu)*r*s[d] + b[d];
        obf[(size_t)t*DIM + d] = (__bf16)o;
        #pragma unroll
        for (int e = 0; e < N_EXP; ++e) p[e] += o * rw[e*DIM + d];
    }
    #pragma unroll
    for (int e = 0; e < N_EXP; ++e){
        #pragma unroll
        for (int off = 32; off; off >>= 1) p[e] += __shfl_xor(p[e], off, 64);
    }
    if (lane == 0){
        #pragma unroll
        for (int e = 0; e < N_EXP; ++e) red2[w][e] = p[e];
    }
    __syncthreads();
    if (threadIdx.x == 0){
        float q[N_EXP];
        #pragma unroll
        for (int e = 0; e < N_EXP; ++e)
            q[e] = red2[0][e]+red2[1][e]+red2[2][e]+red2[3][e];
        float mx = q[0];
        #pragma unroll
        for (int e = 1; e < N_EXP; ++e) mx = fmaxf(mx, q[e]);
        float ssum = 0.f;
        #pragma unroll
        for (int e = 0; e < N_EXP; ++e){ q[e] = expf(q[e]-mx); ssum += q[e]; }
        int i0 = 0;
        #pragma unroll
        for (int e = 1; e < N_EXP; ++e) if (q[e] > q[i0]) i0 = e;
        int i1 = (i0 == 0) ? 1 : 0;
        #pragma unroll
        for (int e = 0; e < N_EXP; ++e) if (e != i0 && q[e] > q[i1]) i1 = e;
        float w0 = q[i0]/ssum, w1 = q[i1]/ssum;
        float sw = w0 + w1; w0 /= sw; w1 /= sw;
        tw[t*2] = w0; tw[t*2+1] = w1;
        ti[t*2] = i0; ti[t*2+1] = i1;
        atomicAdd(&counts[i0], 1);
        atomicAdd(&counts[i1], 1);
    }
}

// ---------------- fast bf16 MFMA GEMM with global_load_lds ----------------
// MODE: 0 dense, 1 gather A via tok_of_slot, 2 contiguous slot rows
// EPI : 0 none, 1 +resid f32
// CBF : 0 C fp32, 1 C bf16
// SWZ : XCD swizzle (dense; nwg%8==0)
template<int MODE, int EPI, int CBF, int SWZ>
__global__ __launch_bounds__(256,3) void mfma_gemm_fast(
    const __bf16* __restrict__ A, const __bf16* __restrict__ W,
    const void* __restrict__ RG, void* __restrict__ Cv,
    const int* __restrict__ tok_of_slot, const int* __restrict__ counts,
    const int* __restrict__ offs, int M, int N, int K, int lda)
{
    int bx = blockIdx.x, by = blockIdx.y;
    if (SWZ){
        int nwg = gridDim.x*gridDim.y;
        int id = by*gridDim.x + bx;
        int swz = (id & 7)*(nwg >> 3) + (id >> 3);
        bx = swz % gridDim.x; by = swz / gridDim.x;
    }
    int e    = (MODE == 0) ? 0 : blockIdx.z;
    int cnt  = (MODE == 0) ? M : counts[e];
    int base = (MODE == 0) ? 0 : offs[e];
    int m0 = by * 128;
    if (m0 >= cnt) return;
    int n0 = bx * 128;
    const __bf16* We = W + (size_t)e * N * K;

    __shared__ __bf16 As[128*32];
    __shared__ __bf16 Ws[128*32];

    int tid = threadIdx.x;
    int wave = tid >> 6, lane = tid & 63;
    int c0 = wave*2, c1 = wave*2 + 1;
    int lr0 = c0*16 + (lane >> 2);
    int lr1 = c1*16 + (lane >> 2);
    int koff = (lane & 3) * 8;

    int ar0, ar1;
    {
        int m0c = m0 + lr0, m1c = m0 + lr1;
        if (MODE != 0){
            if (m0c >= cnt) m0c = cnt - 1;
            if (m1c >= cnt) m1c = cnt - 1;
        }
        if (MODE == 1){ ar0 = tok_of_slot[base + m0c]; ar1 = tok_of_slot[base + m1c]; }
        else if (MODE == 2){ ar0 = base + m0c; ar1 = base + m1c; }
        else { ar0 = m0c; ar1 = m1c; }
    }
    const __bf16* aS0 = A + (size_t)ar0 * lda + koff;
    const __bf16* aS1 = A + (size_t)ar1 * lda + koff;
    const __bf16* wS0 = We + (size_t)(n0 + lr0) * K + koff;
    const __bf16* wS1 = We + (size_t)(n0 + lr1) * K + koff;
    __bf16* ldsA0 = As + c0*512;
    __bf16* ldsA1 = As + c1*512;
    __bf16* ldsW0 = Ws + c0*512;
    __bf16* ldsW1 = Ws + c1*512;

    int wm = (wave >> 1) * 64, wn = (wave & 1) * 64;
    int fr = lane & 15, fk = (lane >> 4) * 8;

    f32x4 acc[4][4];
    #pragma unroll
    for (int i = 0; i < 4; ++i)
        #pragma unroll
        for (int j = 0; j < 4; ++j)
            acc[i][j] = (f32x4){0.f, 0.f, 0.f, 0.f};

    for (int k0 = 0; k0 < K; k0 += 32){
        gload16(aS0 + k0, ldsA0);
        gload16(aS1 + k0, ldsA1);
        gload16(wS0 + k0, ldsW0);
        gload16(wS1 + k0, ldsW1);
        __syncthreads();
        bf16x8 af[4], bf[4];
        #pragma unroll
        for (int i = 0; i < 4; ++i)
            af[i] = *(const bf16x8*)&As[(wm + i*16 + fr)*32 + fk];
        #pragma unroll
        for (int j = 0; j < 4; ++j)
            bf[j] = *(const bf16x8*)&Ws[(wn + j*16 + fr)*32 + fk];
        #pragma unroll
        for (int i = 0; i < 4; ++i)
            #pragma unroll
            for (int j = 0; j < 4; ++j)
                acc[i][j] = mfma16(af[i], bf[j], acc[i][j]);
        __syncthreads();
    }

    int orow = (lane >> 4) * 4;
    int ocol = lane & 15;
    #pragma unroll
    for (int i = 0; i < 4; ++i){
        #pragma unroll
        for (int jj = 0; jj < 4; ++jj){
            #pragma unroll
            for (int j = 0; j < 4; ++j){
                int m = m0 + wm + i*16 + orow + j;
                int n = n0 + wn + jj*16 + ocol;
                if (m < cnt){
                    size_t row = (size_t)(base + m);
                    float v = acc[i][jj][j];
                    if (EPI == 1) v += ((const float*)RG)[row * (size_t)N + n];
                    if (CBF) ((__bf16*)Cv)[row * (size_t)N + n] = (__bf16)v;
                    else     ((float* )Cv)[row * (size_t)N + n] = v;
                }
            }
        }
    }
}

// ---------------- fused MoE gate+up GEMM -> H = silu(XWg^T)*(XWu^T) ----------------
__global__ __launch_bounds__(256,2) void moe_gateup_fast(
    const __bf16* __restrict__ A, const __bf16* __restrict__ Wg,
    const __bf16* __restrict__ Wu, const int* __restrict__ tok_of_slot,
    const int* __restrict__ counts, const int* __restrict__ offs,
    __bf16* __restrict__ H)
{
    int e = blockIdx.z;
    int cnt = counts[e];
    int base = offs[e];
    int m0 = blockIdx.y * 128;
    if (m0 >= cnt) return;
    int n0 = blockIdx.x * 128;
    const __bf16* Wge = Wg + (size_t)e * HID * DIM;
    const __bf16* Wue = Wu + (size_t)e * HID * DIM;

    __shared__ __bf16 As[128*32];
    __shared__ __bf16 Gs[128*32];
    __shared__ __bf16 Us[128*32];

    int tid = threadIdx.x;
    int wave = tid >> 6, lane = tid & 63;
    int c0 = wave*2, c1 = wave*2 + 1;
    int lr0 = c0*16 + (lane >> 2);
    int lr1 = c1*16 + (lane >> 2);
    int koff = (lane & 3) * 8;

    int m0c = m0 + lr0, m1c = m0 + lr1;
    if (m0c >= cnt) m0c = cnt - 1;
    if (m1c >= cnt) m1c = cnt - 1;
    int ar0 = tok_of_slot[base + m0c];
    int ar1 = tok_of_slot[base + m1c];

    const __bf16* aS0 = A + (size_t)ar0 * DIM + koff;
    const __bf16* aS1 = A + (size_t)ar1 * DIM + koff;
    const __bf16* gS0 = Wge + (size_t)(n0 + lr0) * DIM + koff;
    const __bf16* gS1 = Wge + (size_t)(n0 + lr1) * DIM + koff;
    const __bf16* uS0 = Wue + (size_t)(n0 + lr0) * DIM + koff;
    const __bf16* uS1 = Wue + (size_t)(n0 + lr1) * DIM + koff;
    __bf16* ldsA0 = As + c0*512;
    __bf16* ldsA1 = As + c1*512;
    __bf16* ldsG0 = Gs + c0*512;
    __bf16* ldsG1 = Gs + c1*512;
    __bf16* ldsU0 = Us + c0*512;
    __bf16* ldsU1 = Us + c1*512;

    int wm = (wave >> 1) * 64, wn = (wave & 1) * 64;
    int fr = lane & 15, fk = (lane >> 4) * 8;

    f32x4 accg[4][4], accu[4][4];
    #pragma unroll
    for (int i = 0; i < 4; ++i)
        #pragma unroll
        for (int j = 0; j < 4; ++j){
            accg[i][j] = (f32x4){0.f, 0.f, 0.f, 0.f};
            accu[i][j] = (f32x4){0.f, 0.f, 0.f, 0.f};
        }

    for (int k0 = 0; k0 < DIM; k0 += 32){
        gload16(aS0 + k0, ldsA0);
        gload16(aS1 + k0, ldsA1);
        gload16(gS0 + k0, ldsG0);
        gload16(gS1 + k0, ldsG1);
        gload16(uS0 + k0, ldsU0);
        gload16(uS1 + k0, ldsU1);
        __syncthreads();
        bf16x8 af[4], gf[4], uf[4];
        #pragma unroll
        for (int i = 0; i < 4; ++i){
            af[i] = *(const bf16x8*)&As[(wm + i*16 + fr)*32 + fk];
            gf[i] = *(const bf16x8*)&Gs[(wn + i*16 + fr)*32 + fk];
            uf[i] = *(const bf16x8*)&Us[(wn + i*16 + fr)*32 + fk];
        }
        #pragma unroll
        for (int i = 0; i < 4; ++i)
            #pragma unroll
            for (int j = 0; j < 4; ++j){
                accg[i][j] = mfma16(af[i], gf[j], accg[i][j]);
                accu[i][j] = mfma16(af[i], uf[j], accu[i][j]);
            }
        __syncthreads();
    }

    int orow = (lane >> 4) * 4;
    int ocol = lane & 15;
    #pragma unroll
    for (int i = 0; i < 4; ++i){
        #pragma unroll
        for (int jj = 0; jj < 4; ++jj){
            #pragma unroll
            for (int j = 0; j < 4; ++j){
                int m = m0 + wm + i*16 + orow + j;
                if (m < cnt){
                    int n = n0 + wn + jj*16 + ocol;
                    size_t row = (size_t)(base + m);
                    float g = accg[i][jj][j], u = accu[i][jj][j];
                    H[row * (size_t)HID + n] = (__bf16)(siluf(g) * u);
                }
            }
        }
    }
}

// ---------------- x_proj K-split GEMM: part[z] = xcs_bf @ xpw^T (K-slice z) ----------
__global__ __launch_bounds__(256,3) void xproj_ks_kernel(
    const __bf16* __restrict__ A, const __bf16* __restrict__ W,
    float* __restrict__ Cpart)
{
    int m0 = blockIdx.y * 128;
    int kbeg = blockIdx.z * XPJ_KLEN;

    __shared__ __bf16 As[128*32];
    __shared__ __bf16 Ws[128*32];

    int tid = threadIdx.x;
    int wave = tid >> 6, lane = tid & 63;
    int c0 = wave*2, c1 = wave*2 + 1;
    int lr0 = c0*16 + (lane >> 2);
    int lr1 = c1*16 + (lane >> 2);
    int koff = (lane & 3) * 8;

    const __bf16* aS0 = A + (size_t)(m0 + lr0) * D_INNER + kbeg + koff;
    const __bf16* aS1 = A + (size_t)(m0 + lr1) * D_INNER + kbeg + koff;
    const __bf16* wS0 = W + (size_t)lr0 * D_INNER + kbeg + koff;
    const __bf16* wS1 = W + (size_t)lr1 * D_INNER + kbeg + koff;
    __bf16* ldsA0 = As + c0*512;
    __bf16* ldsA1 = As + c1*512;
    __bf16* ldsW0 = Ws + c0*512;
    __bf16* ldsW1 = Ws + c1*512;

    int wm = (wave >> 1) * 64, wn = (wave & 1) * 64;
    int fr = lane & 15, fk = (lane >> 4) * 8;

    f32x4 acc[4][4];
    #pragma unroll
    for (int i = 0; i < 4; ++i)
        #pragma unroll
        for (int j = 0; j < 4; ++j)
            acc[i][j] = (f32x4){0.f, 0.f, 0.f, 0.f};

    for (int k0 = 0; k0 < XPJ_KLEN; k0 += 32){
        gload16(aS0 + k0, ldsA0);
        gload16(aS1 + k0, ldsA1);
        gload16(wS0 + k0, ldsW0);
        gload16(wS1 + k0, ldsW1);
        __syncthreads();
        bf16x8 af[4], bf[4];
        #pragma unroll
        for (int i = 0; i < 4; ++i)
            af[i] = *(const bf16x8*)&As[(wm + i*16 + fr)*32 + fk];
        #pragma unroll
        for (int j = 0; j < 4; ++j)
            bf[j] = *(const bf16x8*)&Ws[(wn + j*16 + fr)*32 + fk];
        #pragma unroll
        for (int i = 0; i < 4; ++i)
            #pragma unroll
            for (int j = 0; j < 4; ++j)
                acc[i][j] = mfma16(af[i], bf[j], acc[i][j]);
        __syncthreads();
    }

    float* Cz = Cpart + (size_t)blockIdx.z * NTOK * 128;
    int orow = (lane >> 4) * 4;
    int ocol = lane & 15;
    #pragma unroll
    for (int i = 0; i < 4; ++i){
        #pragma unroll
        for (int jj = 0; jj < 4; ++jj){
            #pragma unroll
            for (int j = 0; j < 4; ++j){
                int m = m0 + wm + i*16 + orow + j;
                int n = wn + jj*16 + ocol;
                Cz[(size_t)m * 128 + n] = acc[i][jj][j];
            }
        }
    }
}

__global__ __launch_bounds__(256) void xproj_reduce(const float* __restrict__ Cpart,
    float* __restrict__ proj)
{
    int idx = blockIdx.x*256 + threadIdx.x;      // over 4096*96
    int t = idx / 96, n = idx - t*96;
    float s = 0.f;
    #pragma unroll
    for (int z = 0; z < XPJ_KS; ++z)
        s += Cpart[(size_t)z * NTOK * 128 + (size_t)t * 128 + n];
    proj[idx] = s;
}

// ---------------- reg-staging MFMA GEMM (dt: softplus(A@W^T + bias)) ----------------
__global__ __launch_bounds__(256,2) void dt_gemm(
    const float* __restrict__ A, const float* __restrict__ W,
    const float* __restrict__ bias, float* __restrict__ C,
    int M, int N, int K, int lda)
{
    int m0 = blockIdx.y * 128;
    int n0 = blockIdx.x * 128;

    __shared__ __bf16 As[128*32];
    __shared__ __bf16 Ws[128*32];

    int tid = threadIdx.x;
    int srow = tid >> 1;
    int scol = (tid & 1) * 16;

    const float* af = A + (size_t)(m0 + srow) * lda + scol;
    const float* wptr = W + (size_t)(n0 + srow) * K + scol;

    f32x4 raf[4], rw[4];
    #pragma unroll
    for (int q = 0; q < 4; ++q){
        raf[q] = *(const f32x4*)(af + q*4);
        rw[q]  = *(const f32x4*)(wptr + q*4);
    }

    int wave = tid >> 6, lane = tid & 63;
    int wm = (wave >> 1) * 64, wn = (wave & 1) * 64;
    int fr = lane & 15, fk = (lane >> 4) * 8;

    f32x4 acc[4][4];
    #pragma unroll
    for (int i = 0; i < 4; ++i)
        #pragma unroll
        for (int j = 0; j < 4; ++j)
            acc[i][j] = (f32x4){0.f, 0.f, 0.f, 0.f};

    for (int k0 = 0; k0 < K; k0 += 32){
        cvt_store16(&As[srow*32 + scol], raf[0], raf[1], raf[2], raf[3]);
        cvt_store16(&Ws[srow*32 + scol], rw[0], rw[1], rw[2], rw[3]);
        __syncthreads();
        if (k0 + 32 < K){
            #pragma unroll
            for (int q = 0; q < 4; ++q){
                raf[q] = *(const f32x4*)(af + k0 + 32 + q*4);
                rw[q]  = *(const f32x4*)(wptr + k0 + 32 + q*4);
            }
        }
        bf16x8 afr[4], bfr[4];
        #pragma unroll
        for (int i = 0; i < 4; ++i)
            afr[i] = *(const bf16x8*)&As[(wm + i*16 + fr)*32 + fk];
        #pragma unroll
        for (int i = 0; i < 4; ++i)
            bfr[i] = *(const bf16x8*)&Ws[(wn + i*16 + fr)*32 + fk];
        #pragma unroll
        for (int i = 0; i < 4; ++i)
            #pragma unroll
            for (int j = 0; j < 4; ++j)
                acc[i][j] = mfma16(afr[i], bfr[j], acc[i][j]);
        __syncthreads();
    }

    int orow = (lane >> 4) * 4;
    int ocol = lane & 15;
    #pragma unroll
    for (int i = 0; i < 4; ++i){
        #pragma unroll
        for (int jj = 0; jj < 4; ++jj){
            #pragma unroll
            for (int j = 0; j < 4; ++j){
                int m = m0 + wm + i*16 + orow + j;
                int n = n0 + wn + jj*16 + ocol;
                if (m < M && n < N){
                    float v = acc[i][jj][j] + bias[n];
                    v = (v > 20.f) ? v : log1pf(expf(v));
                    C[(size_t)m * N + n] = v;
                }
            }
        }
    }
}

// ---------------- conv: f32 + bf16 outputs ----------------
__global__ __launch_bounds__(256) void conv_kernel(const float* __restrict__ xz,
    const float* __restrict__ cs, const float* __restrict__ cw,
    const float* __restrict__ cb, float* __restrict__ xcs,
    __bf16* __restrict__ xcs_bf)
{
    int idx = blockIdx.x*256 + threadIdx.x;
    int d = idx & (D_INNER-1);
    int bt = idx >> 11;
    int b = bt >> 11;
    int t = bt & (TT-1);
    float acc = cb[d];
    #pragma unroll
    for (int k = 0; k < 4; ++k){
        int tau = t + k - 3;
        float xv;
        if (tau >= 0) xv = xz[(size_t)(b*TT + tau)*(2*D_INNER) + d];
        else          xv = cs[((size_t)b*D_INNER + d)*3 + (tau + 3)];
        acc += cw[d*4 + k] * xv;
    }
    float v = siluf(acc);
    xcs[idx] = v;
    xcs_bf[idx] = (__bf16)v;
}

// ---------------- chunked SSM scan ----------------
__global__ __launch_bounds__(256) void scan_pass1(const float* __restrict__ dtp,
    const float* __restrict__ proj, const float* __restrict__ xcs,
    const float* __restrict__ A_log, float* __restrict__ hend,
    float* __restrict__ sumdt)
{
    int gid = blockIdx.x*256 + threadIdx.x;          // 262144
    int bd = gid & (BB*D_INNER-1);
    int chunk = gid >> 12;
    int b = bd >> 11, d = bd & (D_INNER-1);
    float As[D_STATE], h[D_STATE];
    #pragma unroll
    for (int s = 0; s < D_STATE; ++s){
        As[s] = -__expf(A_log[d*D_STATE + s]);
        h[s] = 0.f;
    }
    float sdt = 0.f;
    int base = b*TT + chunk*CLEN;
    for (int t = 0; t < CLEN; ++t){
        size_t bt = (size_t)(base + t);
        float dt = dtp[bt*D_INNER + d];
        float x  = xcs[bt*D_INNER + d];
        f32x4 Bv[4];
        #pragma unroll
        for (int q = 0; q < 4; ++q) Bv[q] = *(const f32x4*)(proj + bt*96 + DT_RANK + q*4);
        float dtx = dt * x;
        sdt += dt;
        #pragma unroll
        for (int s = 0; s < D_STATE; ++s)
            h[s] = __expf(dt*As[s])*h[s] + Bv[s>>2][s&3]*dtx;
    }
    size_t hb = ((size_t)bd*NCHUNK + chunk)*D_STATE;
    #pragma unroll
    for (int q = 0; q < 4; ++q)
        *(f32x4*)(hend + hb + q*4) = (f32x4){h[q*4], h[q*4+1], h[q*4+2], h[q*4+3]};
    sumdt[bd*NCHUNK + chunk] = sdt;
}

__global__ __launch_bounds__(256) void scan_combine(const float* __restrict__ hend,
    const float* __restrict__ sumdt, const float* __restrict__ A_log,
    const float* __restrict__ ssm0, float* __restrict__ hstart)
{
    int gid = blockIdx.x*256 + threadIdx.x;          // 65536
    int s = gid & 15;
    int bd = gid >> 4;
    int b = bd >> 11, d = bd & (D_INNER-1);
    float As = -__expf(A_log[d*D_STATE + s]);
    float h = ssm0[((size_t)b*D_INNER + d)*D_STATE + s];
    for (int c = 0; c < NCHUNK; ++c){
        size_t idx = ((size_t)bd*NCHUNK + c)*D_STATE + s;
        hstart[idx] = h;
        h = hend[idx] + __expf(As * sumdt[bd*NCHUNK + c]) * h;
    }
}

__global__ __launch_bounds__(256) void scan_pass3(const float* __restrict__ dtp,
    const float* __restrict__ proj, const float* __restrict__ xcs,
    const float* __restrict__ xz, const float* __restrict__ A_log,
    const float* __restrict__ Dp, const float* __restrict__ hstart,
    __bf16* __restrict__ ym)
{
    int gid = blockIdx.x*256 + threadIdx.x;          // 262144
    int bd = gid & (BB*D_INNER-1);
    int chunk = gid >> 12;
    int b = bd >> 11, d = bd & (D_INNER-1);
    float As[D_STATE], h[D_STATE];
    #pragma unroll
    for (int s = 0; s < D_STATE; ++s)
        As[s] = -__expf(A_log[d*D_STATE + s]);
    size_t hb = ((size_t)bd*NCHUNK + chunk)*D_STATE;
    #pragma unroll
    for (int q = 0; q < 4; ++q){
        f32x4 hv = *(const f32x4*)(hstart + hb + q*4);
        h[q*4] = hv[0]; h[q*4+1] = hv[1]; h[q*4+2] = hv[2]; h[q*4+3] = hv[3];
    }
    float Dd = Dp[d];
    int base = b*TT + chunk*CLEN;
    for (int t = 0; t < CLEN; ++t){
        size_t bt = (size_t)(base + t);
        float dt = dtp[bt*D_INNER + d];
        float x  = xcs[bt*D_INNER + d];
        f32x4 Bv[4], Cv[4];
        #pragma unroll
        for (int q = 0; q < 4; ++q){
            Bv[q] = *(const f32x4*)(proj + bt*96 + DT_RANK + q*4);
            Cv[q] = *(const f32x4*)(proj + bt*96 + DT_RANK + D_STATE + q*4);
        }
        float dtx = dt * x;
        float p = 0.f;
        #pragma unroll
        for (int s = 0; s < D_STATE; ++s){
            h[s] = __expf(dt*As[s])*h[s] + Bv[s>>2][s&3]*dtx;
            p += h[s] * Cv[s>>2][s&3];
        }
        float y = p + Dd*x;
        float z = xz[bt*(2*D_INNER) + D_INNER + d];
        float sz = z / (1.f + __expf(-z));
        ym[bt*D_INNER + d] = (__bf16)(y * sz);
    }
}

// ---------------- slot assignment ----------------
__global__ void offs_kernel(const int* __restrict__ counts, int* __restrict__ offs)
{
    if (threadIdx.x == 0 && blockIdx.x == 0){
        int s = 0;
        for (int e = 0; e < N_EXP; ++e){ offs[e] = s; s += counts[e]; }
    }
}

__global__ __launch_bounds__(256) void assign_kernel(const int* __restrict__ ti,
    const int* __restrict__ offs, int* __restrict__ cursors,
    int* __restrict__ tok_of_slot, int* __restrict__ slot_of)
{
    int t = blockIdx.x*256 + threadIdx.x;
    if (t >= NTOK) return;
    #pragma unroll
    for (int k = 0; k < TOP_K; ++k){
        int e = ti[t*2 + k];
        int pos = atomicAdd(&cursors[e], 1);
        int slot = offs[e] + pos;
        tok_of_slot[slot] = t;
        slot_of[t*2 + k] = slot;
    }
}

// ---------------- final combine ----------------
__global__ __launch_bounds__(256) void final_kernel(const float* __restrict__ x1,
    const float* __restrict__ down_out, const float* __restrict__ tw,
    const int* __restrict__ slot_of, float* __restrict__ out)
{
    int idx4 = blockIdx.x*256 + threadIdx.x;
    int t = idx4 >> 8;
    int c = idx4 & 255;
    float w0 = tw[t*2], w1 = tw[t*2+1];
    size_t s0 = (size_t)slot_of[t*2] * DIM;
    size_t s1 = (size_t)slot_of[t*2+1] * DIM;
    float4 a = *(const float4*)(x1 + (size_t)t*DIM + c*4);
    float4 d0 = *(const float4*)(down_out + s0 + c*4);
    float4 d1 = *(const float4*)(down_out + s1 + c*4);
    float4 r;
    r.x = a.x + w0*d0.x + w1*d1.x;
    r.y = a.y + w0*d0.y + w1*d1.y;
    r.z = a.z + w0*d0.z + w1*d1.z;
    r.w = a.w + w0*d0.w + w1*d1.w;
    *(float4*)(out + (size_t)t*DIM + c*4) = r;
}

extern "C" void kernel_launch(void* const* d_in, const int* in_sizes, int n_in,
                              void* d_out, int out_size, void* d_ws, size_t ws_size,
                              hipStream_t stream)
{
    const float* x        = (const float*)d_in[0];
    const float* ssm0     = (const float*)d_in[1];
    const float* conv0    = (const float*)d_in[2];
    const float* ln1_s    = (const float*)d_in[3];
    const float* ln1_b    = (const float*)d_in[4];
    const float* ln2_s    = (const float*)d_in[5];
    const float* ln2_b    = (const float*)d_in[6];
    const float* in_proj  = (const float*)d_in[7];
    const float* conv_w   = (const float*)d_in[8];
    const float* conv_b   = (const float*)d_in[9];
    const float* x_proj   = (const float*)d_in[10];
    const float* dt_proj  = (const float*)d_in[11];
    const float* dt_b     = (const float*)d_in[12];
    const float* A_log    = (const float*)d_in[13];
    const float* Dp       = (const float*)d_in[14];
    const float* out_proj = (const float*)d_in[15];
    const float* router_w = (const float*)d_in[16];
    const float* w_gate   = (const float*)d_in[17];
    const float* w_up     = (const float*)d_in[18];
    const float* w_down   = (const float*)d_in[19];
    float* out = (float*)d_out;

    float* ws = (float*)d_ws;
    __bf16* xn_bf  = (__bf16*)(ws + OFF_R0);
    float*  hend   = ws + OFF_R0;
    __bf16* ym_bf  = (__bf16*)(ws + OFF_R0);
    float*  xpart  = ws + OFF_R1;
    float*  hst    = ws + OFF_R1;
    float*  sdt    = ws + OFF_R2;
    __bf16* opbf   = (__bf16*)(ws + OFF_R2);
    __bf16* xn2bf  = (__bf16*)(ws + OFF_R2);
    float*  xz     = ws + OFF_XZ;
    __bf16* H      = (__bf16*)(ws + OFF_H);
    __bf16* wubf   = (__bf16*)(ws + OFF_WU);
    float*  xcs    = ws + OFF_XCS;
    float*  dnout  = ws + OFF_XCS;
    float*  dtp    = ws + OFF_DTP;
    __bf16* ipbf   = (__bf16*)(ws + OFF_DTP);
    __bf16* wgbf   = (__bf16*)(ws + OFF_DTP);
    __bf16* wdbf   = (__bf16*)(ws + OFF_DTP);
    __bf16* xcs_bf = (__bf16*)(ws + OFF_X1);
    float*  x1     = ws + OFF_X1;
    float*  proj   = ws + OFF_PROJ;
    float*  tw     = ws + OFF_TW;
    __bf16* xpw    = (__bf16*)(ws + OFF_XPW);
    int*    ip     = (int*)(ws + OFF_INT);
    int* ti          = ip + IO_TI;
    int* counts      = ip + IO_CNT;
    int* cursors     = ip + IO_CUR;
    int* offs        = ip + IO_OFS;
    int* tok_of_slot = ip + IO_TOK;
    int* slot_of     = ip + IO_SLOT;

    hipMemsetAsync(counts, 0, 16*sizeof(int), stream);

    // 0a. in_proj -> bf16 (dtp region, dead until step 5)
    cvt_w_kernel<<<1024, 256, 0, stream>>>(in_proj, ipbf, (2*D_INNER*DIM)/4);
    // 1. xn_bf = LN1(x)
    ln_kernel<<<NTOK, 256, 0, stream>>>(x, ln1_s, ln1_b, xn_bf);
    // 2. xz = xn @ in_proj^T
    mfma_gemm_fast<0,0,0,1><<<dim3(32,32), 256, 0, stream>>>(xn_bf, ipbf, nullptr, xz,
        nullptr, nullptr, nullptr, NTOK, 2*D_INNER, DIM, DIM);
    // 3. conv + silu -> xcs f32 (scan) + xcs_bf (x_proj GEMM)
    conv_kernel<<<(NTOK*D_INNER)/256, 256, 0, stream>>>(xz, conv0, conv_w, conv_b, xcs, xcs_bf);
    // 4. proj = xcs @ x_proj^T  (K-split fast GEMM + reduce)
    cvt_pad_xproj<<<256, 256, 0, stream>>>(x_proj, xpw);
    xproj_ks_kernel<<<dim3(1,32,XPJ_KS), 256, 0, stream>>>(xcs_bf, xpw, xpart);
    xproj_reduce<<<(NTOK*96)/256, 256, 0, stream>>>(xpart, proj);
    // 5. dtp = softplus(proj[:,:64] @ dt_proj^T + dt_b)
    dt_gemm<<<dim3(16,32), 256, 0, stream>>>(proj, dt_proj, dt_b, dtp,
        NTOK, D_INNER, DT_RANK, 96);
    // 6. chunked scan
    scan_pass1<<<1024, 256, 0, stream>>>(dtp, proj, xcs, A_log, hend, sdt);
    scan_combine<<<256, 256, 0, stream>>>(hend, sdt, A_log, ssm0, hst);
    scan_pass3<<<1024, 256, 0, stream>>>(dtp, proj, xcs, xz, A_log, Dp, hst, ym_bf);
    // 6b. out_proj -> bf16 (R2; sdt dead after combine)
    cvt_w_kernel<<<512, 256, 0, stream>>>(out_proj, opbf, (DIM*D_INNER)/4);
    // 7. x1 = x + ym @ out_proj^T
    mfma_gemm_fast<0,1,0,1><<<dim3(8,32), 256, 0, stream>>>(ym_bf, opbf, x, x1,
        nullptr, nullptr, nullptr, NTOK, DIM, D_INNER, D_INNER);
    // 8. LN2 + router fused -> xn2bf, tw, ti, counts
    ln2_router_kernel<<<NTOK, 256, 0, stream>>>(x1, ln2_s, ln2_b, router_w,
        xn2bf, tw, ti, counts);
    // 9. slot assignment
    offs_kernel<<<1, 64, 0, stream>>>(counts, offs);
    assign_kernel<<<NTOK/256, 256, 0, stream>>>(ti, offs, cursors, tok_of_slot, slot_of);
    // 10. MoE: wg -> DTP region (dtp dead), wu -> XZ second half (xz dead); fused gate+up
    cvt_w_kernel<<<2048, 256, 0, stream>>>(w_gate, wgbf, (N_EXP*HID*DIM)/4);
    cvt_w_kernel<<<2048, 256, 0, stream>>>(w_up, wubf, (N_EXP*HID*DIM)/4);
    moe_gateup_fast<<<dim3(HID/128, 64, N_EXP), 256, 0, stream>>>(xn2bf, wgbf, wubf,
        tok_of_slot, counts, offs, H);
    // wd overwrites wg (dead after gateup)
    cvt_w_kernel<<<2048, 256, 0, stream>>>(w_down, wdbf, (N_EXP*DIM*HID)/4);
    mfma_gemm_fast<2,0,0,0><<<dim3(DIM/128, 64, N_EXP), 256, 0, stream>>>(H, wdbf, nullptr, dnout,
        tok_of_slot, counts, offs, NSLOT, DIM, HID, HID);
    // 11. out = x1 + weighted experts
    final_kernel<<<(NTOK*DIM/4)/256, 256, 0, stream>>>(x1, dnout, tw, slot_of, out);
}

// Round 7
// 739.981 us; speedup vs baseline: 5.1967x; 1.0058x over previous
//
#include <hip/hip_runtime.h>
#include <hip/hip_bf16.h>
#include <math.h>

#define DIM 1024
#define D_STATE 16
#define D_CONV 4
#define D_INNER 2048
#define DT_RANK 64
#define N_EXP 8
#define TOP_K 2
#define HID 2048
#define BB 2
#define TT 2048
#define NTOK (BB*TT)          // 4096
#define NSLOT (NTOK*TOP_K)    // 8192
#define EPS 1e-5f
#define NCHUNK 64
#define CLEN (TT/NCHUNK)      // 32
#define XPJ_KS 8
#define XPJ_KLEN (D_INNER/XPJ_KS)   // 256

// ---------------- workspace layout (float units) ----------------
#define OFF_R0   ((size_t)0)
#define OFF_R1   ((size_t)4194304)
#define OFF_R2   ((size_t)8388608)
#define OFF_XZ   ((size_t)10485760)
#define OFF_H    OFF_XZ
#define OFF_WU   ((size_t)18874368)
#define OFF_XCS  ((size_t)27262976)
#define OFF_DTP  ((size_t)35651584)
#define OFF_X1   ((size_t)44040192)
#define OFF_PROJ ((size_t)48234496)
#define OFF_TW   ((size_t)48627712)
#define OFF_INT  ((size_t)48635904)
#define OFF_XPW  ((size_t)48668672)
// int offsets (ints)
#define IO_TI    0
#define IO_CNT   8192
#define IO_CUR   8200
#define IO_OFS   8208
#define IO_TOK   8216
#define IO_SLOT  16408

typedef __attribute__((ext_vector_type(4))) float f32x4;
typedef __attribute__((ext_vector_type(8))) __bf16 bf16x8;
typedef __attribute__((ext_vector_type(4))) __bf16 bf16x4;

__device__ __forceinline__ float siluf(float v){ return v / (1.f + expf(-v)); }

__device__ __forceinline__ f32x4 mfma16(bf16x8 a, bf16x8 b, f32x4 c){
    return __builtin_amdgcn_mfma_f32_16x16x32_bf16(a, b, c, 0, 0, 0);
}

__device__ __forceinline__ void gload16(const void* g, void* l){
    __builtin_amdgcn_global_load_lds(
        (const __attribute__((address_space(1))) unsigned int*)g,
        (__attribute__((address_space(3))) unsigned int*)l, 16, 0, 0);
}

__device__ __forceinline__ void cvt_store16(__bf16* dst, f32x4 a0, f32x4 a1, f32x4 a2, f32x4 a3){
    bf16x8 p0, p1;
    #pragma unroll
    for (int j = 0; j < 4; ++j){
        p0[j]   = (__bf16)a0[j];
        p0[j+4] = (__bf16)a1[j];
        p1[j]   = (__bf16)a2[j];
        p1[j+4] = (__bf16)a3[j];
    }
    *(bf16x8*)dst = p0;
    *(bf16x8*)(dst+8) = p1;
}

// ---------------- weight f32 -> bf16 convert ----------------
__global__ __launch_bounds__(256) void cvt_w_kernel(const float* __restrict__ src,
    __bf16* __restrict__ dst, int n4)
{
    int i = blockIdx.x*256 + threadIdx.x;
    int stride = gridDim.x*256;
    for (; i < n4; i += stride){
        f32x4 v = *(const f32x4*)(src + (size_t)i*4);
        bf16x4 o;
        o[0] = (__bf16)v[0]; o[1] = (__bf16)v[1];
        o[2] = (__bf16)v[2]; o[3] = (__bf16)v[3];
        *(bf16x4*)(dst + (size_t)i*4) = o;
    }
}

// x_proj (96x2048) -> padded bf16 (128x2048), rows 96..127 = 0
__global__ __launch_bounds__(256) void cvt_pad_xproj(const float* __restrict__ src,
    __bf16* __restrict__ dst)
{
    int i = blockIdx.x*256 + threadIdx.x;
    int base = i*4;
    int row = base >> 11;
    bf16x4 o;
    if (row < 96){
        f32x4 v = *(const f32x4*)(src + base);
        o[0] = (__bf16)v[0]; o[1] = (__bf16)v[1];
        o[2] = (__bf16)v[2]; o[3] = (__bf16)v[3];
    } else {
        o[0] = (__bf16)0.f; o[1] = (__bf16)0.f;
        o[2] = (__bf16)0.f; o[3] = (__bf16)0.f;
    }
    *(bf16x4*)(dst + base) = o;
}

// ---------------- LayerNorm (LN1): bf16 out ----------------
__global__ __launch_bounds__(256) void ln_kernel(const float* __restrict__ x,
    const float* __restrict__ s, const float* __restrict__ b,
    __bf16* __restrict__ obf)
{
    int t = blockIdx.x;
    const float* xp = x + (size_t)t * DIM;
    float v[4]; float sum = 0.f, sq = 0.f;
    #pragma unroll
    for (int j = 0; j < 4; ++j){
        v[j] = xp[threadIdx.x + 256*j];
        sum += v[j]; sq += v[j]*v[j];
    }
    #pragma unroll
    for (int off = 32; off; off >>= 1){
        sum += __shfl_xor(sum, off, 64);
        sq  += __shfl_xor(sq , off, 64);
    }
    __shared__ float red[4][2];
    int w = threadIdx.x >> 6, lane = threadIdx.x & 63;
    if (lane == 0){ red[w][0] = sum; red[w][1] = sq; }
    __syncthreads();
    sum = red[0][0]+red[1][0]+red[2][0]+red[3][0];
    sq  = red[0][1]+red[1][1]+red[2][1]+red[3][1];
    float mu = sum * (1.f/DIM);
    float var = sq * (1.f/DIM) - mu*mu;
    float r = rsqrtf(var + EPS);
    #pragma unroll
    for (int j = 0; j < 4; ++j){
        int d = threadIdx.x + 256*j;
        obf[(size_t)t*DIM + d] = (__bf16)((v[j]-mu)*r*s[d] + b[d]);
    }
}

// ---------------- LN2 fused with router ----------------
__global__ __launch_bounds__(256) void ln2_router_kernel(const float* __restrict__ x,
    const float* __restrict__ s, const float* __restrict__ b,
    const float* __restrict__ rw, __bf16* __restrict__ obf,
    float* __restrict__ tw, int* __restrict__ ti, int* __restrict__ counts)
{
    int t = blockIdx.x;
    const float* xp = x + (size_t)t * DIM;
    float v[4]; float sum = 0.f, sq = 0.f;
    #pragma unroll
    for (int j = 0; j < 4; ++j){
        v[j] = xp[threadIdx.x + 256*j];
        sum += v[j]; sq += v[j]*v[j];
    }
    #pragma unroll
    for (int off = 32; off; off >>= 1){
        sum += __shfl_xor(sum, off, 64);
        sq  += __shfl_xor(sq , off, 64);
    }
    __shared__ float red[4][2];
    __shared__ float red2[4][N_EXP];
    int w = threadIdx.x >> 6, lane = threadIdx.x & 63;
    if (lane == 0){ red[w][0] = sum; red[w][1] = sq; }
    __syncthreads();
    sum = red[0][0]+red[1][0]+red[2][0]+red[3][0];
    sq  = red[0][1]+red[1][1]+red[2][1]+red[3][1];
    float mu = sum * (1.f/DIM);
    float var = sq * (1.f/DIM) - mu*mu;
    float r = rsqrtf(var + EPS);
    float p[N_EXP] = {};
    #pragma unroll
    for (int j = 0; j < 4; ++j){
        int d = threadIdx.x + 256*j;
        float o = (v[j]-mu)*r*s[d] + b[d];
        obf[(size_t)t*DIM + d] = (__bf16)o;
        #pragma unroll
        for (int e = 0; e < N_EXP; ++e) p[e] += o * rw[e*DIM + d];
    }
    #pragma unroll
    for (int e = 0; e < N_EXP; ++e){
        #pragma unroll
        for (int off = 32; off; off >>= 1) p[e] += __shfl_xor(p[e], off, 64);
    }
    if (lane == 0){
        #pragma unroll
        for (int e = 0; e < N_EXP; ++e) red2[w][e] = p[e];
    }
    __syncthreads();
    if (threadIdx.x == 0){
        float q[N_EXP];
        #pragma unroll
        for (int e = 0; e < N_EXP; ++e)
            q[e] = red2[0][e]+red2[1][e]+red2[2][e]+red2[3][e];
        float mx = q[0];
        #pragma unroll
        for (int e = 1; e < N_EXP; ++e) mx = fmaxf(mx, q[e]);
        float ssum = 0.f;
        #pragma unroll
        for (int e = 0; e < N_EXP; ++e){ q[e] = expf(q[e]-mx); ssum += q[e]; }
        int i0 = 0;
        #pragma unroll
        for (int e = 1; e < N_EXP; ++e) if (q[e] > q[i0]) i0 = e;
        int i1 = (i0 == 0) ? 1 : 0;
        #pragma unroll
        for (int e = 0; e < N_EXP; ++e) if (e != i0 && q[e] > q[i1]) i1 = e;
        float w0 = q[i0]/ssum, w1 = q[i1]/ssum;
        float sw = w0 + w1; w0 /= sw; w1 /= sw;
        tw[t*2] = w0; tw[t*2+1] = w1;
        ti[t*2] = i0; ti[t*2+1] = i1;
        atomicAdd(&counts[i0], 1);
        atomicAdd(&counts[i1], 1);
    }
}

// ============ fast bf16 MFMA GEMM: double-buffered prefetch + XOR swizzle ============
// Staging: lane l of wave w loads 16B for LDS slot (row=2w*16+(l>>2) [or +16], cb=l&3),
// which must hold global colblock cb ^ ((l>>3)&3) (XOR swizzle, rule #21 both-sides).
// Read: row r, colblock cb lives at slot cb ^ ((r>>1)&3); lane-constant since
// (r>>1)&3 == (fr>>1)&3 for r = wm|wn + i*16 + fr.
// Pipeline: stage(next) -> s_waitcnt vmcnt(4) (counted, never 0 mid-loop) ->
// raw s_barrier -> ds_read+MFMA(cur) -> raw s_barrier -> swap.
// MODE: 0 dense, 1 gather A via tok_of_slot, 2 contiguous slot rows
// EPI : 0 none, 1 +resid f32 ; CBF: C bf16 ; SWZ: XCD swizzle
template<int MODE, int EPI, int CBF, int SWZ>
__global__ __launch_bounds__(256,3) void mfma_gemm_fast(
    const __bf16* __restrict__ A, const __bf16* __restrict__ W,
    const void* __restrict__ RG, void* __restrict__ Cv,
    const int* __restrict__ tok_of_slot, const int* __restrict__ counts,
    const int* __restrict__ offs, int M, int N, int K, int lda)
{
    int bx = blockIdx.x, by = blockIdx.y;
    if (SWZ){
        int nwg = gridDim.x*gridDim.y;
        int id = by*gridDim.x + bx;
        int swz = (id & 7)*(nwg >> 3) + (id >> 3);
        bx = swz % gridDim.x; by = swz / gridDim.x;
    }
    int e    = (MODE == 0) ? 0 : blockIdx.z;
    int cnt  = (MODE == 0) ? M : counts[e];
    int base = (MODE == 0) ? 0 : offs[e];
    int m0 = by * 128;
    if (m0 >= cnt) return;
    int n0 = bx * 128;
    const __bf16* We = W + (size_t)e * N * K;

    __shared__ __bf16 As[2*128*32];
    __shared__ __bf16 Ws[2*128*32];

    int tid = threadIdx.x;
    int wave = tid >> 6, lane = tid & 63;
    int c0 = wave*2, c1 = wave*2 + 1;
    int lr0 = c0*16 + (lane >> 2);
    int lr1 = c1*16 + (lane >> 2);
    int koff = (((lane & 3) ^ ((lane >> 3) & 3)) * 8);   // swizzled source colblock

    int ar0, ar1;
    {
        int m0c = m0 + lr0, m1c = m0 + lr1;
        if (MODE != 0){
            if (m0c >= cnt) m0c = cnt - 1;
            if (m1c >= cnt) m1c = cnt - 1;
        }
        if (MODE == 1){ ar0 = tok_of_slot[base + m0c]; ar1 = tok_of_slot[base + m1c]; }
        else if (MODE == 2){ ar0 = base + m0c; ar1 = base + m1c; }
        else { ar0 = m0c; ar1 = m1c; }
    }
    const __bf16* aS0 = A + (size_t)ar0 * lda + koff;
    const __bf16* aS1 = A + (size_t)ar1 * lda + koff;
    const __bf16* wS0 = We + (size_t)(n0 + lr0) * K + koff;
    const __bf16* wS1 = We + (size_t)(n0 + lr1) * K + koff;
    __bf16* ldsA0 = As + c0*512;
    __bf16* ldsA1 = As + c1*512;
    __bf16* ldsW0 = Ws + c0*512;
    __bf16* ldsW1 = Ws + c1*512;

    int wm = (wave >> 1) * 64, wn = (wave & 1) * 64;
    int fr = lane & 15;
    const int scb = (((lane >> 4) ^ ((lane >> 1) & 3)) * 8);  // swizzled read colblock

    f32x4 acc[4][4];
    #pragma unroll
    for (int i = 0; i < 4; ++i)
        #pragma unroll
        for (int j = 0; j < 4; ++j)
            acc[i][j] = (f32x4){0.f, 0.f, 0.f, 0.f};

    // prologue: stage tile 0 into buffer 0
    gload16(aS0, ldsA0);
    gload16(aS1, ldsA1);
    gload16(wS0, ldsW0);
    gload16(wS1, ldsW1);

    int bo = 0;
    for (int k0 = 0; k0 < K; k0 += 32){
        int nbo = bo ^ 4096;
        if (k0 + 32 < K){
            gload16(aS0 + k0 + 32, ldsA0 + nbo);
            gload16(aS1 + k0 + 32, ldsA1 + nbo);
            gload16(wS0 + k0 + 32, ldsW0 + nbo);
            gload16(wS1 + k0 + 32, ldsW1 + nbo);
            asm volatile("s_waitcnt vmcnt(4)" ::: "memory");
        } else {
            asm volatile("s_waitcnt vmcnt(0)" ::: "memory");
        }
        __builtin_amdgcn_s_barrier();
        bf16x8 af[4], bf[4];
        #pragma unroll
        for (int i = 0; i < 4; ++i)
            af[i] = *(const bf16x8*)&As[bo + (wm + i*16 + fr)*32 + scb];
        #pragma unroll
        for (int j = 0; j < 4; ++j)
            bf[j] = *(const bf16x8*)&Ws[bo + (wn + j*16 + fr)*32 + scb];
        #pragma unroll
        for (int i = 0; i < 4; ++i)
            #pragma unroll
            for (int j = 0; j < 4; ++j)
                acc[i][j] = mfma16(af[i], bf[j], acc[i][j]);
        __builtin_amdgcn_s_barrier();
        bo = nbo;
    }

    int orow = (lane >> 4) * 4;
    int ocol = lane & 15;
    #pragma unroll
    for (int i = 0; i < 4; ++i){
        #pragma unroll
        for (int jj = 0; jj < 4; ++jj){
            #pragma unroll
            for (int j = 0; j < 4; ++j){
                int m = m0 + wm + i*16 + orow + j;
                int n = n0 + wn + jj*16 + ocol;
                if (m < cnt){
                    size_t row = (size_t)(base + m);
                    float v = acc[i][jj][j];
                    if (EPI == 1) v += ((const float*)RG)[row * (size_t)N + n];
                    if (CBF) ((__bf16*)Cv)[row * (size_t)N + n] = (__bf16)v;
                    else     ((float* )Cv)[row * (size_t)N + n] = v;
                }
            }
        }
    }
}

// ---------------- fused MoE gate+up GEMM (prefetch + swizzle) ----------------
__global__ __launch_bounds__(256,2) void moe_gateup_fast(
    const __bf16* __restrict__ A, const __bf16* __restrict__ Wg,
    const __bf16* __restrict__ Wu, const int* __restrict__ tok_of_slot,
    const int* __restrict__ counts, const int* __restrict__ offs,
    __bf16* __restrict__ H)
{
    int e = blockIdx.z;
    int cnt = counts[e];
    int base = offs[e];
    int m0 = blockIdx.y * 128;
    if (m0 >= cnt) return;
    int n0 = blockIdx.x * 128;
    const __bf16* Wge = Wg + (size_t)e * HID * DIM;
    const __bf16* Wue = Wu + (size_t)e * HID * DIM;

    __shared__ __bf16 As[2*128*32];
    __shared__ __bf16 Gs[2*128*32];
    __shared__ __bf16 Us[2*128*32];

    int tid = threadIdx.x;
    int wave = tid >> 6, lane = tid & 63;
    int c0 = wave*2, c1 = wave*2 + 1;
    int lr0 = c0*16 + (lane >> 2);
    int lr1 = c1*16 + (lane >> 2);
    int koff = (((lane & 3) ^ ((lane >> 3) & 3)) * 8);

    int m0c = m0 + lr0, m1c = m0 + lr1;
    if (m0c >= cnt) m0c = cnt - 1;
    if (m1c >= cnt) m1c = cnt - 1;
    int ar0 = tok_of_slot[base + m0c];
    int ar1 = tok_of_slot[base + m1c];

    const __bf16* aS0 = A + (size_t)ar0 * DIM + koff;
    const __bf16* aS1 = A + (size_t)ar1 * DIM + koff;
    const __bf16* gS0 = Wge + (size_t)(n0 + lr0) * DIM + koff;
    const __bf16* gS1 = Wge + (size_t)(n0 + lr1) * DIM + koff;
    const __bf16* uS0 = Wue + (size_t)(n0 + lr0) * DIM + koff;
    const __bf16* uS1 = Wue + (size_t)(n0 + lr1) * DIM + koff;
    __bf16* ldsA0 = As + c0*512;
    __bf16* ldsA1 = As + c1*512;
    __bf16* ldsG0 = Gs + c0*512;
    __bf16* ldsG1 = Gs + c1*512;
    __bf16* ldsU0 = Us + c0*512;
    __bf16* ldsU1 = Us + c1*512;

    int wm = (wave >> 1) * 64, wn = (wave & 1) * 64;
    int fr = lane & 15;
    const int scb = (((lane >> 4) ^ ((lane >> 1) & 3)) * 8);

    f32x4 accg[4][4], accu[4][4];
    #pragma unroll
    for (int i = 0; i < 4; ++i)
        #pragma unroll
        for (int j = 0; j < 4; ++j){
            accg[i][j] = (f32x4){0.f, 0.f, 0.f, 0.f};
            accu[i][j] = (f32x4){0.f, 0.f, 0.f, 0.f};
        }

    gload16(aS0, ldsA0);
    gload16(aS1, ldsA1);
    gload16(gS0, ldsG0);
    gload16(gS1, ldsG1);
    gload16(uS0, ldsU0);
    gload16(uS1, ldsU1);

    int bo = 0;
    for (int k0 = 0; k0 < DIM; k0 += 32){
        int nbo = bo ^ 4096;
        if (k0 + 32 < DIM){
            gload16(aS0 + k0 + 32, ldsA0 + nbo);
            gload16(aS1 + k0 + 32, ldsA1 + nbo);
            gload16(gS0 + k0 + 32, ldsG0 + nbo);
            gload16(gS1 + k0 + 32, ldsG1 + nbo);
            gload16(uS0 + k0 + 32, ldsU0 + nbo);
            gload16(uS1 + k0 + 32, ldsU1 + nbo);
            asm volatile("s_waitcnt vmcnt(6)" ::: "memory");
        } else {
            asm volatile("s_waitcnt vmcnt(0)" ::: "memory");
        }
        __builtin_amdgcn_s_barrier();
        bf16x8 af[4], gf[4], uf[4];
        #pragma unroll
        for (int i = 0; i < 4; ++i){
            af[i] = *(const bf16x8*)&As[bo + (wm + i*16 + fr)*32 + scb];
            gf[i] = *(const bf16x8*)&Gs[bo + (wn + i*16 + fr)*32 + scb];
            uf[i] = *(const bf16x8*)&Us[bo + (wn + i*16 + fr)*32 + scb];
        }
        #pragma unroll
        for (int i = 0; i < 4; ++i)
            #pragma unroll
            for (int j = 0; j < 4; ++j){
                accg[i][j] = mfma16(af[i], gf[j], accg[i][j]);
                accu[i][j] = mfma16(af[i], uf[j], accu[i][j]);
            }
        __builtin_amdgcn_s_barrier();
        bo = nbo;
    }

    int orow = (lane >> 4) * 4;
    int ocol = lane & 15;
    #pragma unroll
    for (int i = 0; i < 4; ++i){
        #pragma unroll
        for (int jj = 0; jj < 4; ++jj){
            #pragma unroll
            for (int j = 0; j < 4; ++j){
                int m = m0 + wm + i*16 + orow + j;
                if (m < cnt){
                    int n = n0 + wn + jj*16 + ocol;
                    size_t row = (size_t)(base + m);
                    float g = accg[i][jj][j], u = accu[i][jj][j];
                    H[row * (size_t)HID + n] = (__bf16)(siluf(g) * u);
                }
            }
        }
    }
}

// ---------------- x_proj K-split GEMM (prefetch + swizzle) ----------------
__global__ __launch_bounds__(256,3) void xproj_ks_kernel(
    const __bf16* __restrict__ A, const __bf16* __restrict__ W,
    float* __restrict__ Cpart)
{
    int m0 = blockIdx.y * 128;
    int kbeg = blockIdx.z * XPJ_KLEN;

    __shared__ __bf16 As[2*128*32];
    __shared__ __bf16 Ws[2*128*32];

    int tid = threadIdx.x;
    int wave = tid >> 6, lane = tid & 63;
    int c0 = wave*2, c1 = wave*2 + 1;
    int lr0 = c0*16 + (lane >> 2);
    int lr1 = c1*16 + (lane >> 2);
    int koff = (((lane & 3) ^ ((lane >> 3) & 3)) * 8);

    const __bf16* aS0 = A + (size_t)(m0 + lr0) * D_INNER + kbeg + koff;
    const __bf16* aS1 = A + (size_t)(m0 + lr1) * D_INNER + kbeg + koff;
    const __bf16* wS0 = W + (size_t)lr0 * D_INNER + kbeg + koff;
    const __bf16* wS1 = W + (size_t)lr1 * D_INNER + kbeg + koff;
    __bf16* ldsA0 = As + c0*512;
    __bf16* ldsA1 = As + c1*512;
    __bf16* ldsW0 = Ws + c0*512;
    __bf16* ldsW1 = Ws + c1*512;

    int wm = (wave >> 1) * 64, wn = (wave & 1) * 64;
    int fr = lane & 15;
    const int scb = (((lane >> 4) ^ ((lane >> 1) & 3)) * 8);

    f32x4 acc[4][4];
    #pragma unroll
    for (int i = 0; i < 4; ++i)
        #pragma unroll
        for (int j = 0; j < 4; ++j)
            acc[i][j] = (f32x4){0.f, 0.f, 0.f, 0.f};

    gload16(aS0, ldsA0);
    gload16(aS1, ldsA1);
    gload16(wS0, ldsW0);
    gload16(wS1, ldsW1);

    int bo = 0;
    for (int k0 = 0; k0 < XPJ_KLEN; k0 += 32){
        int nbo = bo ^ 4096;
        if (k0 + 32 < XPJ_KLEN){
            gload16(aS0 + k0 + 32, ldsA0 + nbo);
            gload16(aS1 + k0 + 32, ldsA1 + nbo);
            gload16(wS0 + k0 + 32, ldsW0 + nbo);
            gload16(wS1 + k0 + 32, ldsW1 + nbo);
            asm volatile("s_waitcnt vmcnt(4)" ::: "memory");
        } else {
            asm volatile("s_waitcnt vmcnt(0)" ::: "memory");
        }
        __builtin_amdgcn_s_barrier();
        bf16x8 af[4], bf[4];
        #pragma unroll
        for (int i = 0; i < 4; ++i)
            af[i] = *(const bf16x8*)&As[bo + (wm + i*16 + fr)*32 + scb];
        #pragma unroll
        for (int j = 0; j < 4; ++j)
            bf[j] = *(const bf16x8*)&Ws[bo + (wn + j*16 + fr)*32 + scb];
        #pragma unroll
        for (int i = 0; i < 4; ++i)
            #pragma unroll
            for (int j = 0; j < 4; ++j)
                acc[i][j] = mfma16(af[i], bf[j], acc[i][j]);
        __builtin_amdgcn_s_barrier();
        bo = nbo;
    }

    float* Cz = Cpart + (size_t)blockIdx.z * NTOK * 128;
    int orow = (lane >> 4) * 4;
    int ocol = lane & 15;
    #pragma unroll
    for (int i = 0; i < 4; ++i){
        #pragma unroll
        for (int jj = 0; jj < 4; ++jj){
            #pragma unroll
            for (int j = 0; j < 4; ++j){
                int m = m0 + wm + i*16 + orow + j;
                int n = wn + jj*16 + ocol;
                Cz[(size_t)m * 128 + n] = acc[i][jj][j];
            }
        }
    }
}

__global__ __launch_bounds__(256) void xproj_reduce(const float* __restrict__ Cpart,
    float* __restrict__ proj)
{
    int idx = blockIdx.x*256 + threadIdx.x;
    int t = idx / 96, n = idx - t*96;
    float s = 0.f;
    #pragma unroll
    for (int z = 0; z < XPJ_KS; ++z)
        s += Cpart[(size_t)z * NTOK * 128 + (size_t)t * 128 + n];
    proj[idx] = s;
}

// ---------------- reg-staging MFMA GEMM (dt: softplus(A@W^T + bias)) ----------------
__global__ __launch_bounds__(256,2) void dt_gemm(
    const float* __restrict__ A, const float* __restrict__ W,
    const float* __restrict__ bias, float* __restrict__ C,
    int M, int N, int K, int lda)
{
    int m0 = blockIdx.y * 128;
    int n0 = blockIdx.x * 128;

    __shared__ __bf16 As[128*32];
    __shared__ __bf16 Ws[128*32];

    int tid = threadIdx.x;
    int srow = tid >> 1;
    int scol = (tid & 1) * 16;

    const float* af = A + (size_t)(m0 + srow) * lda + scol;
    const float* wptr = W + (size_t)(n0 + srow) * K + scol;

    f32x4 raf[4], rw[4];
    #pragma unroll
    for (int q = 0; q < 4; ++q){
        raf[q] = *(const f32x4*)(af + q*4);
        rw[q]  = *(const f32x4*)(wptr + q*4);
    }

    int wave = tid >> 6, lane = tid & 63;
    int wm = (wave >> 1) * 64, wn = (wave & 1) * 64;
    int fr = lane & 15, fk = (lane >> 4) * 8;

    f32x4 acc[4][4];
    #pragma unroll
    for (int i = 0; i < 4; ++i)
        #pragma unroll
        for (int j = 0; j < 4; ++j)
            acc[i][j] = (f32x4){0.f, 0.f, 0.f, 0.f};

    for (int k0 = 0; k0 < K; k0 += 32){
        cvt_store16(&As[srow*32 + scol], raf[0], raf[1], raf[2], raf[3]);
        cvt_store16(&Ws[srow*32 + scol], rw[0], rw[1], rw[2], rw[3]);
        __syncthreads();
        if (k0 + 32 < K){
            #pragma unroll
            for (int q = 0; q < 4; ++q){
                raf[q] = *(const f32x4*)(af + k0 + 32 + q*4);
                rw[q]  = *(const f32x4*)(wptr + k0 + 32 + q*4);
            }
        }
        bf16x8 afr[4], bfr[4];
        #pragma unroll
        for (int i = 0; i < 4; ++i)
            afr[i] = *(const bf16x8*)&As[(wm + i*16 + fr)*32 + fk];
        #pragma unroll
        for (int i = 0; i < 4; ++i)
            bfr[i] = *(const bf16x8*)&Ws[(wn + i*16 + fr)*32 + fk];
        #pragma unroll
        for (int i = 0; i < 4; ++i)
            #pragma unroll
            for (int j = 0; j < 4; ++j)
                acc[i][j] = mfma16(afr[i], bfr[j], acc[i][j]);
        __syncthreads();
    }

    int orow = (lane >> 4) * 4;
    int ocol = lane & 15;
    #pragma unroll
    for (int i = 0; i < 4; ++i){
        #pragma unroll
        for (int jj = 0; jj < 4; ++jj){
            #pragma unroll
            for (int j = 0; j < 4; ++j){
                int m = m0 + wm + i*16 + orow + j;
                int n = n0 + wn + jj*16 + ocol;
                if (m < M && n < N){
                    float v = acc[i][jj][j] + bias[n];
                    v = (v > 20.f) ? v : log1pf(expf(v));
                    C[(size_t)m * N + n] = v;
                }
            }
        }
    }
}

// ---------------- conv: f32 + bf16 outputs ----------------
__global__ __launch_bounds__(256) void conv_kernel(const float* __restrict__ xz,
    const float* __restrict__ cs, const float* __restrict__ cw,
    const float* __restrict__ cb, float* __restrict__ xcs,
    __bf16* __restrict__ xcs_bf)
{
    int idx = blockIdx.x*256 + threadIdx.x;
    int d = idx & (D_INNER-1);
    int bt = idx >> 11;
    int b = bt >> 11;
    int t = bt & (TT-1);
    float acc = cb[d];
    #pragma unroll
    for (int k = 0; k < 4; ++k){
        int tau = t + k - 3;
        float xv;
        if (tau >= 0) xv = xz[(size_t)(b*TT + tau)*(2*D_INNER) + d];
        else          xv = cs[((size_t)b*D_INNER + d)*3 + (tau + 3)];
        acc += cw[d*4 + k] * xv;
    }
    float v = siluf(acc);
    xcs[idx] = v;
    xcs_bf[idx] = (__bf16)v;
}

// ---------------- chunked SSM scan ----------------
__global__ __launch_bounds__(256) void scan_pass1(const float* __restrict__ dtp,
    const float* __restrict__ proj, const float* __restrict__ xcs,
    const float* __restrict__ A_log, float* __restrict__ hend,
    float* __restrict__ sumdt)
{
    int gid = blockIdx.x*256 + threadIdx.x;
    int bd = gid & (BB*D_INNER-1);
    int chunk = gid >> 12;
    int b = bd >> 11, d = bd & (D_INNER-1);
    float As[D_STATE], h[D_STATE];
    #pragma unroll
    for (int s = 0; s < D_STATE; ++s){
        As[s] = -__expf(A_log[d*D_STATE + s]);
        h[s] = 0.f;
    }
    float sdt = 0.f;
    int base = b*TT + chunk*CLEN;
    for (int t = 0; t < CLEN; ++t){
        size_t bt = (size_t)(base + t);
        float dt = dtp[bt*D_INNER + d];
        float x  = xcs[bt*D_INNER + d];
        f32x4 Bv[4];
        #pragma unroll
        for (int q = 0; q < 4; ++q) Bv[q] = *(const f32x4*)(proj + bt*96 + DT_RANK + q*4);
        float dtx = dt * x;
        sdt += dt;
        #pragma unroll
        for (int s = 0; s < D_STATE; ++s)
            h[s] = __expf(dt*As[s])*h[s] + Bv[s>>2][s&3]*dtx;
    }
    size_t hb = ((size_t)bd*NCHUNK + chunk)*D_STATE;
    #pragma unroll
    for (int q = 0; q < 4; ++q)
        *(f32x4*)(hend + hb + q*4) = (f32x4){h[q*4], h[q*4+1], h[q*4+2], h[q*4+3]};
    sumdt[bd*NCHUNK + chunk] = sdt;
}

__global__ __launch_bounds__(256) void scan_combine(const float* __restrict__ hend,
    const float* __restrict__ sumdt, const float* __restrict__ A_log,
    const float* __restrict__ ssm0, float* __restrict__ hstart)
{
    int gid = blockIdx.x*256 + threadIdx.x;
    int s = gid & 15;
    int bd = gid >> 4;
    int b = bd >> 11, d = bd & (D_INNER-1);
    float As = -__expf(A_log[d*D_STATE + s]);
    float h = ssm0[((size_t)b*D_INNER + d)*D_STATE + s];
    for (int c = 0; c < NCHUNK; ++c){
        size_t idx = ((size_t)bd*NCHUNK + c)*D_STATE + s;
        hstart[idx] = h;
        h = hend[idx] + __expf(As * sumdt[bd*NCHUNK + c]) * h;
    }
}

__global__ __launch_bounds__(256) void scan_pass3(const float* __restrict__ dtp,
    const float* __restrict__ proj, const float* __restrict__ xcs,
    const float* __restrict__ xz, const float* __restrict__ A_log,
    const float* __restrict__ Dp, const float* __restrict__ hstart,
    __bf16* __restrict__ ym)
{
    int gid = blockIdx.x*256 + threadIdx.x;
    int bd = gid & (BB*D_INNER-1);
    int chunk = gid >> 12;
    int b = bd >> 11, d = bd & (D_INNER-1);
    float As[D_STATE], h[D_STATE];
    #pragma unroll
    for (int s = 0; s < D_STATE; ++s)
        As[s] = -__expf(A_log[d*D_STATE + s]);
    size_t hb = ((size_t)bd*NCHUNK + chunk)*D_STATE;
    #pragma unroll
    for (int q = 0; q < 4; ++q){
        f32x4 hv = *(const f32x4*)(hstart + hb + q*4);
        h[q*4] = hv[0]; h[q*4+1] = hv[1]; h[q*4+2] = hv[2]; h[q*4+3] = hv[3];
    }
    float Dd = Dp[d];
    int base = b*TT + chunk*CLEN;
    for (int t = 0; t < CLEN; ++t){
        size_t bt = (size_t)(base + t);
        float dt = dtp[bt*D_INNER + d];
        float x  = xcs[bt*D_INNER + d];
        f32x4 Bv[4], Cv[4];
        #pragma unroll
        for (int q = 0; q < 4; ++q){
            Bv[q] = *(const f32x4*)(proj + bt*96 + DT_RANK + q*4);
            Cv[q] = *(const f32x4*)(proj + bt*96 + DT_RANK + D_STATE + q*4);
        }
        float dtx = dt * x;
        float p = 0.f;
        #pragma unroll
        for (int s = 0; s < D_STATE; ++s){
            h[s] = __expf(dt*As[s])*h[s] + Bv[s>>2][s&3]*dtx;
            p += h[s] * Cv[s>>2][s&3];
        }
        float y = p + Dd*x;
        float z = xz[bt*(2*D_INNER) + D_INNER + d];
        float sz = z / (1.f + __expf(-z));
        ym[bt*D_INNER + d] = (__bf16)(y * sz);
    }
}

// ---------------- slot assignment ----------------
__global__ void offs_kernel(const int* __restrict__ counts, int* __restrict__ offs)
{
    if (threadIdx.x == 0 && blockIdx.x == 0){
        int s = 0;
        for (int e = 0; e < N_EXP; ++e){ offs[e] = s; s += counts[e]; }
    }
}

__global__ __launch_bounds__(256) void assign_kernel(const int* __restrict__ ti,
    const int* __restrict__ offs, int* __restrict__ cursors,
    int* __restrict__ tok_of_slot, int* __restrict__ slot_of)
{
    int t = blockIdx.x*256 + threadIdx.x;
    if (t >= NTOK) return;
    #pragma unroll
    for (int k = 0; k < TOP_K; ++k){
        int e = ti[t*2 + k];
        int pos = atomicAdd(&cursors[e], 1);
        int slot = offs[e] + pos;
        tok_of_slot[slot] = t;
        slot_of[t*2 + k] = slot;
    }
}

// ---------------- final combine ----------------
__global__ __launch_bounds__(256) void final_kernel(const float* __restrict__ x1,
    const float* __restrict__ down_out, const float* __restrict__ tw,
    const int* __restrict__ slot_of, float* __restrict__ out)
{
    int idx4 = blockIdx.x*256 + threadIdx.x;
    int t = idx4 >> 8;
    int c = idx4 & 255;
    float w0 = tw[t*2], w1 = tw[t*2+1];
    size_t s0 = (size_t)slot_of[t*2] * DIM;
    size_t s1 = (size_t)slot_of[t*2+1] * DIM;
    float4 a = *(const float4*)(x1 + (size_t)t*DIM + c*4);
    float4 d0 = *(const float4*)(down_out + s0 + c*4);
    float4 d1 = *(const float4*)(down_out + s1 + c*4);
    float4 r;
    r.x = a.x + w0*d0.x + w1*d1.x;
    r.y = a.y + w0*d0.y + w1*d1.y;
    r.z = a.z + w0*d0.z + w1*d1.z;
    r.w = a.w + w0*d0.w + w1*d1.w;
    *(float4*)(out + (size_t)t*DIM + c*4) = r;
}

extern "C" void kernel_launch(void* const* d_in, const int* in_sizes, int n_in,
                              void* d_out, int out_size, void* d_ws, size_t ws_size,
                              hipStream_t stream)
{
    const float* x        = (const float*)d_in[0];
    const float* ssm0     = (const float*)d_in[1];
    const float* conv0    = (const float*)d_in[2];
    const float* ln1_s    = (const float*)d_in[3];
    const float* ln1_b    = (const float*)d_in[4];
    const float* ln2_s    = (const float*)d_in[5];
    const float* ln2_b    = (const float*)d_in[6];
    const float* in_proj  = (const float*)d_in[7];
    const float* conv_w   = (const float*)d_in[8];
    const float* conv_b   = (const float*)d_in[9];
    const float* x_proj   = (const float*)d_in[10];
    const float* dt_proj  = (const float*)d_in[11];
    const float* dt_b     = (const float*)d_in[12];
    const float* A_log    = (const float*)d_in[13];
    const float* Dp       = (const float*)d_in[14];
    const float* out_proj = (const float*)d_in[15];
    const float* router_w = (const float*)d_in[16];
    const float* w_gate   = (const float*)d_in[17];
    const float* w_up     = (const float*)d_in[18];
    const float* w_down   = (const float*)d_in[19];
    float* out = (float*)d_out;

    float* ws = (float*)d_ws;
    __bf16* xn_bf  = (__bf16*)(ws + OFF_R0);
    float*  hend   = ws + OFF_R0;
    __bf16* ym_bf  = (__bf16*)(ws + OFF_R0);
    float*  xpart  = ws + OFF_R1;
    float*  hst    = ws + OFF_R1;
    float*  sdt    = ws + OFF_R2;
    __bf16* opbf   = (__bf16*)(ws + OFF_R2);
    __bf16* xn2bf  = (__bf16*)(ws + OFF_R2);
    float*  xz     = ws + OFF_XZ;
    __bf16* H      = (__bf16*)(ws + OFF_H);
    __bf16* wubf   = (__bf16*)(ws + OFF_WU);
    float*  xcs    = ws + OFF_XCS;
    float*  dnout  = ws + OFF_XCS;
    float*  dtp    = ws + OFF_DTP;
    __bf16* ipbf   = (__bf16*)(ws + OFF_DTP);
    __bf16* wgbf   = (__bf16*)(ws + OFF_DTP);
    __bf16* wdbf   = (__bf16*)(ws + OFF_DTP);
    __bf16* xcs_bf = (__bf16*)(ws + OFF_X1);
    float*  x1     = ws + OFF_X1;
    float*  proj   = ws + OFF_PROJ;
    float*  tw     = ws + OFF_TW;
    __bf16* xpw    = (__bf16*)(ws + OFF_XPW);
    int*    ip     = (int*)(ws + OFF_INT);
    int* ti          = ip + IO_TI;
    int* counts      = ip + IO_CNT;
    int* cursors     = ip + IO_CUR;
    int* offs        = ip + IO_OFS;
    int* tok_of_slot = ip + IO_TOK;
    int* slot_of     = ip + IO_SLOT;

    hipMemsetAsync(counts, 0, 16*sizeof(int), stream);

    // 0a. in_proj -> bf16 (dtp region, dead until step 5)
    cvt_w_kernel<<<1024, 256, 0, stream>>>(in_proj, ipbf, (2*D_INNER*DIM)/4);
    // 1. xn_bf = LN1(x)
    ln_kernel<<<NTOK, 256, 0, stream>>>(x, ln1_s, ln1_b, xn_bf);
    // 2. xz = xn @ in_proj^T
    mfma_gemm_fast<0,0,0,1><<<dim3(32,32), 256, 0, stream>>>(xn_bf, ipbf, nullptr, xz,
        nullptr, nullptr, nullptr, NTOK, 2*D_INNER, DIM, DIM);
    // 3. conv + silu -> xcs f32 (scan) + xcs_bf (x_proj GEMM)
    conv_kernel<<<(NTOK*D_INNER)/256, 256, 0, stream>>>(xz, conv0, conv_w, conv_b, xcs, xcs_bf);
    // 4. proj = xcs @ x_proj^T  (K-split fast GEMM + reduce)
    cvt_pad_xproj<<<256, 256, 0, stream>>>(x_proj, xpw);
    xproj_ks_kernel<<<dim3(1,32,XPJ_KS), 256, 0, stream>>>(xcs_bf, xpw, xpart);
    xproj_reduce<<<(NTOK*96)/256, 256, 0, stream>>>(xpart, proj);
    // 5. dtp = softplus(proj[:,:64] @ dt_proj^T + dt_b)
    dt_gemm<<<dim3(16,32), 256, 0, stream>>>(proj, dt_proj, dt_b, dtp,
        NTOK, D_INNER, DT_RANK, 96);
    // 6. chunked scan
    scan_pass1<<<1024, 256, 0, stream>>>(dtp, proj, xcs, A_log, hend, sdt);
    scan_combine<<<256, 256, 0, stream>>>(hend, sdt, A_log, ssm0, hst);
    scan_pass3<<<1024, 256, 0, stream>>>(dtp, proj, xcs, xz, A_log, Dp, hst, ym_bf);
    // 6b. out_proj -> bf16 (R2; sdt dead after combine)
    cvt_w_kernel<<<512, 256, 0, stream>>>(out_proj, opbf, (DIM*D_INNER)/4);
    // 7. x1 = x + ym @ out_proj^T
    mfma_gemm_fast<0,1,0,1><<<dim3(8,32), 256, 0, stream>>>(ym_bf, opbf, x, x1,
        nullptr, nullptr, nullptr, NTOK, DIM, D_INNER, D_INNER);
    // 8. LN2 + router fused -> xn2bf, tw, ti, counts
    ln2_router_kernel<<<NTOK, 256, 0, stream>>>(x1, ln2_s, ln2_b, router_w,
        xn2bf, tw, ti, counts);
    // 9. slot assignment
    offs_kernel<<<1, 64, 0, stream>>>(counts, offs);
    assign_kernel<<<NTOK/256, 256, 0, stream>>>(ti, offs, cursors, tok_of_slot, slot_of);
    // 10. MoE: wg -> DTP region (dtp dead), wu -> XZ second half (xz dead); fused gate+up
    cvt_w_kernel<<<2048, 256, 0, stream>>>(w_gate, wgbf, (N_EXP*HID*DIM)/4);
    cvt_w_kernel<<<2048, 256, 0, stream>>>(w_up, wubf, (N_EXP*HID*DIM)/4);
    moe_gateup_fast<<<dim3(HID/128, 64, N_EXP), 256, 0, stream>>>(xn2bf, wgbf, wubf,
        tok_of_slot, counts, offs, H);
    // wd overwrites wg (dead after gateup)
    cvt_w_kernel<<<2048, 256, 0, stream>>>(w_down, wdbf, (N_EXP*DIM*HID)/4);
    mfma_gemm_fast<2,0,0,0><<<dim3(DIM/128, 64, N_EXP), 256, 0, stream>>>(H, wdbf, nullptr, dnout,
        tok_of_slot, counts, offs, NSLOT, DIM, HID, HID);
    // 11. out = x1 + weighted experts
    final_kernel<<<(NTOK*DIM/4)/256, 256, 0, stream>>>(x1, dnout, tw, slot_of, out);
}

// Round 8
// 738.519 us; speedup vs baseline: 5.2070x; 1.0020x over previous
//
#include <hip/hip_runtime.h>
#include <hip/hip_bf16.h>
#include <math.h>

#define DIM 1024
#define D_STATE 16
#define D_CONV 4
#define D_INNER 2048
#define DT_RANK 64
#define N_EXP 8
#define TOP_K 2
#define HID 2048
#define BB 2
#define TT 2048
#define NTOK (BB*TT)          // 4096
#define NSLOT (NTOK*TOP_K)    // 8192
#define EPS 1e-5f
#define NCHUNK 64
#define CLEN (TT/NCHUNK)      // 32
#define XPJ_KS 8
#define XPJ_KLEN (D_INNER/XPJ_KS)   // 256

// ---------------- workspace layout (float units) ----------------
#define OFF_R0   ((size_t)0)
#define OFF_R1   ((size_t)4194304)
#define OFF_R2   ((size_t)8388608)
#define OFF_XZ   ((size_t)10485760)
#define OFF_H    OFF_XZ
#define OFF_WU   ((size_t)18874368)
#define OFF_XCS  ((size_t)27262976)
#define OFF_DTP  ((size_t)35651584)
#define OFF_X1   ((size_t)44040192)
#define OFF_PROJ ((size_t)48234496)
#define OFF_TW   ((size_t)48627712)
#define OFF_INT  ((size_t)48635904)
#define OFF_XPW  ((size_t)48668672)
// int offsets (ints)
#define IO_TI    0
#define IO_CNT   8192
#define IO_CUR   8200
#define IO_OFS   8208
#define IO_TOK   8216
#define IO_SLOT  16408

typedef __attribute__((ext_vector_type(4))) float f32x4;
typedef __attribute__((ext_vector_type(8))) __bf16 bf16x8;
typedef __attribute__((ext_vector_type(4))) __bf16 bf16x4;

__device__ __forceinline__ float siluf(float v){ return v / (1.f + expf(-v)); }

__device__ __forceinline__ f32x4 mfma16(bf16x8 a, bf16x8 b, f32x4 c){
    return __builtin_amdgcn_mfma_f32_16x16x32_bf16(a, b, c, 0, 0, 0);
}

__device__ __forceinline__ void gload16(const void* g, void* l){
    __builtin_amdgcn_global_load_lds(
        (const __attribute__((address_space(1))) unsigned int*)g,
        (__attribute__((address_space(3))) unsigned int*)l, 16, 0, 0);
}

__device__ __forceinline__ void cvt_store16(__bf16* dst, f32x4 a0, f32x4 a1, f32x4 a2, f32x4 a3){
    bf16x8 p0, p1;
    #pragma unroll
    for (int j = 0; j < 4; ++j){
        p0[j]   = (__bf16)a0[j];
        p0[j+4] = (__bf16)a1[j];
        p1[j]   = (__bf16)a2[j];
        p1[j+4] = (__bf16)a3[j];
    }
    *(bf16x8*)dst = p0;
    *(bf16x8*)(dst+8) = p1;
}

// ---------------- weight f32 -> bf16 convert ----------------
__global__ __launch_bounds__(256) void cvt_w_kernel(const float* __restrict__ src,
    __bf16* __restrict__ dst, int n4)
{
    int i = blockIdx.x*256 + threadIdx.x;
    int stride = gridDim.x*256;
    for (; i < n4; i += stride){
        f32x4 v = *(const f32x4*)(src + (size_t)i*4);
        bf16x4 o;
        o[0] = (__bf16)v[0]; o[1] = (__bf16)v[1];
        o[2] = (__bf16)v[2]; o[3] = (__bf16)v[3];
        *(bf16x4*)(dst + (size_t)i*4) = o;
    }
}

// x_proj (96x2048) -> padded bf16 (128x2048), rows 96..127 = 0
__global__ __launch_bounds__(256) void cvt_pad_xproj(const float* __restrict__ src,
    __bf16* __restrict__ dst)
{
    int i = blockIdx.x*256 + threadIdx.x;
    int base = i*4;
    int row = base >> 11;
    bf16x4 o;
    if (row < 96){
        f32x4 v = *(const f32x4*)(src + base);
        o[0] = (__bf16)v[0]; o[1] = (__bf16)v[1];
        o[2] = (__bf16)v[2]; o[3] = (__bf16)v[3];
    } else {
        o[0] = (__bf16)0.f; o[1] = (__bf16)0.f;
        o[2] = (__bf16)0.f; o[3] = (__bf16)0.f;
    }
    *(bf16x4*)(dst + base) = o;
}

// ---------------- LayerNorm (LN1): bf16 out ----------------
__global__ __launch_bounds__(256) void ln_kernel(const float* __restrict__ x,
    const float* __restrict__ s, const float* __restrict__ b,
    __bf16* __restrict__ obf)
{
    int t = blockIdx.x;
    const float* xp = x + (size_t)t * DIM;
    float v[4]; float sum = 0.f, sq = 0.f;
    #pragma unroll
    for (int j = 0; j < 4; ++j){
        v[j] = xp[threadIdx.x + 256*j];
        sum += v[j]; sq += v[j]*v[j];
    }
    #pragma unroll
    for (int off = 32; off; off >>= 1){
        sum += __shfl_xor(sum, off, 64);
        sq  += __shfl_xor(sq , off, 64);
    }
    __shared__ float red[4][2];
    int w = threadIdx.x >> 6, lane = threadIdx.x & 63;
    if (lane == 0){ red[w][0] = sum; red[w][1] = sq; }
    __syncthreads();
    sum = red[0][0]+red[1][0]+red[2][0]+red[3][0];
    sq  = red[0][1]+red[1][1]+red[2][1]+red[3][1];
    float mu = sum * (1.f/DIM);
    float var = sq * (1.f/DIM) - mu*mu;
    float r = rsqrtf(var + EPS);
    #pragma unroll
    for (int j = 0; j < 4; ++j){
        int d = threadIdx.x + 256*j;
        obf[(size_t)t*DIM + d] = (__bf16)((v[j]-mu)*r*s[d] + b[d]);
    }
}

// ---------------- LN2 fused with router ----------------
__global__ __launch_bounds__(256) void ln2_router_kernel(const float* __restrict__ x,
    const float* __restrict__ s, const float* __restrict__ b,
    const float* __restrict__ rw, __bf16* __restrict__ obf,
    float* __restrict__ tw, int* __restrict__ ti, int* __restrict__ counts)
{
    int t = blockIdx.x;
    const float* xp = x + (size_t)t * DIM;
    float v[4]; float sum = 0.f, sq = 0.f;
    #pragma unroll
    for (int j = 0; j < 4; ++j){
        v[j] = xp[threadIdx.x + 256*j];
        sum += v[j]; sq += v[j]*v[j];
    }
    #pragma unroll
    for (int off = 32; off; off >>= 1){
        sum += __shfl_xor(sum, off, 64);
        sq  += __shfl_xor(sq , off, 64);
    }
    __shared__ float red[4][2];
    __shared__ float red2[4][N_EXP];
    int w = threadIdx.x >> 6, lane = threadIdx.x & 63;
    if (lane == 0){ red[w][0] = sum; red[w][1] = sq; }
    __syncthreads();
    sum = red[0][0]+red[1][0]+red[2][0]+red[3][0];
    sq  = red[0][1]+red[1][1]+red[2][1]+red[3][1];
    float mu = sum * (1.f/DIM);
    float var = sq * (1.f/DIM) - mu*mu;
    float r = rsqrtf(var + EPS);
    float p[N_EXP] = {};
    #pragma unroll
    for (int j = 0; j < 4; ++j){
        int d = threadIdx.x + 256*j;
        float o = (v[j]-mu)*r*s[d] + b[d];
        obf[(size_t)t*DIM + d] = (__bf16)o;
        #pragma unroll
        for (int e = 0; e < N_EXP; ++e) p[e] += o * rw[e*DIM + d];
    }
    #pragma unroll
    for (int e = 0; e < N_EXP; ++e){
        #pragma unroll
        for (int off = 32; off; off >>= 1) p[e] += __shfl_xor(p[e], off, 64);
    }
    if (lane == 0){
        #pragma unroll
        for (int e = 0; e < N_EXP; ++e) red2[w][e] = p[e];
    }
    __syncthreads();
    if (threadIdx.x == 0){
        float q[N_EXP];
        #pragma unroll
        for (int e = 0; e < N_EXP; ++e)
            q[e] = red2[0][e]+red2[1][e]+red2[2][e]+red2[3][e];
        float mx = q[0];
        #pragma unroll
        for (int e = 1; e < N_EXP; ++e) mx = fmaxf(mx, q[e]);
        float ssum = 0.f;
        #pragma unroll
        for (int e = 0; e < N_EXP; ++e){ q[e] = expf(q[e]-mx); ssum += q[e]; }
        int i0 = 0;
        #pragma unroll
        for (int e = 1; e < N_EXP; ++e) if (q[e] > q[i0]) i0 = e;
        int i1 = (i0 == 0) ? 1 : 0;
        #pragma unroll
        for (int e = 0; e < N_EXP; ++e) if (e != i0 && q[e] > q[i1]) i1 = e;
        float w0 = q[i0]/ssum, w1 = q[i1]/ssum;
        float sw = w0 + w1; w0 /= sw; w1 /= sw;
        tw[t*2] = w0; tw[t*2+1] = w1;
        ti[t*2] = i0; ti[t*2+1] = i1;
        atomicAdd(&counts[i0], 1);
        atomicAdd(&counts[i1], 1);
    }
}

// ============ fast bf16 MFMA GEMM: 3-buffer 2-deep prefetch + XOR swizzle ============
// Pipeline: prologue stages tiles 0,1; iter t stages t+2 then vmcnt(8) (= tile t's
// 4 loads complete, issued 2 phases ago) -> barrier -> ds_read+MFMA(t) -> barrier.
// Buffers: read buf[t%3]; in-flight writes target (t+1)%3,(t+2)%3 - disjoint.
template<int MODE, int EPI, int CBF, int SWZ>
__global__ __launch_bounds__(256,3) void mfma_gemm_fast(
    const __bf16* __restrict__ A, const __bf16* __restrict__ W,
    const void* __restrict__ RG, void* __restrict__ Cv,
    const int* __restrict__ tok_of_slot, const int* __restrict__ counts,
    const int* __restrict__ offs, int M, int N, int K, int lda)
{
    int bx = blockIdx.x, by = blockIdx.y;
    if (SWZ){
        int nwg = gridDim.x*gridDim.y;
        int id = by*gridDim.x + bx;
        int swz = (id & 7)*(nwg >> 3) + (id >> 3);
        bx = swz % gridDim.x; by = swz / gridDim.x;
    }
    int e    = (MODE == 0) ? 0 : blockIdx.z;
    int cnt  = (MODE == 0) ? M : counts[e];
    int base = (MODE == 0) ? 0 : offs[e];
    int m0 = by * 128;
    if (m0 >= cnt) return;
    int n0 = bx * 128;
    const __bf16* We = W + (size_t)e * N * K;

    __shared__ __bf16 As[3*128*32];
    __shared__ __bf16 Ws[3*128*32];

    int tid = threadIdx.x;
    int wave = tid >> 6, lane = tid & 63;
    int c0 = wave*2, c1 = wave*2 + 1;
    int lr0 = c0*16 + (lane >> 2);
    int lr1 = c1*16 + (lane >> 2);
    int koff = (((lane & 3) ^ ((lane >> 3) & 3)) * 8);   // swizzled source colblock

    int ar0, ar1;
    {
        int m0c = m0 + lr0, m1c = m0 + lr1;
        if (MODE != 0){
            if (m0c >= cnt) m0c = cnt - 1;
            if (m1c >= cnt) m1c = cnt - 1;
        }
        if (MODE == 1){ ar0 = tok_of_slot[base + m0c]; ar1 = tok_of_slot[base + m1c]; }
        else if (MODE == 2){ ar0 = base + m0c; ar1 = base + m1c; }
        else { ar0 = m0c; ar1 = m1c; }
    }
    const __bf16* aS0 = A + (size_t)ar0 * lda + koff;
    const __bf16* aS1 = A + (size_t)ar1 * lda + koff;
    const __bf16* wS0 = We + (size_t)(n0 + lr0) * K + koff;
    const __bf16* wS1 = We + (size_t)(n0 + lr1) * K + koff;
    __bf16* ldsA0 = As + c0*512;
    __bf16* ldsA1 = As + c1*512;
    __bf16* ldsW0 = Ws + c0*512;
    __bf16* ldsW1 = Ws + c1*512;

    int wm = (wave >> 1) * 64, wn = (wave & 1) * 64;
    int fr = lane & 15;
    const int scb = (((lane >> 4) ^ ((lane >> 1) & 3)) * 8);  // swizzled read colblock

    f32x4 acc[4][4];
    #pragma unroll
    for (int i = 0; i < 4; ++i)
        #pragma unroll
        for (int j = 0; j < 4; ++j)
            acc[i][j] = (f32x4){0.f, 0.f, 0.f, 0.f};

    int NK = K >> 5;
    // prologue: stage tiles 0 (buf0) and 1 (buf1)
    gload16(aS0, ldsA0);        gload16(aS1, ldsA1);
    gload16(wS0, ldsW0);        gload16(wS1, ldsW1);
    if (NK > 1){
        gload16(aS0 + 32, ldsA0 + 4096); gload16(aS1 + 32, ldsA1 + 4096);
        gload16(wS0 + 32, ldsW0 + 4096); gload16(wS1 + 32, ldsW1 + 4096);
    }

    int cur = 0;
    for (int t = 0; t < NK; ++t){
        if (t + 2 < NK){
            int nb = cur + 2; if (nb >= 3) nb -= 3;
            int off = nb*4096;
            size_t ko = (size_t)(t+2)*32;
            gload16(aS0 + ko, ldsA0 + off);
            gload16(aS1 + ko, ldsA1 + off);
            gload16(wS0 + ko, ldsW0 + off);
            gload16(wS1 + ko, ldsW1 + off);
            asm volatile("s_waitcnt vmcnt(8)" ::: "memory");
        } else if (t + 1 < NK){
            asm volatile("s_waitcnt vmcnt(4)" ::: "memory");
        } else {
            asm volatile("s_waitcnt vmcnt(0)" ::: "memory");
        }
        __builtin_amdgcn_s_barrier();
        int bo = cur*4096;
        bf16x8 af[4], bf[4];
        #pragma unroll
        for (int i = 0; i < 4; ++i)
            af[i] = *(const bf16x8*)&As[bo + (wm + i*16 + fr)*32 + scb];
        #pragma unroll
        for (int j = 0; j < 4; ++j)
            bf[j] = *(const bf16x8*)&Ws[bo + (wn + j*16 + fr)*32 + scb];
        __builtin_amdgcn_s_setprio(1);
        #pragma unroll
        for (int i = 0; i < 4; ++i)
            #pragma unroll
            for (int j = 0; j < 4; ++j)
                acc[i][j] = mfma16(af[i], bf[j], acc[i][j]);
        __builtin_amdgcn_s_setprio(0);
        __builtin_amdgcn_s_barrier();
        cur = cur + 1; if (cur >= 3) cur -= 3;
    }

    int orow = (lane >> 4) * 4;
    int ocol = lane & 15;
    #pragma unroll
    for (int i = 0; i < 4; ++i){
        #pragma unroll
        for (int jj = 0; jj < 4; ++jj){
            #pragma unroll
            for (int j = 0; j < 4; ++j){
                int m = m0 + wm + i*16 + orow + j;
                int n = n0 + wn + jj*16 + ocol;
                if (m < cnt){
                    size_t row = (size_t)(base + m);
                    float v = acc[i][jj][j];
                    if (EPI == 1) v += ((const float*)RG)[row * (size_t)N + n];
                    if (CBF) ((__bf16*)Cv)[row * (size_t)N + n] = (__bf16)v;
                    else     ((float* )Cv)[row * (size_t)N + n] = v;
                }
            }
        }
    }
}

// ---------------- fused MoE gate+up GEMM (3-buffer 2-deep + swizzle) ----------------
__global__ __launch_bounds__(256,2) void moe_gateup_fast(
    const __bf16* __restrict__ A, const __bf16* __restrict__ Wg,
    const __bf16* __restrict__ Wu, const int* __restrict__ tok_of_slot,
    const int* __restrict__ counts, const int* __restrict__ offs,
    __bf16* __restrict__ H)
{
    int e = blockIdx.z;
    int cnt = counts[e];
    int base = offs[e];
    int m0 = blockIdx.y * 128;
    if (m0 >= cnt) return;
    int n0 = blockIdx.x * 128;
    const __bf16* Wge = Wg + (size_t)e * HID * DIM;
    const __bf16* Wue = Wu + (size_t)e * HID * DIM;

    __shared__ __bf16 As[3*128*32];
    __shared__ __bf16 Gs[3*128*32];
    __shared__ __bf16 Us[3*128*32];

    int tid = threadIdx.x;
    int wave = tid >> 6, lane = tid & 63;
    int c0 = wave*2, c1 = wave*2 + 1;
    int lr0 = c0*16 + (lane >> 2);
    int lr1 = c1*16 + (lane >> 2);
    int koff = (((lane & 3) ^ ((lane >> 3) & 3)) * 8);

    int m0c = m0 + lr0, m1c = m0 + lr1;
    if (m0c >= cnt) m0c = cnt - 1;
    if (m1c >= cnt) m1c = cnt - 1;
    int ar0 = tok_of_slot[base + m0c];
    int ar1 = tok_of_slot[base + m1c];

    const __bf16* aS0 = A + (size_t)ar0 * DIM + koff;
    const __bf16* aS1 = A + (size_t)ar1 * DIM + koff;
    const __bf16* gS0 = Wge + (size_t)(n0 + lr0) * DIM + koff;
    const __bf16* gS1 = Wge + (size_t)(n0 + lr1) * DIM + koff;
    const __bf16* uS0 = Wue + (size_t)(n0 + lr0) * DIM + koff;
    const __bf16* uS1 = Wue + (size_t)(n0 + lr1) * DIM + koff;
    __bf16* ldsA0 = As + c0*512;
    __bf16* ldsA1 = As + c1*512;
    __bf16* ldsG0 = Gs + c0*512;
    __bf16* ldsG1 = Gs + c1*512;
    __bf16* ldsU0 = Us + c0*512;
    __bf16* ldsU1 = Us + c1*512;

    int wm = (wave >> 1) * 64, wn = (wave & 1) * 64;
    int fr = lane & 15;
    const int scb = (((lane >> 4) ^ ((lane >> 1) & 3)) * 8);

    f32x4 accg[4][4], accu[4][4];
    #pragma unroll
    for (int i = 0; i < 4; ++i)
        #pragma unroll
        for (int j = 0; j < 4; ++j){
            accg[i][j] = (f32x4){0.f, 0.f, 0.f, 0.f};
            accu[i][j] = (f32x4){0.f, 0.f, 0.f, 0.f};
        }

    // prologue: tiles 0,1
    gload16(aS0, ldsA0); gload16(aS1, ldsA1);
    gload16(gS0, ldsG0); gload16(gS1, ldsG1);
    gload16(uS0, ldsU0); gload16(uS1, ldsU1);
    gload16(aS0 + 32, ldsA0 + 4096); gload16(aS1 + 32, ldsA1 + 4096);
    gload16(gS0 + 32, ldsG0 + 4096); gload16(gS1 + 32, ldsG1 + 4096);
    gload16(uS0 + 32, ldsU0 + 4096); gload16(uS1 + 32, ldsU1 + 4096);

    const int NK = DIM >> 5;   // 32
    int cur = 0;
    for (int t = 0; t < NK; ++t){
        if (t + 2 < NK){
            int nb = cur + 2; if (nb >= 3) nb -= 3;
            int off = nb*4096;
            size_t ko = (size_t)(t+2)*32;
            gload16(aS0 + ko, ldsA0 + off);
            gload16(aS1 + ko, ldsA1 + off);
            gload16(gS0 + ko, ldsG0 + off);
            gload16(gS1 + ko, ldsG1 + off);
            gload16(uS0 + ko, ldsU0 + off);
            gload16(uS1 + ko, ldsU1 + off);
            asm volatile("s_waitcnt vmcnt(12)" ::: "memory");
        } else if (t + 1 < NK){
            asm volatile("s_waitcnt vmcnt(6)" ::: "memory");
        } else {
            asm volatile("s_waitcnt vmcnt(0)" ::: "memory");
        }
        __builtin_amdgcn_s_barrier();
        int bo = cur*4096;
        bf16x8 af[4], gf[4], uf[4];
        #pragma unroll
        for (int i = 0; i < 4; ++i){
            af[i] = *(const bf16x8*)&As[bo + (wm + i*16 + fr)*32 + scb];
            gf[i] = *(const bf16x8*)&Gs[bo + (wn + i*16 + fr)*32 + scb];
            uf[i] = *(const bf16x8*)&Us[bo + (wn + i*16 + fr)*32 + scb];
        }
        __builtin_amdgcn_s_setprio(1);
        #pragma unroll
        for (int i = 0; i < 4; ++i)
            #pragma unroll
            for (int j = 0; j < 4; ++j){
                accg[i][j] = mfma16(af[i], gf[j], accg[i][j]);
                accu[i][j] = mfma16(af[i], uf[j], accu[i][j]);
            }
        __builtin_amdgcn_s_setprio(0);
        __builtin_amdgcn_s_barrier();
        cur = cur + 1; if (cur >= 3) cur -= 3;
    }

    int orow = (lane >> 4) * 4;
    int ocol = lane & 15;
    #pragma unroll
    for (int i = 0; i < 4; ++i){
        #pragma unroll
        for (int jj = 0; jj < 4; ++jj){
            #pragma unroll
            for (int j = 0; j < 4; ++j){
                int m = m0 + wm + i*16 + orow + j;
                if (m < cnt){
                    int n = n0 + wn + jj*16 + ocol;
                    size_t row = (size_t)(base + m);
                    float g = accg[i][jj][j], u = accu[i][jj][j];
                    H[row * (size_t)HID + n] = (__bf16)(siluf(g) * u);
                }
            }
        }
    }
}

// ---------------- x_proj K-split GEMM (3-buffer 2-deep + swizzle) ----------------
__global__ __launch_bounds__(256,3) void xproj_ks_kernel(
    const __bf16* __restrict__ A, const __bf16* __restrict__ W,
    float* __restrict__ Cpart)
{
    int m0 = blockIdx.y * 128;
    int kbeg = blockIdx.z * XPJ_KLEN;

    __shared__ __bf16 As[3*128*32];
    __shared__ __bf16 Ws[3*128*32];

    int tid = threadIdx.x;
    int wave = tid >> 6, lane = tid & 63;
    int c0 = wave*2, c1 = wave*2 + 1;
    int lr0 = c0*16 + (lane >> 2);
    int lr1 = c1*16 + (lane >> 2);
    int koff = (((lane & 3) ^ ((lane >> 3) & 3)) * 8);

    const __bf16* aS0 = A + (size_t)(m0 + lr0) * D_INNER + kbeg + koff;
    const __bf16* aS1 = A + (size_t)(m0 + lr1) * D_INNER + kbeg + koff;
    const __bf16* wS0 = W + (size_t)lr0 * D_INNER + kbeg + koff;
    const __bf16* wS1 = W + (size_t)lr1 * D_INNER + kbeg + koff;
    __bf16* ldsA0 = As + c0*512;
    __bf16* ldsA1 = As + c1*512;
    __bf16* ldsW0 = Ws + c0*512;
    __bf16* ldsW1 = Ws + c1*512;

    int wm = (wave >> 1) * 64, wn = (wave & 1) * 64;
    int fr = lane & 15;
    const int scb = (((lane >> 4) ^ ((lane >> 1) & 3)) * 8);

    f32x4 acc[4][4];
    #pragma unroll
    for (int i = 0; i < 4; ++i)
        #pragma unroll
        for (int j = 0; j < 4; ++j)
            acc[i][j] = (f32x4){0.f, 0.f, 0.f, 0.f};

    gload16(aS0, ldsA0); gload16(aS1, ldsA1);
    gload16(wS0, ldsW0); gload16(wS1, ldsW1);
    gload16(aS0 + 32, ldsA0 + 4096); gload16(aS1 + 32, ldsA1 + 4096);
    gload16(wS0 + 32, ldsW0 + 4096); gload16(wS1 + 32, ldsW1 + 4096);

    const int NK = XPJ_KLEN >> 5;   // 8
    int cur = 0;
    for (int t = 0; t < NK; ++t){
        if (t + 2 < NK){
            int nb = cur + 2; if (nb >= 3) nb -= 3;
            int off = nb*4096;
            size_t ko = (size_t)(t+2)*32;
            gload16(aS0 + ko, ldsA0 + off);
            gload16(aS1 + ko, ldsA1 + off);
            gload16(wS0 + ko, ldsW0 + off);
            gload16(wS1 + ko, ldsW1 + off);
            asm volatile("s_waitcnt vmcnt(8)" ::: "memory");
        } else if (t + 1 < NK){
            asm volatile("s_waitcnt vmcnt(4)" ::: "memory");
        } else {
            asm volatile("s_waitcnt vmcnt(0)" ::: "memory");
        }
        __builtin_amdgcn_s_barrier();
        int bo = cur*4096;
        bf16x8 af[4], bf[4];
        #pragma unroll
        for (int i = 0; i < 4; ++i)
            af[i] = *(const bf16x8*)&As[bo + (wm + i*16 + fr)*32 + scb];
        #pragma unroll
        for (int j = 0; j < 4; ++j)
            bf[j] = *(const bf16x8*)&Ws[bo + (wn + j*16 + fr)*32 + scb];
        __builtin_amdgcn_s_setprio(1);
        #pragma unroll
        for (int i = 0; i < 4; ++i)
            #pragma unroll
            for (int j = 0; j < 4; ++j)
                acc[i][j] = mfma16(af[i], bf[j], acc[i][j]);
        __builtin_amdgcn_s_setprio(0);
        __builtin_amdgcn_s_barrier();
        cur = cur + 1; if (cur >= 3) cur -= 3;
    }

    float* Cz = Cpart + (size_t)blockIdx.z * NTOK * 128;
    int orow = (lane >> 4) * 4;
    int ocol = lane & 15;
    #pragma unroll
    for (int i = 0; i < 4; ++i){
        #pragma unroll
        for (int jj = 0; jj < 4; ++jj){
            #pragma unroll
            for (int j = 0; j < 4; ++j){
                int m = m0 + wm + i*16 + orow + j;
                int n = wn + jj*16 + ocol;
                Cz[(size_t)m * 128 + n] = acc[i][jj][j];
            }
        }
    }
}

__global__ __launch_bounds__(256) void xproj_reduce(const float* __restrict__ Cpart,
    float* __restrict__ proj)
{
    int idx = blockIdx.x*256 + threadIdx.x;
    int t = idx / 96, n = idx - t*96;
    float s = 0.f;
    #pragma unroll
    for (int z = 0; z < XPJ_KS; ++z)
        s += Cpart[(size_t)z * NTOK * 128 + (size_t)t * 128 + n];
    proj[idx] = s;
}

// ---------------- reg-staging MFMA GEMM (dt: softplus(A@W^T + bias)) ----------------
__global__ __launch_bounds__(256,2) void dt_gemm(
    const float* __restrict__ A, const float* __restrict__ W,
    const float* __restrict__ bias, float* __restrict__ C,
    int M, int N, int K, int lda)
{
    int m0 = blockIdx.y * 128;
    int n0 = blockIdx.x * 128;

    __shared__ __bf16 As[128*32];
    __shared__ __bf16 Ws[128*32];

    int tid = threadIdx.x;
    int srow = tid >> 1;
    int scol = (tid & 1) * 16;

    const float* af = A + (size_t)(m0 + srow) * lda + scol;
    const float* wptr = W + (size_t)(n0 + srow) * K + scol;

    f32x4 raf[4], rw[4];
    #pragma unroll
    for (int q = 0; q < 4; ++q){
        raf[q] = *(const f32x4*)(af + q*4);
        rw[q]  = *(const f32x4*)(wptr + q*4);
    }

    int wave = tid >> 6, lane = tid & 63;
    int wm = (wave >> 1) * 64, wn = (wave & 1) * 64;
    int fr = lane & 15, fk = (lane >> 4) * 8;

    f32x4 acc[4][4];
    #pragma unroll
    for (int i = 0; i < 4; ++i)
        #pragma unroll
        for (int j = 0; j < 4; ++j)
            acc[i][j] = (f32x4){0.f, 0.f, 0.f, 0.f};

    for (int k0 = 0; k0 < K; k0 += 32){
        cvt_store16(&As[srow*32 + scol], raf[0], raf[1], raf[2], raf[3]);
        cvt_store16(&Ws[srow*32 + scol], rw[0], rw[1], rw[2], rw[3]);
        __syncthreads();
        if (k0 + 32 < K){
            #pragma unroll
            for (int q = 0; q < 4; ++q){
                raf[q] = *(const f32x4*)(af + k0 + 32 + q*4);
                rw[q]  = *(const f32x4*)(wptr + k0 + 32 + q*4);
            }
        }
        bf16x8 afr[4], bfr[4];
        #pragma unroll
        for (int i = 0; i < 4; ++i)
            afr[i] = *(const bf16x8*)&As[(wm + i*16 + fr)*32 + fk];
        #pragma unroll
        for (int i = 0; i < 4; ++i)
            bfr[i] = *(const bf16x8*)&Ws[(wn + i*16 + fr)*32 + fk];
        #pragma unroll
        for (int i = 0; i < 4; ++i)
            #pragma unroll
            for (int j = 0; j < 4; ++j)
                acc[i][j] = mfma16(afr[i], bfr[j], acc[i][j]);
        __syncthreads();
    }

    int orow = (lane >> 4) * 4;
    int ocol = lane & 15;
    #pragma unroll
    for (int i = 0; i < 4; ++i){
        #pragma unroll
        for (int jj = 0; jj < 4; ++jj){
            #pragma unroll
            for (int j = 0; j < 4; ++j){
                int m = m0 + wm + i*16 + orow + j;
                int n = n0 + wn + jj*16 + ocol;
                if (m < M && n < N){
                    float v = acc[i][jj][j] + bias[n];
                    v = (v > 20.f) ? v : log1pf(expf(v));
                    C[(size_t)m * N + n] = v;
                }
            }
        }
    }
}

// ---------------- conv: f32 + bf16 outputs ----------------
__global__ __launch_bounds__(256) void conv_kernel(const float* __restrict__ xz,
    const float* __restrict__ cs, const float* __restrict__ cw,
    const float* __restrict__ cb, float* __restrict__ xcs,
    __bf16* __restrict__ xcs_bf)
{
    int idx = blockIdx.x*256 + threadIdx.x;
    int d = idx & (D_INNER-1);
    int bt = idx >> 11;
    int b = bt >> 11;
    int t = bt & (TT-1);
    float acc = cb[d];
    #pragma unroll
    for (int k = 0; k < 4; ++k){
        int tau = t + k - 3;
        float xv;
        if (tau >= 0) xv = xz[(size_t)(b*TT + tau)*(2*D_INNER) + d];
        else          xv = cs[((size_t)b*D_INNER + d)*3 + (tau + 3)];
        acc += cw[d*4 + k] * xv;
    }
    float v = siluf(acc);
    xcs[idx] = v;
    xcs_bf[idx] = (__bf16)v;
}

// ---------------- chunked SSM scan ----------------
__global__ __launch_bounds__(256) void scan_pass1(const float* __restrict__ dtp,
    const float* __restrict__ proj, const float* __restrict__ xcs,
    const float* __restrict__ A_log, float* __restrict__ hend,
    float* __restrict__ sumdt)
{
    int gid = blockIdx.x*256 + threadIdx.x;
    int bd = gid & (BB*D_INNER-1);
    int chunk = gid >> 12;
    int b = bd >> 11, d = bd & (D_INNER-1);
    float As[D_STATE], h[D_STATE];
    #pragma unroll
    for (int s = 0; s < D_STATE; ++s){
        As[s] = -__expf(A_log[d*D_STATE + s]);
        h[s] = 0.f;
    }
    float sdt = 0.f;
    int base = b*TT + chunk*CLEN;
    for (int t = 0; t < CLEN; ++t){
        size_t bt = (size_t)(base + t);
        float dt = dtp[bt*D_INNER + d];
        float x  = xcs[bt*D_INNER + d];
        f32x4 Bv[4];
        #pragma unroll
        for (int q = 0; q < 4; ++q) Bv[q] = *(const f32x4*)(proj + bt*96 + DT_RANK + q*4);
        float dtx = dt * x;
        sdt += dt;
        #pragma unroll
        for (int s = 0; s < D_STATE; ++s)
            h[s] = __expf(dt*As[s])*h[s] + Bv[s>>2][s&3]*dtx;
    }
    size_t hb = ((size_t)bd*NCHUNK + chunk)*D_STATE;
    #pragma unroll
    for (int q = 0; q < 4; ++q)
        *(f32x4*)(hend + hb + q*4) = (f32x4){h[q*4], h[q*4+1], h[q*4+2], h[q*4+3]};
    sumdt[bd*NCHUNK + chunk] = sdt;
}

__global__ __launch_bounds__(256) void scan_combine(const float* __restrict__ hend,
    const float* __restrict__ sumdt, const float* __restrict__ A_log,
    const float* __restrict__ ssm0, float* __restrict__ hstart)
{
    int gid = blockIdx.x*256 + threadIdx.x;
    int s = gid & 15;
    int bd = gid >> 4;
    int b = bd >> 11, d = bd & (D_INNER-1);
    float As = -__expf(A_log[d*D_STATE + s]);
    float h = ssm0[((size_t)b*D_INNER + d)*D_STATE + s];
    for (int c = 0; c < NCHUNK; ++c){
        size_t idx = ((size_t)bd*NCHUNK + c)*D_STATE + s;
        hstart[idx] = h;
        h = hend[idx] + __expf(As * sumdt[bd*NCHUNK + c]) * h;
    }
}

__global__ __launch_bounds__(256) void scan_pass3(const float* __restrict__ dtp,
    const float* __restrict__ proj, const float* __restrict__ xcs,
    const float* __restrict__ xz, const float* __restrict__ A_log,
    const float* __restrict__ Dp, const float* __restrict__ hstart,
    __bf16* __restrict__ ym)
{
    int gid = blockIdx.x*256 + threadIdx.x;
    int bd = gid & (BB*D_INNER-1);
    int chunk = gid >> 12;
    int b = bd >> 11, d = bd & (D_INNER-1);
    float As[D_STATE], h[D_STATE];
    #pragma unroll
    for (int s = 0; s < D_STATE; ++s)
        As[s] = -__expf(A_log[d*D_STATE + s]);
    size_t hb = ((size_t)bd*NCHUNK + chunk)*D_STATE;
    #pragma unroll
    for (int q = 0; q < 4; ++q){
        f32x4 hv = *(const f32x4*)(hstart + hb + q*4);
        h[q*4] = hv[0]; h[q*4+1] = hv[1]; h[q*4+2] = hv[2]; h[q*4+3] = hv[3];
    }
    float Dd = Dp[d];
    int base = b*TT + chunk*CLEN;
    for (int t = 0; t < CLEN; ++t){
        size_t bt = (size_t)(base + t);
        float dt = dtp[bt*D_INNER + d];
        float x  = xcs[bt*D_INNER + d];
        f32x4 Bv[4], Cv[4];
        #pragma unroll
        for (int q = 0; q < 4; ++q){
            Bv[q] = *(const f32x4*)(proj + bt*96 + DT_RANK + q*4);
            Cv[q] = *(const f32x4*)(proj + bt*96 + DT_RANK + D_STATE + q*4);
        }
        float dtx = dt * x;
        float p = 0.f;
        #pragma unroll
        for (int s = 0; s < D_STATE; ++s){
            h[s] = __expf(dt*As[s])*h[s] + Bv[s>>2][s&3]*dtx;
            p += h[s] * Cv[s>>2][s&3];
        }
        float y = p + Dd*x;
        float z = xz[bt*(2*D_INNER) + D_INNER + d];
        float sz = z / (1.f + __expf(-z));
        ym[bt*D_INNER + d] = (__bf16)(y * sz);
    }
}

// ---------------- slot assignment ----------------
__global__ void offs_kernel(const int* __restrict__ counts, int* __restrict__ offs)
{
    if (threadIdx.x == 0 && blockIdx.x == 0){
        int s = 0;
        for (int e = 0; e < N_EXP; ++e){ offs[e] = s; s += counts[e]; }
    }
}

__global__ __launch_bounds__(256) void assign_kernel(const int* __restrict__ ti,
    const int* __restrict__ offs, int* __restrict__ cursors,
    int* __restrict__ tok_of_slot, int* __restrict__ slot_of)
{
    int t = blockIdx.x*256 + threadIdx.x;
    if (t >= NTOK) return;
    #pragma unroll
    for (int k = 0; k < TOP_K; ++k){
        int e = ti[t*2 + k];
        int pos = atomicAdd(&cursors[e], 1);
        int slot = offs[e] + pos;
        tok_of_slot[slot] = t;
        slot_of[t*2 + k] = slot;
    }
}

// ---------------- final combine ----------------
__global__ __launch_bounds__(256) void final_kernel(const float* __restrict__ x1,
    const float* __restrict__ down_out, const float* __restrict__ tw,
    const int* __restrict__ slot_of, float* __restrict__ out)
{
    int idx4 = blockIdx.x*256 + threadIdx.x;
    int t = idx4 >> 8;
    int c = idx4 & 255;
    float w0 = tw[t*2], w1 = tw[t*2+1];
    size_t s0 = (size_t)slot_of[t*2] * DIM;
    size_t s1 = (size_t)slot_of[t*2+1] * DIM;
    float4 a = *(const float4*)(x1 + (size_t)t*DIM + c*4);
    float4 d0 = *(const float4*)(down_out + s0 + c*4);
    float4 d1 = *(const float4*)(down_out + s1 + c*4);
    float4 r;
    r.x = a.x + w0*d0.x + w1*d1.x;
    r.y = a.y + w0*d0.y + w1*d1.y;
    r.z = a.z + w0*d0.z + w1*d1.z;
    r.w = a.w + w0*d0.w + w1*d1.w;
    *(float4*)(out + (size_t)t*DIM + c*4) = r;
}

extern "C" void kernel_launch(void* const* d_in, const int* in_sizes, int n_in,
                              void* d_out, int out_size, void* d_ws, size_t ws_size,
                              hipStream_t stream)
{
    const float* x        = (const float*)d_in[0];
    const float* ssm0     = (const float*)d_in[1];
    const float* conv0    = (const float*)d_in[2];
    const float* ln1_s    = (const float*)d_in[3];
    const float* ln1_b    = (const float*)d_in[4];
    const float* ln2_s    = (const float*)d_in[5];
    const float* ln2_b    = (const float*)d_in[6];
    const float* in_proj  = (const float*)d_in[7];
    const float* conv_w   = (const float*)d_in[8];
    const float* conv_b   = (const float*)d_in[9];
    const float* x_proj   = (const float*)d_in[10];
    const float* dt_proj  = (const float*)d_in[11];
    const float* dt_b     = (const float*)d_in[12];
    const float* A_log    = (const float*)d_in[13];
    const float* Dp       = (const float*)d_in[14];
    const float* out_proj = (const float*)d_in[15];
    const float* router_w = (const float*)d_in[16];
    const float* w_gate   = (const float*)d_in[17];
    const float* w_up     = (const float*)d_in[18];
    const float* w_down   = (const float*)d_in[19];
    float* out = (float*)d_out;

    float* ws = (float*)d_ws;
    __bf16* xn_bf  = (__bf16*)(ws + OFF_R0);
    float*  hend   = ws + OFF_R0;
    __bf16* ym_bf  = (__bf16*)(ws + OFF_R0);
    float*  xpart  = ws + OFF_R1;
    float*  hst    = ws + OFF_R1;
    float*  sdt    = ws + OFF_R2;
    __bf16* opbf   = (__bf16*)(ws + OFF_R2);
    __bf16* xn2bf  = (__bf16*)(ws + OFF_R2);
    float*  xz     = ws + OFF_XZ;
    __bf16* H      = (__bf16*)(ws + OFF_H);
    __bf16* wubf   = (__bf16*)(ws + OFF_WU);
    float*  xcs    = ws + OFF_XCS;
    float*  dnout  = ws + OFF_XCS;
    float*  dtp    = ws + OFF_DTP;
    __bf16* ipbf   = (__bf16*)(ws + OFF_DTP);
    __bf16* wgbf   = (__bf16*)(ws + OFF_DTP);
    __bf16* wdbf   = (__bf16*)(ws + OFF_DTP);
    __bf16* xcs_bf = (__bf16*)(ws + OFF_X1);
    float*  x1     = ws + OFF_X1;
    float*  proj   = ws + OFF_PROJ;
    float*  tw     = ws + OFF_TW;
    __bf16* xpw    = (__bf16*)(ws + OFF_XPW);
    int*    ip     = (int*)(ws + OFF_INT);
    int* ti          = ip + IO_TI;
    int* counts      = ip + IO_CNT;
    int* cursors     = ip + IO_CUR;
    int* offs        = ip + IO_OFS;
    int* tok_of_slot = ip + IO_TOK;
    int* slot_of     = ip + IO_SLOT;

    hipMemsetAsync(counts, 0, 16*sizeof(int), stream);

    // 0a. in_proj -> bf16 (dtp region, dead until step 5)
    cvt_w_kernel<<<1024, 256, 0, stream>>>(in_proj, ipbf, (2*D_INNER*DIM)/4);
    // 1. xn_bf = LN1(x)
    ln_kernel<<<NTOK, 256, 0, stream>>>(x, ln1_s, ln1_b, xn_bf);
    // 2. xz = xn @ in_proj^T
    mfma_gemm_fast<0,0,0,1><<<dim3(32,32), 256, 0, stream>>>(xn_bf, ipbf, nullptr, xz,
        nullptr, nullptr, nullptr, NTOK, 2*D_INNER, DIM, DIM);
    // 3. conv + silu -> xcs f32 (scan) + xcs_bf (x_proj GEMM)
    conv_kernel<<<(NTOK*D_INNER)/256, 256, 0, stream>>>(xz, conv0, conv_w, conv_b, xcs, xcs_bf);
    // 4. proj = xcs @ x_proj^T  (K-split fast GEMM + reduce)
    cvt_pad_xproj<<<256, 256, 0, stream>>>(x_proj, xpw);
    xproj_ks_kernel<<<dim3(1,32,XPJ_KS), 256, 0, stream>>>(xcs_bf, xpw, xpart);
    xproj_reduce<<<(NTOK*96)/256, 256, 0, stream>>>(xpart, proj);
    // 5. dtp = softplus(proj[:,:64] @ dt_proj^T + dt_b)
    dt_gemm<<<dim3(16,32), 256, 0, stream>>>(proj, dt_proj, dt_b, dtp,
        NTOK, D_INNER, DT_RANK, 96);
    // 6. chunked scan
    scan_pass1<<<1024, 256, 0, stream>>>(dtp, proj, xcs, A_log, hend, sdt);
    scan_combine<<<256, 256, 0, stream>>>(hend, sdt, A_log, ssm0, hst);
    scan_pass3<<<1024, 256, 0, stream>>>(dtp, proj, xcs, xz, A_log, Dp, hst, ym_bf);
    // 6b. out_proj -> bf16 (R2; sdt dead after combine)
    cvt_w_kernel<<<512, 256, 0, stream>>>(out_proj, opbf, (DIM*D_INNER)/4);
    // 7. x1 = x + ym @ out_proj^T
    mfma_gemm_fast<0,1,0,1><<<dim3(8,32), 256, 0, stream>>>(ym_bf, opbf, x, x1,
        nullptr, nullptr, nullptr, NTOK, DIM, D_INNER, D_INNER);
    // 8. LN2 + router fused -> xn2bf, tw, ti, counts
    ln2_router_kernel<<<NTOK, 256, 0, stream>>>(x1, ln2_s, ln2_b, router_w,
        xn2bf, tw, ti, counts);
    // 9. slot assignment
    offs_kernel<<<1, 64, 0, stream>>>(counts, offs);
    assign_kernel<<<NTOK/256, 256, 0, stream>>>(ti, offs, cursors, tok_of_slot, slot_of);
    // 10. MoE: wg -> DTP region (dtp dead), wu -> XZ second half (xz dead); fused gate+up
    cvt_w_kernel<<<2048, 256, 0, stream>>>(w_gate, wgbf, (N_EXP*HID*DIM)/4);
    cvt_w_kernel<<<2048, 256, 0, stream>>>(w_up, wubf, (N_EXP*HID*DIM)/4);
    moe_gateup_fast<<<dim3(HID/128, 64, N_EXP), 256, 0, stream>>>(xn2bf, wgbf, wubf,
        tok_of_slot, counts, offs, H);
    // wd overwrites wg (dead after gateup)
    cvt_w_kernel<<<2048, 256, 0, stream>>>(w_down, wdbf, (N_EXP*DIM*HID)/4);
    mfma_gemm_fast<2,0,0,0><<<dim3(DIM/128, 64, N_EXP), 256, 0, stream>>>(H, wdbf, nullptr, dnout,
        tok_of_slot, counts, offs, NSLOT, DIM, HID, HID);
    // 11. out = x1 + weighted experts
    final_kernel<<<(NTOK*DIM/4)/256, 256, 0, stream>>>(x1, dnout, tw, slot_of, out);
}

// Round 9
// 732.466 us; speedup vs baseline: 5.2501x; 1.0083x over previous
//
#include <hip/hip_runtime.h>
#include <hip/hip_bf16.h>
#include <math.h>

#define DIM 1024
#define D_STATE 16
#define D_CONV 4
#define D_INNER 2048
#define DT_RANK 64
#define N_EXP 8
#define TOP_K 2
#define HID 2048
#define BB 2
#define TT 2048
#define NTOK (BB*TT)          // 4096
#define NSLOT (NTOK*TOP_K)    // 8192
#define EPS 1e-5f
#define NCHUNK 64
#define CLEN (TT/NCHUNK)      // 32
#define XPJ_KS 8
#define XPJ_KLEN (D_INNER/XPJ_KS)   // 256

// ---------------- workspace layout (float units) ----------------
#define OFF_R0   ((size_t)0)
#define OFF_R1   ((size_t)4194304)
#define OFF_R2   ((size_t)8388608)
#define OFF_XZ   ((size_t)10485760)
#define OFF_H    OFF_XZ
#define OFF_WU   ((size_t)18874368)
#define OFF_XCS  ((size_t)27262976)
#define OFF_DTP  ((size_t)35651584)
#define OFF_X1   ((size_t)44040192)
#define OFF_PROJ ((size_t)48234496)
#define OFF_TW   ((size_t)48627712)
#define OFF_INT  ((size_t)48635904)
#define OFF_XPW  ((size_t)48668672)
// int offsets (ints)
#define IO_TI    0
#define IO_CNT   8192
#define IO_CUR   8200
#define IO_OFS   8208
#define IO_TOK   8216
#define IO_SLOT  16408

typedef __attribute__((ext_vector_type(4))) float f32x4;
typedef __attribute__((ext_vector_type(8))) __bf16 bf16x8;
typedef __attribute__((ext_vector_type(4))) __bf16 bf16x4;

__device__ __forceinline__ float siluf(float v){ return v / (1.f + expf(-v)); }

__device__ __forceinline__ f32x4 mfma16(bf16x8 a, bf16x8 b, f32x4 c){
    return __builtin_amdgcn_mfma_f32_16x16x32_bf16(a, b, c, 0, 0, 0);
}

__device__ __forceinline__ void gload16(const void* g, void* l){
    __builtin_amdgcn_global_load_lds(
        (const __attribute__((address_space(1))) unsigned int*)g,
        (__attribute__((address_space(3))) unsigned int*)l, 16, 0, 0);
}

__device__ __forceinline__ void cvt_store16(__bf16* dst, f32x4 a0, f32x4 a1, f32x4 a2, f32x4 a3){
    bf16x8 p0, p1;
    #pragma unroll
    for (int j = 0; j < 4; ++j){
        p0[j]   = (__bf16)a0[j];
        p0[j+4] = (__bf16)a1[j];
        p1[j]   = (__bf16)a2[j];
        p1[j+4] = (__bf16)a3[j];
    }
    *(bf16x8*)dst = p0;
    *(bf16x8*)(dst+8) = p1;
}

// ---------------- weight f32 -> bf16 convert ----------------
__global__ __launch_bounds__(256) void cvt_w_kernel(const float* __restrict__ src,
    __bf16* __restrict__ dst, int n4)
{
    int i = blockIdx.x*256 + threadIdx.x;
    int stride = gridDim.x*256;
    for (; i < n4; i += stride){
        f32x4 v = *(const f32x4*)(src + (size_t)i*4);
        bf16x4 o;
        o[0] = (__bf16)v[0]; o[1] = (__bf16)v[1];
        o[2] = (__bf16)v[2]; o[3] = (__bf16)v[3];
        *(bf16x4*)(dst + (size_t)i*4) = o;
    }
}

// x_proj (96x2048) -> padded bf16 (128x2048), rows 96..127 = 0
__global__ __launch_bounds__(256) void cvt_pad_xproj(const float* __restrict__ src,
    __bf16* __restrict__ dst)
{
    int i = blockIdx.x*256 + threadIdx.x;
    int base = i*4;
    int row = base >> 11;
    bf16x4 o;
    if (row < 96){
        f32x4 v = *(const f32x4*)(src + base);
        o[0] = (__bf16)v[0]; o[1] = (__bf16)v[1];
        o[2] = (__bf16)v[2]; o[3] = (__bf16)v[3];
    } else {
        o[0] = (__bf16)0.f; o[1] = (__bf16)0.f;
        o[2] = (__bf16)0.f; o[3] = (__bf16)0.f;
    }
    *(bf16x4*)(dst + base) = o;
}

// ---------------- LayerNorm (LN1): bf16 out ----------------
__global__ __launch_bounds__(256) void ln_kernel(const float* __restrict__ x,
    const float* __restrict__ s, const float* __restrict__ b,
    __bf16* __restrict__ obf)
{
    int t = blockIdx.x;
    const float* xp = x + (size_t)t * DIM;
    float v[4]; float sum = 0.f, sq = 0.f;
    #pragma unroll
    for (int j = 0; j < 4; ++j){
        v[j] = xp[threadIdx.x + 256*j];
        sum += v[j]; sq += v[j]*v[j];
    }
    #pragma unroll
    for (int off = 32; off; off >>= 1){
        sum += __shfl_xor(sum, off, 64);
        sq  += __shfl_xor(sq , off, 64);
    }
    __shared__ float red[4][2];
    int w = threadIdx.x >> 6, lane = threadIdx.x & 63;
    if (lane == 0){ red[w][0] = sum; red[w][1] = sq; }
    __syncthreads();
    sum = red[0][0]+red[1][0]+red[2][0]+red[3][0];
    sq  = red[0][1]+red[1][1]+red[2][1]+red[3][1];
    float mu = sum * (1.f/DIM);
    float var = sq * (1.f/DIM) - mu*mu;
    float r = rsqrtf(var + EPS);
    #pragma unroll
    for (int j = 0; j < 4; ++j){
        int d = threadIdx.x + 256*j;
        obf[(size_t)t*DIM + d] = (__bf16)((v[j]-mu)*r*s[d] + b[d]);
    }
}

// ---------------- LN2 fused with router ----------------
__global__ __launch_bounds__(256) void ln2_router_kernel(const float* __restrict__ x,
    const float* __restrict__ s, const float* __restrict__ b,
    const float* __restrict__ rw, __bf16* __restrict__ obf,
    float* __restrict__ tw, int* __restrict__ ti, int* __restrict__ counts)
{
    int t = blockIdx.x;
    const float* xp = x + (size_t)t * DIM;
    float v[4]; float sum = 0.f, sq = 0.f;
    #pragma unroll
    for (int j = 0; j < 4; ++j){
        v[j] = xp[threadIdx.x + 256*j];
        sum += v[j]; sq += v[j]*v[j];
    }
    #pragma unroll
    for (int off = 32; off; off >>= 1){
        sum += __shfl_xor(sum, off, 64);
        sq  += __shfl_xor(sq , off, 64);
    }
    __shared__ float red[4][2];
    __shared__ float red2[4][N_EXP];
    int w = threadIdx.x >> 6, lane = threadIdx.x & 63;
    if (lane == 0){ red[w][0] = sum; red[w][1] = sq; }
    __syncthreads();
    sum = red[0][0]+red[1][0]+red[2][0]+red[3][0];
    sq  = red[0][1]+red[1][1]+red[2][1]+red[3][1];
    float mu = sum * (1.f/DIM);
    float var = sq * (1.f/DIM) - mu*mu;
    float r = rsqrtf(var + EPS);
    float p[N_EXP] = {};
    #pragma unroll
    for (int j = 0; j < 4; ++j){
        int d = threadIdx.x + 256*j;
        float o = (v[j]-mu)*r*s[d] + b[d];
        obf[(size_t)t*DIM + d] = (__bf16)o;
        #pragma unroll
        for (int e = 0; e < N_EXP; ++e) p[e] += o * rw[e*DIM + d];
    }
    #pragma unroll
    for (int e = 0; e < N_EXP; ++e){
        #pragma unroll
        for (int off = 32; off; off >>= 1) p[e] += __shfl_xor(p[e], off, 64);
    }
    if (lane == 0){
        #pragma unroll
        for (int e = 0; e < N_EXP; ++e) red2[w][e] = p[e];
    }
    __syncthreads();
    if (threadIdx.x == 0){
        float q[N_EXP];
        #pragma unroll
        for (int e = 0; e < N_EXP; ++e)
            q[e] = red2[0][e]+red2[1][e]+red2[2][e]+red2[3][e];
        float mx = q[0];
        #pragma unroll
        for (int e = 1; e < N_EXP; ++e) mx = fmaxf(mx, q[e]);
        float ssum = 0.f;
        #pragma unroll
        for (int e = 0; e < N_EXP; ++e){ q[e] = expf(q[e]-mx); ssum += q[e]; }
        int i0 = 0;
        #pragma unroll
        for (int e = 1; e < N_EXP; ++e) if (q[e] > q[i0]) i0 = e;
        int i1 = (i0 == 0) ? 1 : 0;
        #pragma unroll
        for (int e = 0; e < N_EXP; ++e) if (e != i0 && q[e] > q[i1]) i1 = e;
        float w0 = q[i0]/ssum, w1 = q[i1]/ssum;
        float sw = w0 + w1; w0 /= sw; w1 /= sw;
        tw[t*2] = w0; tw[t*2+1] = w1;
        ti[t*2] = i0; ti[t*2+1] = i1;
        atomicAdd(&counts[i0], 1);
        atomicAdd(&counts[i1], 1);
    }
}

// ============ fast bf16 MFMA GEMM: 3-buffer 2-deep prefetch + XOR swizzle ============
template<int MODE, int EPI, int CBF, int SWZ>
__global__ __launch_bounds__(256,3) void mfma_gemm_fast(
    const __bf16* __restrict__ A, const __bf16* __restrict__ W,
    const void* __restrict__ RG, void* __restrict__ Cv,
    const int* __restrict__ tok_of_slot, const int* __restrict__ counts,
    const int* __restrict__ offs, int M, int N, int K, int lda)
{
    int bx = blockIdx.x, by = blockIdx.y;
    if (SWZ){
        int nwg = gridDim.x*gridDim.y;
        int id = by*gridDim.x + bx;
        int swz = (id & 7)*(nwg >> 3) + (id >> 3);
        bx = swz % gridDim.x; by = swz / gridDim.x;
    }
    int e    = (MODE == 0) ? 0 : blockIdx.z;
    int cnt  = (MODE == 0) ? M : counts[e];
    int base = (MODE == 0) ? 0 : offs[e];
    int m0 = by * 128;
    if (m0 >= cnt) return;
    int n0 = bx * 128;
    const __bf16* We = W + (size_t)e * N * K;

    __shared__ __bf16 As[3*128*32];
    __shared__ __bf16 Ws[3*128*32];

    int tid = threadIdx.x;
    int wave = tid >> 6, lane = tid & 63;
    int c0 = wave*2, c1 = wave*2 + 1;
    int lr0 = c0*16 + (lane >> 2);
    int lr1 = c1*16 + (lane >> 2);
    int koff = (((lane & 3) ^ ((lane >> 3) & 3)) * 8);   // swizzled source colblock

    int ar0, ar1;
    {
        int m0c = m0 + lr0, m1c = m0 + lr1;
        if (MODE != 0){
            if (m0c >= cnt) m0c = cnt - 1;
            if (m1c >= cnt) m1c = cnt - 1;
        }
        if (MODE == 1){ ar0 = tok_of_slot[base + m0c]; ar1 = tok_of_slot[base + m1c]; }
        else if (MODE == 2){ ar0 = base + m0c; ar1 = base + m1c; }
        else { ar0 = m0c; ar1 = m1c; }
    }
    const __bf16* aS0 = A + (size_t)ar0 * lda + koff;
    const __bf16* aS1 = A + (size_t)ar1 * lda + koff;
    const __bf16* wS0 = We + (size_t)(n0 + lr0) * K + koff;
    const __bf16* wS1 = We + (size_t)(n0 + lr1) * K + koff;
    __bf16* ldsA0 = As + c0*512;
    __bf16* ldsA1 = As + c1*512;
    __bf16* ldsW0 = Ws + c0*512;
    __bf16* ldsW1 = Ws + c1*512;

    int wm = (wave >> 1) * 64, wn = (wave & 1) * 64;
    int fr = lane & 15;
    const int scb = (((lane >> 4) ^ ((lane >> 1) & 3)) * 8);  // swizzled read colblock

    f32x4 acc[4][4];
    #pragma unroll
    for (int i = 0; i < 4; ++i)
        #pragma unroll
        for (int j = 0; j < 4; ++j)
            acc[i][j] = (f32x4){0.f, 0.f, 0.f, 0.f};

    int NK = K >> 5;
    gload16(aS0, ldsA0);        gload16(aS1, ldsA1);
    gload16(wS0, ldsW0);        gload16(wS1, ldsW1);
    if (NK > 1){
        gload16(aS0 + 32, ldsA0 + 4096); gload16(aS1 + 32, ldsA1 + 4096);
        gload16(wS0 + 32, ldsW0 + 4096); gload16(wS1 + 32, ldsW1 + 4096);
    }

    int cur = 0;
    for (int t = 0; t < NK; ++t){
        if (t + 2 < NK){
            int nb = cur + 2; if (nb >= 3) nb -= 3;
            int off = nb*4096;
            size_t ko = (size_t)(t+2)*32;
            gload16(aS0 + ko, ldsA0 + off);
            gload16(aS1 + ko, ldsA1 + off);
            gload16(wS0 + ko, ldsW0 + off);
            gload16(wS1 + ko, ldsW1 + off);
            asm volatile("s_waitcnt vmcnt(8)" ::: "memory");
        } else if (t + 1 < NK){
            asm volatile("s_waitcnt vmcnt(4)" ::: "memory");
        } else {
            asm volatile("s_waitcnt vmcnt(0)" ::: "memory");
        }
        __builtin_amdgcn_s_barrier();
        int bo = cur*4096;
        bf16x8 af[4], bf[4];
        #pragma unroll
        for (int i = 0; i < 4; ++i)
            af[i] = *(const bf16x8*)&As[bo + (wm + i*16 + fr)*32 + scb];
        #pragma unroll
        for (int j = 0; j < 4; ++j)
            bf[j] = *(const bf16x8*)&Ws[bo + (wn + j*16 + fr)*32 + scb];
        __builtin_amdgcn_s_setprio(1);
        #pragma unroll
        for (int i = 0; i < 4; ++i)
            #pragma unroll
            for (int j = 0; j < 4; ++j)
                acc[i][j] = mfma16(af[i], bf[j], acc[i][j]);
        __builtin_amdgcn_s_setprio(0);
        __builtin_amdgcn_s_barrier();
        cur = cur + 1; if (cur >= 3) cur -= 3;
    }

    int orow = (lane >> 4) * 4;
    int ocol = lane & 15;
    #pragma unroll
    for (int i = 0; i < 4; ++i){
        #pragma unroll
        for (int jj = 0; jj < 4; ++jj){
            #pragma unroll
            for (int j = 0; j < 4; ++j){
                int m = m0 + wm + i*16 + orow + j;
                int n = n0 + wn + jj*16 + ocol;
                if (m < cnt){
                    size_t row = (size_t)(base + m);
                    float v = acc[i][jj][j];
                    if (EPI == 1) v += ((const float*)RG)[row * (size_t)N + n];
                    if (CBF) ((__bf16*)Cv)[row * (size_t)N + n] = (__bf16)v;
                    else     ((float* )Cv)[row * (size_t)N + n] = v;
                }
            }
        }
    }
}

// ======== fused MoE gate+up GEMM, occupancy-tiled: block 64x128, wave 64x32 ========
// acc = 16 f32x4 (64 regs); LDS = 2buf x (A 4KB + G 8KB + U 8KB) = 40KB -> ~4 blk/CU.
// Grid (HID/128, 32, N_EXP), outer stride loop over m-blocks of 64 slots.
__global__ __launch_bounds__(256,3) void moe_gateup_fast(
    const __bf16* __restrict__ A, const __bf16* __restrict__ Wg,
    const __bf16* __restrict__ Wu, const int* __restrict__ tok_of_slot,
    const int* __restrict__ counts, const int* __restrict__ offs,
    __bf16* __restrict__ H)
{
    int e = blockIdx.z;
    int cnt = counts[e];
    int base = offs[e];
    int n0 = blockIdx.x * 128;
    const __bf16* Wge = Wg + (size_t)e * HID * DIM;
    const __bf16* Wue = Wu + (size_t)e * HID * DIM;

    __shared__ __bf16 As[2*64*32];     // buf stride 2048 elems
    __shared__ __bf16 Gs[2*128*32];    // buf stride 4096 elems
    __shared__ __bf16 Us[2*128*32];

    int tid = threadIdx.x;
    int wave = tid >> 6, lane = tid & 63;
    int lrow = lane >> 2;                       // row within 16-row chunk
    int koff = (((lane & 3) ^ ((lane >> 3) & 3)) * 8);   // swizzled source colblock

    // weight source pointers (fixed across mb loop): wave w stages G/U chunks 2w,2w+1
    const __bf16* gS0 = Wge + (size_t)(n0 + wave*32      + lrow) * DIM + koff;
    const __bf16* gS1 = Wge + (size_t)(n0 + wave*32 + 16 + lrow) * DIM + koff;
    const __bf16* uS0 = Wue + (size_t)(n0 + wave*32      + lrow) * DIM + koff;
    const __bf16* uS1 = Wue + (size_t)(n0 + wave*32 + 16 + lrow) * DIM + koff;
    __bf16* ldsA  = As + wave*512;              // A chunk w (16 rows)
    __bf16* ldsG0 = Gs + (wave*2    )*512;
    __bf16* ldsG1 = Gs + (wave*2 + 1)*512;
    __bf16* ldsU0 = Us + (wave*2    )*512;
    __bf16* ldsU1 = Us + (wave*2 + 1)*512;

    int fr = lane & 15;
    const int scb = (((lane >> 4) ^ ((lane >> 1) & 3)) * 8);
    int orow = (lane >> 4) * 4;
    int ocol = lane & 15;
    const int NK = DIM >> 5;   // 32

    for (int mb = blockIdx.y; mb * 64 < cnt; mb += gridDim.y){
        int m0 = mb * 64;
        // A gather source for this m-block: wave w stages rows m0+16w..+15
        int mc = m0 + wave*16 + lrow;
        if (mc >= cnt) mc = cnt - 1;
        const __bf16* aS = A + (size_t)tok_of_slot[base + mc] * DIM + koff;

        f32x4 accg[4][2], accu[4][2];
        #pragma unroll
        for (int i = 0; i < 4; ++i)
            #pragma unroll
            for (int j = 0; j < 2; ++j){
                accg[i][j] = (f32x4){0.f, 0.f, 0.f, 0.f};
                accu[i][j] = (f32x4){0.f, 0.f, 0.f, 0.f};
            }

        // prologue: stage tile 0 into buf 0
        gload16(aS, ldsA);
        gload16(gS0, ldsG0); gload16(gS1, ldsG1);
        gload16(uS0, ldsU0); gload16(uS1, ldsU1);

        int bo = 0;
        for (int t = 0; t < NK; ++t){
            if (t + 1 < NK){
                int nA = (bo ^ 1) * 2048, nW = (bo ^ 1) * 4096;
                size_t ko = (size_t)(t+1)*32;
                gload16(aS + ko, ldsA + nA);
                gload16(gS0 + ko, ldsG0 + nW); gload16(gS1 + ko, ldsG1 + nW);
                gload16(uS0 + ko, ldsU0 + nW); gload16(uS1 + ko, ldsU1 + nW);
                asm volatile("s_waitcnt vmcnt(5)" ::: "memory");
            } else {
                asm volatile("s_waitcnt vmcnt(0)" ::: "memory");
            }
            __builtin_amdgcn_s_barrier();
            int boA = bo*2048, boW = bo*4096;
            bf16x8 af[4], gf[2], uf[2];
            #pragma unroll
            for (int i = 0; i < 4; ++i)
                af[i] = *(const bf16x8*)&As[boA + (i*16 + fr)*32 + scb];
            #pragma unroll
            for (int j = 0; j < 2; ++j){
                gf[j] = *(const bf16x8*)&Gs[boW + (wave*32 + j*16 + fr)*32 + scb];
                uf[j] = *(const bf16x8*)&Us[boW + (wave*32 + j*16 + fr)*32 + scb];
            }
            __builtin_amdgcn_s_setprio(1);
            #pragma unroll
            for (int i = 0; i < 4; ++i)
                #pragma unroll
                for (int j = 0; j < 2; ++j){
                    accg[i][j] = mfma16(af[i], gf[j], accg[i][j]);
                    accu[i][j] = mfma16(af[i], uf[j], accu[i][j]);
                }
            __builtin_amdgcn_s_setprio(0);
            __builtin_amdgcn_s_barrier();
            bo ^= 1;
        }

        // epilogue: H[slot][n0 + wave*32 + j*16 + ocol]
        #pragma unroll
        for (int i = 0; i < 4; ++i){
            #pragma unroll
            for (int j = 0; j < 2; ++j){
                #pragma unroll
                for (int j4 = 0; j4 < 4; ++j4){
                    int m = m0 + i*16 + orow + j4;
                    if (m < cnt){
                        size_t row = (size_t)(base + m);
                        int n = n0 + wave*32 + j*16 + ocol;
                        float g = accg[i][j][j4], u = accu[i][j][j4];
                        H[row * (size_t)HID + n] = (__bf16)(siluf(g) * u);
                    }
                }
            }
        }
        // loop ends after a barrier; safe to restage buf 0 next iteration
    }
}

// ---------------- x_proj K-split GEMM (3-buffer 2-deep + swizzle) ----------------
__global__ __launch_bounds__(256,3) void xproj_ks_kernel(
    const __bf16* __restrict__ A, const __bf16* __restrict__ W,
    float* __restrict__ Cpart)
{
    int m0 = blockIdx.y * 128;
    int kbeg = blockIdx.z * XPJ_KLEN;

    __shared__ __bf16 As[3*128*32];
    __shared__ __bf16 Ws[3*128*32];

    int tid = threadIdx.x;
    int wave = tid >> 6, lane = tid & 63;
    int c0 = wave*2, c1 = wave*2 + 1;
    int lr0 = c0*16 + (lane >> 2);
    int lr1 = c1*16 + (lane >> 2);
    int koff = (((lane & 3) ^ ((lane >> 3) & 3)) * 8);

    const __bf16* aS0 = A + (size_t)(m0 + lr0) * D_INNER + kbeg + koff;
    const __bf16* aS1 = A + (size_t)(m0 + lr1) * D_INNER + kbeg + koff;
    const __bf16* wS0 = W + (size_t)lr0 * D_INNER + kbeg + koff;
    const __bf16* wS1 = W + (size_t)lr1 * D_INNER + kbeg + koff;
    __bf16* ldsA0 = As + c0*512;
    __bf16* ldsA1 = As + c1*512;
    __bf16* ldsW0 = Ws + c0*512;
    __bf16* ldsW1 = Ws + c1*512;

    int wm = (wave >> 1) * 64, wn = (wave & 1) * 64;
    int fr = lane & 15;
    const int scb = (((lane >> 4) ^ ((lane >> 1) & 3)) * 8);

    f32x4 acc[4][4];
    #pragma unroll
    for (int i = 0; i < 4; ++i)
        #pragma unroll
        for (int j = 0; j < 4; ++j)
            acc[i][j] = (f32x4){0.f, 0.f, 0.f, 0.f};

    gload16(aS0, ldsA0); gload16(aS1, ldsA1);
    gload16(wS0, ldsW0); gload16(wS1, ldsW1);
    gload16(aS0 + 32, ldsA0 + 4096); gload16(aS1 + 32, ldsA1 + 4096);
    gload16(wS0 + 32, ldsW0 + 4096); gload16(wS1 + 32, ldsW1 + 4096);

    const int NK = XPJ_KLEN >> 5;   // 8
    int cur = 0;
    for (int t = 0; t < NK; ++t){
        if (t + 2 < NK){
            int nb = cur + 2; if (nb >= 3) nb -= 3;
            int off = nb*4096;
            size_t ko = (size_t)(t+2)*32;
            gload16(aS0 + ko, ldsA0 + off);
            gload16(aS1 + ko, ldsA1 + off);
            gload16(wS0 + ko, ldsW0 + off);
            gload16(wS1 + ko, ldsW1 + off);
            asm volatile("s_waitcnt vmcnt(8)" ::: "memory");
        } else if (t + 1 < NK){
            asm volatile("s_waitcnt vmcnt(4)" ::: "memory");
        } else {
            asm volatile("s_waitcnt vmcnt(0)" ::: "memory");
        }
        __builtin_amdgcn_s_barrier();
        int bo = cur*4096;
        bf16x8 af[4], bf[4];
        #pragma unroll
        for (int i = 0; i < 4; ++i)
            af[i] = *(const bf16x8*)&As[bo + (wm + i*16 + fr)*32 + scb];
        #pragma unroll
        for (int j = 0; j < 4; ++j)
            bf[j] = *(const bf16x8*)&Ws[bo + (wn + j*16 + fr)*32 + scb];
        __builtin_amdgcn_s_setprio(1);
        #pragma unroll
        for (int i = 0; i < 4; ++i)
            #pragma unroll
            for (int j = 0; j < 4; ++j)
                acc[i][j] = mfma16(af[i], bf[j], acc[i][j]);
        __builtin_amdgcn_s_setprio(0);
        __builtin_amdgcn_s_barrier();
        cur = cur + 1; if (cur >= 3) cur -= 3;
    }

    float* Cz = Cpart + (size_t)blockIdx.z * NTOK * 128;
    int orow = (lane >> 4) * 4;
    int ocol = lane & 15;
    #pragma unroll
    for (int i = 0; i < 4; ++i){
        #pragma unroll
        for (int jj = 0; jj < 4; ++jj){
            #pragma unroll
            for (int j = 0; j < 4; ++j){
                int m = m0 + wm + i*16 + orow + j;
                int n = wn + jj*16 + ocol;
                Cz[(size_t)m * 128 + n] = acc[i][jj][j];
            }
        }
    }
}

__global__ __launch_bounds__(256) void xproj_reduce(const float* __restrict__ Cpart,
    float* __restrict__ proj)
{
    int idx = blockIdx.x*256 + threadIdx.x;
    int t = idx / 96, n = idx - t*96;
    float s = 0.f;
    #pragma unroll
    for (int z = 0; z < XPJ_KS; ++z)
        s += Cpart[(size_t)z * NTOK * 128 + (size_t)t * 128 + n];
    proj[idx] = s;
}

// ---------------- reg-staging MFMA GEMM (dt: softplus(A@W^T + bias)) ----------------
__global__ __launch_bounds__(256,2) void dt_gemm(
    const float* __restrict__ A, const float* __restrict__ W,
    const float* __restrict__ bias, float* __restrict__ C,
    int M, int N, int K, int lda)
{
    int m0 = blockIdx.y * 128;
    int n0 = blockIdx.x * 128;

    __shared__ __bf16 As[128*32];
    __shared__ __bf16 Ws[128*32];

    int tid = threadIdx.x;
    int srow = tid >> 1;
    int scol = (tid & 1) * 16;

    const float* af = A + (size_t)(m0 + srow) * lda + scol;
    const float* wptr = W + (size_t)(n0 + srow) * K + scol;

    f32x4 raf[4], rw[4];
    #pragma unroll
    for (int q = 0; q < 4; ++q){
        raf[q] = *(const f32x4*)(af + q*4);
        rw[q]  = *(const f32x4*)(wptr + q*4);
    }

    int wave = tid >> 6, lane = tid & 63;
    int wm = (wave >> 1) * 64, wn = (wave & 1) * 64;
    int fr = lane & 15, fk = (lane >> 4) * 8;

    f32x4 acc[4][4];
    #pragma unroll
    for (int i = 0; i < 4; ++i)
        #pragma unroll
        for (int j = 0; j < 4; ++j)
            acc[i][j] = (f32x4){0.f, 0.f, 0.f, 0.f};

    for (int k0 = 0; k0 < K; k0 += 32){
        cvt_store16(&As[srow*32 + scol], raf[0], raf[1], raf[2], raf[3]);
        cvt_store16(&Ws[srow*32 + scol], rw[0], rw[1], rw[2], rw[3]);
        __syncthreads();
        if (k0 + 32 < K){
            #pragma unroll
            for (int q = 0; q < 4; ++q){
                raf[q] = *(const f32x4*)(af + k0 + 32 + q*4);
                rw[q]  = *(const f32x4*)(wptr + k0 + 32 + q*4);
            }
        }
        bf16x8 afr[4], bfr[4];
        #pragma unroll
        for (int i = 0; i < 4; ++i)
            afr[i] = *(const bf16x8*)&As[(wm + i*16 + fr)*32 + fk];
        #pragma unroll
        for (int i = 0; i < 4; ++i)
            bfr[i] = *(const bf16x8*)&Ws[(wn + i*16 + fr)*32 + fk];
        #pragma unroll
        for (int i = 0; i < 4; ++i)
            #pragma unroll
            for (int j = 0; j < 4; ++j)
                acc[i][j] = mfma16(afr[i], bfr[j], acc[i][j]);
        __syncthreads();
    }

    int orow = (lane >> 4) * 4;
    int ocol = lane & 15;
    #pragma unroll
    for (int i = 0; i < 4; ++i){
        #pragma unroll
        for (int jj = 0; jj < 4; ++jj){
            #pragma unroll
            for (int j = 0; j < 4; ++j){
                int m = m0 + wm + i*16 + orow + j;
                int n = n0 + wn + jj*16 + ocol;
                if (m < M && n < N){
                    float v = acc[i][jj][j] + bias[n];
                    v = (v > 20.f) ? v : log1pf(expf(v));
                    C[(size_t)m * N + n] = v;
                }
            }
        }
    }
}

// ---------------- conv: f32 + bf16 outputs ----------------
__global__ __launch_bounds__(256) void conv_kernel(const float* __restrict__ xz,
    const float* __restrict__ cs, const float* __restrict__ cw,
    const float* __restrict__ cb, float* __restrict__ xcs,
    __bf16* __restrict__ xcs_bf)
{
    int idx = blockIdx.x*256 + threadIdx.x;
    int d = idx & (D_INNER-1);
    int bt = idx >> 11;
    int b = bt >> 11;
    int t = bt & (TT-1);
    float acc = cb[d];
    #pragma unroll
    for (int k = 0; k < 4; ++k){
        int tau = t + k - 3;
        float xv;
        if (tau >= 0) xv = xz[(size_t)(b*TT + tau)*(2*D_INNER) + d];
        else          xv = cs[((size_t)b*D_INNER + d)*3 + (tau + 3)];
        acc += cw[d*4 + k] * xv;
    }
    float v = siluf(acc);
    xcs[idx] = v;
    xcs_bf[idx] = (__bf16)v;
}

// ---------------- chunked SSM scan ----------------
__global__ __launch_bounds__(256) void scan_pass1(const float* __restrict__ dtp,
    const float* __restrict__ proj, const float* __restrict__ xcs,
    const float* __restrict__ A_log, float* __restrict__ hend,
    float* __restrict__ sumdt)
{
    int gid = blockIdx.x*256 + threadIdx.x;
    int bd = gid & (BB*D_INNER-1);
    int chunk = gid >> 12;
    int b = bd >> 11, d = bd & (D_INNER-1);
    float As[D_STATE], h[D_STATE];
    #pragma unroll
    for (int s = 0; s < D_STATE; ++s){
        As[s] = -__expf(A_log[d*D_STATE + s]);
        h[s] = 0.f;
    }
    float sdt = 0.f;
    int base = b*TT + chunk*CLEN;
    for (int t = 0; t < CLEN; ++t){
        size_t bt = (size_t)(base + t);
        float dt = dtp[bt*D_INNER + d];
        float x  = xcs[bt*D_INNER + d];
        f32x4 Bv[4];
        #pragma unroll
        for (int q = 0; q < 4; ++q) Bv[q] = *(const f32x4*)(proj + bt*96 + DT_RANK + q*4);
        float dtx = dt * x;
        sdt += dt;
        #pragma unroll
        for (int s = 0; s < D_STATE; ++s)
            h[s] = __expf(dt*As[s])*h[s] + Bv[s>>2][s&3]*dtx;
    }
    size_t hb = ((size_t)bd*NCHUNK + chunk)*D_STATE;
    #pragma unroll
    for (int q = 0; q < 4; ++q)
        *(f32x4*)(hend + hb + q*4) = (f32x4){h[q*4], h[q*4+1], h[q*4+2], h[q*4+3]};
    sumdt[bd*NCHUNK + chunk] = sdt;
}

__global__ __launch_bounds__(256) void scan_combine(const float* __restrict__ hend,
    const float* __restrict__ sumdt, const float* __restrict__ A_log,
    const float* __restrict__ ssm0, float* __restrict__ hstart)
{
    int gid = blockIdx.x*256 + threadIdx.x;
    int s = gid & 15;
    int bd = gid >> 4;
    int b = bd >> 11, d = bd & (D_INNER-1);
    float As = -__expf(A_log[d*D_STATE + s]);
    float h = ssm0[((size_t)b*D_INNER + d)*D_STATE + s];
    for (int c = 0; c < NCHUNK; ++c){
        size_t idx = ((size_t)bd*NCHUNK + c)*D_STATE + s;
        hstart[idx] = h;
        h = hend[idx] + __expf(As * sumdt[bd*NCHUNK + c]) * h;
    }
}

__global__ __launch_bounds__(256) void scan_pass3(const float* __restrict__ dtp,
    const float* __restrict__ proj, const float* __restrict__ xcs,
    const float* __restrict__ xz, const float* __restrict__ A_log,
    const float* __restrict__ Dp, const float* __restrict__ hstart,
    __bf16* __restrict__ ym)
{
    int gid = blockIdx.x*256 + threadIdx.x;
    int bd = gid & (BB*D_INNER-1);
    int chunk = gid >> 12;
    int b = bd >> 11, d = bd & (D_INNER-1);
    float As[D_STATE], h[D_STATE];
    #pragma unroll
    for (int s = 0; s < D_STATE; ++s)
        As[s] = -__expf(A_log[d*D_STATE + s]);
    size_t hb = ((size_t)bd*NCHUNK + chunk)*D_STATE;
    #pragma unroll
    for (int q = 0; q < 4; ++q){
        f32x4 hv = *(const f32x4*)(hstart + hb + q*4);
        h[q*4] = hv[0]; h[q*4+1] = hv[1]; h[q*4+2] = hv[2]; h[q*4+3] = hv[3];
    }
    float Dd = Dp[d];
    int base = b*TT + chunk*CLEN;
    for (int t = 0; t < CLEN; ++t){
        size_t bt = (size_t)(base + t);
        float dt = dtp[bt*D_INNER + d];
        float x  = xcs[bt*D_INNER + d];
        f32x4 Bv[4], Cv[4];
        #pragma unroll
        for (int q = 0; q < 4; ++q){
            Bv[q] = *(const f32x4*)(proj + bt*96 + DT_RANK + q*4);
            Cv[q] = *(const f32x4*)(proj + bt*96 + DT_RANK + D_STATE + q*4);
        }
        float dtx = dt * x;
        float p = 0.f;
        #pragma unroll
        for (int s = 0; s < D_STATE; ++s){
            h[s] = __expf(dt*As[s])*h[s] + Bv[s>>2][s&3]*dtx;
            p += h[s] * Cv[s>>2][s&3];
        }
        float y = p + Dd*x;
        float z = xz[bt*(2*D_INNER) + D_INNER + d];
        float sz = z / (1.f + __expf(-z));
        ym[bt*D_INNER + d] = (__bf16)(y * sz);
    }
}

// ---------------- slot assignment ----------------
__global__ void offs_kernel(const int* __restrict__ counts, int* __restrict__ offs)
{
    if (threadIdx.x == 0 && blockIdx.x == 0){
        int s = 0;
        for (int e = 0; e < N_EXP; ++e){ offs[e] = s; s += counts[e]; }
    }
}

__global__ __launch_bounds__(256) void assign_kernel(const int* __restrict__ ti,
    const int* __restrict__ offs, int* __restrict__ cursors,
    int* __restrict__ tok_of_slot, int* __restrict__ slot_of)
{
    int t = blockIdx.x*256 + threadIdx.x;
    if (t >= NTOK) return;
    #pragma unroll
    for (int k = 0; k < TOP_K; ++k){
        int e = ti[t*2 + k];
        int pos = atomicAdd(&cursors[e], 1);
        int slot = offs[e] + pos;
        tok_of_slot[slot] = t;
        slot_of[t*2 + k] = slot;
    }
}

// ---------------- final combine ----------------
__global__ __launch_bounds__(256) void final_kernel(const float* __restrict__ x1,
    const float* __restrict__ down_out, const float* __restrict__ tw,
    const int* __restrict__ slot_of, float* __restrict__ out)
{
    int idx4 = blockIdx.x*256 + threadIdx.x;
    int t = idx4 >> 8;
    int c = idx4 & 255;
    float w0 = tw[t*2], w1 = tw[t*2+1];
    size_t s0 = (size_t)slot_of[t*2] * DIM;
    size_t s1 = (size_t)slot_of[t*2+1] * DIM;
    float4 a = *(const float4*)(x1 + (size_t)t*DIM + c*4);
    float4 d0 = *(const float4*)(down_out + s0 + c*4);
    float4 d1 = *(const float4*)(down_out + s1 + c*4);
    float4 r;
    r.x = a.x + w0*d0.x + w1*d1.x;
    r.y = a.y + w0*d0.y + w1*d1.y;
    r.z = a.z + w0*d0.z + w1*d1.z;
    r.w = a.w + w0*d0.w + w1*d1.w;
    *(float4*)(out + (size_t)t*DIM + c*4) = r;
}

extern "C" void kernel_launch(void* const* d_in, const int* in_sizes, int n_in,
                              void* d_out, int out_size, void* d_ws, size_t ws_size,
                              hipStream_t stream)
{
    const float* x        = (const float*)d_in[0];
    const float* ssm0     = (const float*)d_in[1];
    const float* conv0    = (const float*)d_in[2];
    const float* ln1_s    = (const float*)d_in[3];
    const float* ln1_b    = (const float*)d_in[4];
    const float* ln2_s    = (const float*)d_in[5];
    const float* ln2_b    = (const float*)d_in[6];
    const float* in_proj  = (const float*)d_in[7];
    const float* conv_w   = (const float*)d_in[8];
    const float* conv_b   = (const float*)d_in[9];
    const float* x_proj   = (const float*)d_in[10];
    const float* dt_proj  = (const float*)d_in[11];
    const float* dt_b     = (const float*)d_in[12];
    const float* A_log    = (const float*)d_in[13];
    const float* Dp       = (const float*)d_in[14];
    const float* out_proj = (const float*)d_in[15];
    const float* router_w = (const float*)d_in[16];
    const float* w_gate   = (const float*)d_in[17];
    const float* w_up     = (const float*)d_in[18];
    const float* w_down   = (const float*)d_in[19];
    float* out = (float*)d_out;

    float* ws = (float*)d_ws;
    __bf16* xn_bf  = (__bf16*)(ws + OFF_R0);
    float*  hend   = ws + OFF_R0;
    __bf16* ym_bf  = (__bf16*)(ws + OFF_R0);
    float*  xpart  = ws + OFF_R1;
    float*  hst    = ws + OFF_R1;
    float*  sdt    = ws + OFF_R2;
    __bf16* opbf   = (__bf16*)(ws + OFF_R2);
    __bf16* xn2bf  = (__bf16*)(ws + OFF_R2);
    float*  xz     = ws + OFF_XZ;
    __bf16* H      = (__bf16*)(ws + OFF_H);
    __bf16* wubf   = (__bf16*)(ws + OFF_WU);
    float*  xcs    = ws + OFF_XCS;
    float*  dnout  = ws + OFF_XCS;
    float*  dtp    = ws + OFF_DTP;
    __bf16* ipbf   = (__bf16*)(ws + OFF_DTP);
    __bf16* wgbf   = (__bf16*)(ws + OFF_DTP);
    __bf16* wdbf   = (__bf16*)(ws + OFF_DTP);
    __bf16* xcs_bf = (__bf16*)(ws + OFF_X1);
    float*  x1     = ws + OFF_X1;
    float*  proj   = ws + OFF_PROJ;
    float*  tw     = ws + OFF_TW;
    __bf16* xpw    = (__bf16*)(ws + OFF_XPW);
    int*    ip     = (int*)(ws + OFF_INT);
    int* ti          = ip + IO_TI;
    int* counts      = ip + IO_CNT;
    int* cursors     = ip + IO_CUR;
    int* offs        = ip + IO_OFS;
    int* tok_of_slot = ip + IO_TOK;
    int* slot_of     = ip + IO_SLOT;

    hipMemsetAsync(counts, 0, 16*sizeof(int), stream);

    // 0a. in_proj -> bf16 (dtp region, dead until step 5)
    cvt_w_kernel<<<1024, 256, 0, stream>>>(in_proj, ipbf, (2*D_INNER*DIM)/4);
    // 1. xn_bf = LN1(x)
    ln_kernel<<<NTOK, 256, 0, stream>>>(x, ln1_s, ln1_b, xn_bf);
    // 2. xz = xn @ in_proj^T
    mfma_gemm_fast<0,0,0,1><<<dim3(32,32), 256, 0, stream>>>(xn_bf, ipbf, nullptr, xz,
        nullptr, nullptr, nullptr, NTOK, 2*D_INNER, DIM, DIM);
    // 3. conv + silu -> xcs f32 (scan) + xcs_bf (x_proj GEMM)
    conv_kernel<<<(NTOK*D_INNER)/256, 256, 0, stream>>>(xz, conv0, conv_w, conv_b, xcs, xcs_bf);
    // 4. proj = xcs @ x_proj^T  (K-split fast GEMM + reduce)
    cvt_pad_xproj<<<256, 256, 0, stream>>>(x_proj, xpw);
    xproj_ks_kernel<<<dim3(1,32,XPJ_KS), 256, 0, stream>>>(xcs_bf, xpw, xpart);
    xproj_reduce<<<(NTOK*96)/256, 256, 0, stream>>>(xpart, proj);
    // 5. dtp = softplus(proj[:,:64] @ dt_proj^T + dt_b)
    dt_gemm<<<dim3(16,32), 256, 0, stream>>>(proj, dt_proj, dt_b, dtp,
        NTOK, D_INNER, DT_RANK, 96);
    // 6. chunked scan
    scan_pass1<<<1024, 256, 0, stream>>>(dtp, proj, xcs, A_log, hend, sdt);
    scan_combine<<<256, 256, 0, stream>>>(hend, sdt, A_log, ssm0, hst);
    scan_pass3<<<1024, 256, 0, stream>>>(dtp, proj, xcs, xz, A_log, Dp, hst, ym_bf);
    // 6b. out_proj -> bf16 (R2; sdt dead after combine)
    cvt_w_kernel<<<512, 256, 0, stream>>>(out_proj, opbf, (DIM*D_INNER)/4);
    // 7. x1 = x + ym @ out_proj^T
    mfma_gemm_fast<0,1,0,1><<<dim3(8,32), 256, 0, stream>>>(ym_bf, opbf, x, x1,
        nullptr, nullptr, nullptr, NTOK, DIM, D_INNER, D_INNER);
    // 8. LN2 + router fused -> xn2bf, tw, ti, counts
    ln2_router_kernel<<<NTOK, 256, 0, stream>>>(x1, ln2_s, ln2_b, router_w,
        xn2bf, tw, ti, counts);
    // 9. slot assignment
    offs_kernel<<<1, 64, 0, stream>>>(counts, offs);
    assign_kernel<<<NTOK/256, 256, 0, stream>>>(ti, offs, cursors, tok_of_slot, slot_of);
    // 10. MoE: wg -> DTP region (dtp dead), wu -> XZ second half (xz dead); fused gate+up
    cvt_w_kernel<<<2048, 256, 0, stream>>>(w_gate, wgbf, (N_EXP*HID*DIM)/4);
    cvt_w_kernel<<<2048, 256, 0, stream>>>(w_up, wubf, (N_EXP*HID*DIM)/4);
    moe_gateup_fast<<<dim3(HID/128, 32, N_EXP), 256, 0, stream>>>(xn2bf, wgbf, wubf,
        tok_of_slot, counts, offs, H);
    // wd overwrites wg (dead after gateup)
    cvt_w_kernel<<<2048, 256, 0, stream>>>(w_down, wdbf, (N_EXP*DIM*HID)/4);
    mfma_gemm_fast<2,0,0,0><<<dim3(DIM/128, 64, N_EXP), 256, 0, stream>>>(H, wdbf, nullptr, dnout,
        tok_of_slot, counts, offs, NSLOT, DIM, HID, HID);
    // 11. out = x1 + weighted experts
    final_kernel<<<(NTOK*DIM/4)/256, 256, 0, stream>>>(x1, dnout, tw, slot_of, out);
}